// Round 11
// baseline (720.342 us; speedup 1.0000x reference)
//
#include <hip/hip_runtime.h>

#define BB   32
#define SS   512
#define DDIM 512
#define HH   8
#define DFFN 2048
#define MR   (BB*SS)   // 16384 rows

typedef unsigned int   u32;
typedef unsigned short u16;
typedef unsigned char  u8;
typedef __attribute__((ext_vector_type(8))) short bf16x8;
typedef __attribute__((ext_vector_type(4))) float f32x4;

// ---------- bf16 helpers ----------
__device__ __forceinline__ u32 packbf2(float x, float y) {
  u32 ux = __float_as_uint(x), uy = __float_as_uint(y);
  u32 hx = (ux + 0x7FFFu + ((ux >> 16) & 1u)) >> 16;
  u32 hy = (uy + 0x7FFFu + ((uy >> 16) & 1u)) >> 16;
  return hx | (hy << 16);
}
__device__ __forceinline__ u16 pack1bf(float x) {
  u32 u = __float_as_uint(x);
  return (u16)((u + 0x7FFFu + ((u >> 16) & 1u)) >> 16);
}

__device__ __forceinline__ float redsum2(float v) {
  v += __shfl_xor(v, 16, 64);
  v += __shfl_xor(v, 32, 64);
  return v;
}

// exp without max-subtraction: clamp keeps 512*e^80 < f32 max (r9-proven).
__device__ __forceinline__ float expc(float x) { return __expf(fminf(x, 80.f)); }

// ---------- flat f32 -> bf16 pack ----------
__global__ __launch_bounds__(256) void pack_flat(const float* __restrict__ in,
                                                 u16* __restrict__ out) {
  size_t i = ((size_t)blockIdx.x * 256 + threadIdx.x) * 8;
  float4 a = *(const float4*)(in + i);
  float4 b = *(const float4*)(in + i + 4);
  uint4 o;
  o.x = packbf2(a.x, a.y); o.y = packbf2(a.z, a.w);
  o.z = packbf2(b.x, b.y); o.w = packbf2(b.z, b.w);
  *(uint4*)(out + i) = o;
}

// ---------- weight transpose-pack: f32 [K,N] -> bf16 [N,K], gridDim.z = layers ----------
__global__ __launch_bounds__(256) void pack_w_t(const float* __restrict__ in,
                                                u16* __restrict__ out, int K, int N) {
  __shared__ float tile[64][65];
  const int t  = threadIdx.x;
  const int n0 = blockIdx.x * 64, k0 = blockIdx.y * 64;
  in  += (size_t)blockIdx.z * K * N;
  out += (size_t)blockIdx.z * N * K;
  #pragma unroll
  for (int it = 0; it < 4; ++it) {
    int idx = it * 256 + t;
    int kk = idx >> 4, n4 = idx & 15;
    float4 v = *(const float4*)(in + (size_t)(k0 + kk) * N + n0 + n4 * 4);
    tile[kk][n4*4+0] = v.x; tile[kk][n4*4+1] = v.y;
    tile[kk][n4*4+2] = v.z; tile[kk][n4*4+3] = v.w;
  }
  __syncthreads();
  #pragma unroll
  for (int it = 0; it < 4; ++it) {
    int idx = it * 256 + t;
    int nn = idx >> 4, g = idx & 15;
    uint2 o;
    o.x = packbf2(tile[g*4+0][nn], tile[g*4+1][nn]);
    o.y = packbf2(tile[g*4+2][nn], tile[g*4+3][nn]);
    *(uint2*)(out + (size_t)(n0 + nn) * K + k0 + g * 4) = o;
  }
}

// ---------- 256x256 8-phase bf16 MFMA GEMM (m201-style port, plain HIP) ----------
__global__ __launch_bounds__(512, 2) void gemm8(
    const u16* __restrict__ Aa, const u16* __restrict__ Ab, int lda,
    const u16* __restrict__ Ba, const u16* __restrict__ Bb, int ldb,
    const float* __restrict__ biasa, const float* __restrict__ biasb,
    float* __restrict__ outFa, float* __restrict__ outFb,
    u16* __restrict__ outBa, u16* __restrict__ outBb,
    int ldc, int Kz, int relu, float sca, float scb)
{
  __shared__ __align__(16) u8 lds[131072];

  const int z = blockIdx.z;
  const u16* A    = z ? Ab : Aa;
  const u16* Bt   = z ? Bb : Ba;
  const float* bias = z ? biasb : biasa;
  float* outF = z ? outFb : outFa;
  u16*   outB = z ? outBb : outBa;
  const float sc = z ? scb : sca;

  const int nwg  = gridDim.x * gridDim.y;
  const int orig = blockIdx.y * gridDim.x + blockIdx.x;
  const int q8   = nwg >> 3, r8 = nwg & 7;
  const int xcd  = orig & 7, idx8 = orig >> 3;
  const int wg   = (xcd < r8 ? xcd * (q8 + 1) : r8 * (q8 + 1) + (xcd - r8) * q8) + idx8;
  const int bx   = wg % gridDim.x, by = wg / gridDim.x;
  const int row0 = by * 256, col0 = bx * 256;

  const int t    = threadIdx.x;
  const int lane = t & 63, wid = t >> 6;
  const int wm   = wid >> 2, wn = wid & 3;
  const int rl   = lane & 15, kg = lane >> 4;

  const int NT = Kz >> 6;

  f32x4 acc[8][4] = {};

  auto stageA = [&](int buf, int h, int kt) {
    #pragma unroll
    for (int l = 0; l < 2; ++l) {
      int s  = (l * 512 + t) >> 3;
      int kb = ((lane & 7) * 16) ^ ((s & 7) << 4);
      int row = row0 + ((s >> 6) * 128) + h * 64 + (s & 63);
      const u8* src = (const u8*)A + (size_t)row * lda * 2 + (size_t)kt * 128 + kb;
      u8* dst = lds + buf * 65536 + h * 16384 + (l * 512 + wid * 64) * 16;
      __builtin_amdgcn_global_load_lds(
          (const __attribute__((address_space(1))) u32*)src,
          (__attribute__((address_space(3))) u32*)dst, 16, 0, 0);
    }
  };
  auto stageB = [&](int buf, int h, int kt) {
    #pragma unroll
    for (int l = 0; l < 2; ++l) {
      int s  = (l * 512 + t) >> 3;
      int kb = ((lane & 7) * 16) ^ ((s & 7) << 4);
      int col = col0 + ((s >> 5) * 64) + h * 32 + (s & 31);
      const u8* src = (const u8*)Bt + (size_t)col * ldb * 2 + (size_t)kt * 128 + kb;
      u8* dst = lds + buf * 65536 + 32768 + h * 16384 + (l * 512 + wid * 64) * 16;
      __builtin_amdgcn_global_load_lds(
          (const __attribute__((address_space(1))) u32*)src,
          (__attribute__((address_space(3))) u32*)dst, 16, 0, 0);
    }
  };

  auto rdA = [&](int buf, int mh, int m, int ks) -> bf16x8 {
    int s = wm * 64 + m * 16 + rl;
    int off = buf * 65536 + mh * 16384 + s * 128 + (((ks * 32 + kg * 8) * 2) ^ ((s & 7) << 4));
    return *(const bf16x8*)(lds + off);
  };
  auto rdB = [&](int buf, int nh, int n, int ks) -> bf16x8 {
    int s = wn * 32 + n * 16 + rl;
    int off = buf * 65536 + 32768 + nh * 16384 + s * 128 + (((ks * 32 + kg * 8) * 2) ^ ((s & 7) << 4));
    return *(const bf16x8*)(lds + off);
  };

#define GBAR asm volatile("s_barrier" ::: "memory")
#define VMW4 asm volatile("s_waitcnt vmcnt(4)" ::: "memory")

#define PHASE(BUF, MH, NH, STAGECODE, DOVM) do {                               \
    bf16x8 af_[4][2], bf_[2][2];                                               \
    _Pragma("unroll") for (int m_ = 0; m_ < 4; ++m_)                           \
      _Pragma("unroll") for (int k_ = 0; k_ < 2; ++k_)                         \
        af_[m_][k_] = rdA(BUF, MH, m_, k_);                                    \
    _Pragma("unroll") for (int n_ = 0; n_ < 2; ++n_)                           \
      _Pragma("unroll") for (int k_ = 0; k_ < 2; ++k_)                         \
        bf_[n_][k_] = rdB(BUF, NH, n_, k_);                                    \
    STAGECODE;                                                                 \
    if (DOVM) VMW4;                                                            \
    GBAR;                                                                      \
    __builtin_amdgcn_s_setprio(1);                                             \
    _Pragma("unroll") for (int m_ = 0; m_ < 4; ++m_)                           \
      _Pragma("unroll") for (int n_ = 0; n_ < 2; ++n_) {                       \
        acc[(MH)*4+m_][(NH)*2+n_] = __builtin_amdgcn_mfma_f32_16x16x32_bf16(   \
            af_[m_][0], bf_[n_][0], acc[(MH)*4+m_][(NH)*2+n_], 0, 0, 0);       \
        acc[(MH)*4+m_][(NH)*2+n_] = __builtin_amdgcn_mfma_f32_16x16x32_bf16(   \
            af_[m_][1], bf_[n_][1], acc[(MH)*4+m_][(NH)*2+n_], 0, 0, 0);       \
      }                                                                        \
    __builtin_amdgcn_s_setprio(0);                                             \
    GBAR;                                                                      \
  } while (0)

  stageA(0, 0, 0); stageB(0, 0, 0); stageA(0, 1, 0); stageB(0, 1, 0);
  stageA(1, 0, 1); stageB(1, 0, 1);
  VMW4; GBAR;

  for (int i = 0; i < (NT >> 1); ++i) {
    const int T1 = 2 * i + 1;
    int T2 = 2 * i + 2; if (T2 >= NT) T2 -= NT;
    int T3 = 2 * i + 3; if (T3 >= NT) T3 -= NT;
    PHASE(0, 0, 0, stageA(1, 1, T1), 0);
    PHASE(0, 0, 1, stageB(1, 1, T1), 0);
    PHASE(0, 1, 0, stageA(0, 0, T2), 0);
    PHASE(0, 1, 1, stageB(0, 0, T2), 1);
    PHASE(1, 0, 0, stageA(0, 1, T2), 0);
    PHASE(1, 0, 1, stageB(0, 1, T2), 0);
    PHASE(1, 1, 0, stageA(1, 0, T3), 0);
    PHASE(1, 1, 1, stageB(1, 0, T3), 1);
  }
#undef PHASE
#undef GBAR
#undef VMW4

  #pragma unroll
  for (int M = 0; M < 8; ++M) {
    #pragma unroll
    for (int N2 = 0; N2 < 4; ++N2) {
      const int col = col0 + wn * 64 + N2 * 16 + rl;
      const float bs = bias ? bias[col] : 0.f;
      #pragma unroll
      for (int q = 0; q < 4; ++q) {
        const int row = row0 + wm * 128 + M * 16 + kg * 4 + q;
        float v = (acc[M][N2][q] + bs) * sc;
        if (relu) v = fmaxf(v, 0.f);
        if (outF) outF[(size_t)row * ldc + col] = v;
        if (outB) outB[(size_t)row * ldc + col] = pack1bf(v);
      }
    }
  }
}

// ---------- MFMA attention, 2-pass streamed, chain-free pass 2 ----------
// Block = (b,h), 512 threads (8 waves), wave owns row-tiles {w,15-w,16+w,31-w}.
// QK prescaled by sqrt(1/8) in the GEMM epilogue. Pass 1 computes per-chunk
// totals tt (2-shfl butterfly) and stores the exclusive prefix cbA[32] in
// registers (static-indexed) -> pass 2 has NO loop-carried cumsum chain and
// no broadcast shfl (r10 post-mortem: the cbase+=tt chain serialized pass 2's
// rem/sqrt/exp work at only 2 waves/SIMD of TLP).
__global__ __attribute__((amdgpu_flat_work_group_size(512, 512)))
           __attribute__((amdgpu_waves_per_eu(1, 2)))
void attn_mfma(
    const u16* __restrict__ qk, const u16* __restrict__ vbuf,
    const float* __restrict__ gam, u16* __restrict__ out,
    int mask_excl, int zero_pad)
{
  __shared__ __align__(16) u8 kSb[65536];  // K/Q rows [512][64] bf16, byte ^= (row&7)<<4
  __shared__ __align__(16) u8 vTb[65536];  // V^T [64 d][512 k] bf16, u32 ^= ((d&7)^(d>>3))<<4
  __shared__ __align__(16) u8 pChb[8192];  // per-wave 1KB P chunk buffers

  const int t    = threadIdx.x;
  const int lane = t & 63, wid = t >> 6;
  const int ql   = lane & 15, g = lane >> 4;
  const int bh   = blockIdx.x, b = bh >> 3, h = bh & 7;
  const size_t base = (size_t)b * SS * DDIM + (size_t)h * 64;

  float gv = gam[h];
  float sp = (gv > 0.f) ? (gv + log1pf(__expf(-gv))) : log1pf(__expf(gv));
  const float gamma = -sp;

  // ---- stage K/Q (pre-scaled by sqrt(1/8)) ----
  for (int it = 0; it < 8; ++it) {
    int idx = it * 512 + t;
    int j = idx >> 3, u = idx & 7;
    uint4 w = *(const uint4*)(qk + base + (size_t)j * DDIM + u * 8);
    *(uint4*)(kSb + ((j * 128 + u * 16) ^ ((j & 7) << 4))) = w;
  }
  // ---- stage V^T: row-pair loads, packed u32 writes (no same-dword u16
  //      half-writes -> kills the r10 2.08M bank conflicts; 2-way max) ----
  for (int it = 0; it < 4; ++it) {
    int idx = it * 512 + t;
    int jp = idx >> 3, u = idx & 7;   // k-pair = {2jp, 2jp+1}, d-segment u
    const u16* src = vbuf + base + (size_t)(2 * jp) * DDIM + u * 8;
    uint4 r0 = *(const uint4*)src;
    uint4 r1 = *(const uint4*)(src + DDIM);
    const u16* a0 = (const u16*)&r0;
    const u16* a1 = (const u16*)&r1;
    #pragma unroll
    for (int dd = 0; dd < 8; ++dd) {
      int d = u * 8 + dd;
      u32 w = (u32)a0[dd] | ((u32)a1[dd] << 16);
      *(u32*)(vTb + d * 1024 + ((4 * jp) ^ ((dd ^ u) << 4))) = w;
    }
  }
  __syncthreads();

  bool vm[4];
  #pragma unroll
  for (int rg = 0; rg < 4; ++rg) {
    int kl = 4 * g + rg;
    vm[rg] = mask_excl ? (kl < ql) : (kl <= ql);
  }

  u8* pB = pChb + wid * 1024;
  const int swp = (ql & 7) << 4;

  int vbase[4], vsw[4];
  #pragma unroll
  for (int n = 0; n < 4; ++n) {
    int d = n * 16 + ql;
    vbase[n] = d * 1024;
    vsw[n]   = ((d & 7) ^ ((d >> 3) & 7)) << 4;
  }

  #pragma unroll
  for (int ri = 0; ri < 4; ++ri) {
    int r0_ = (ri == 0) ? wid : (ri == 1) ? (15 - wid) : (ri == 2) ? (16 + wid) : (31 - wid);
    const int rs = __builtin_amdgcn_readfirstlane(r0_);
    const int i0 = rs * 16;

    const int qrow = i0 + ql;
    const int qsw  = (qrow & 7) << 4;
    bf16x8 qf0 = *(const bf16x8*)(kSb + ((qrow * 128      + g * 16) ^ qsw));
    bf16x8 qf1 = *(const bf16x8*)(kSb + ((qrow * 128 + 64 + g * 16) ^ qsw));

    // ---- pass 1: chunk totals tt -> register prefix cbA[kt]; S1 = total ----
    float cbA[32];
    float running = 0.f;
    #pragma unroll
    for (int kt = 0; kt < 32; ++kt) {
      if (kt <= rs) {
        const bool dg = (kt == rs);
        const int krow = kt * 16 + ql;
        const int ksw  = (krow & 7) << 4;
        bf16x8 ka0 = *(const bf16x8*)(kSb + ((krow * 128      + g * 16) ^ ksw));
        bf16x8 ka1 = *(const bf16x8*)(kSb + ((krow * 128 + 64 + g * 16) ^ ksw));
        f32x4 dv = {};
        dv = __builtin_amdgcn_mfma_f32_16x16x32_bf16(ka0, qf0, dv, 0, 0, 0);
        dv = __builtin_amdgcn_mfma_f32_16x16x32_bf16(ka1, qf1, dv, 0, 0, 0);
        float e0 = (!dg || vm[0]) ? expc(dv[0]) : 0.f;
        float e1 = (!dg || vm[1]) ? expc(dv[1]) : 0.f;
        float e2 = (!dg || vm[2]) ? expc(dv[2]) : 0.f;
        float e3 = (!dg || vm[3]) ? expc(dv[3]) : 0.f;
        float L  = (e0 + e1) + (e2 + e3);
        float bq = __shfl_xor(L, 16, 64);
        float s1p = L + bq;
        float cq = __shfl_xor(s1p, 32, 64);
        cbA[kt] = running;
        running += s1p + cq;
      } else cbA[kt] = 0.f;
    }
    const float S1   = running;                 // per-q-row total (uniform over g)
    const float inv1 = (S1 > 0.f) ? (1.f / S1) : 0.f;

    // ---- pass 2: chain-free streamed recompute -> rescore -> PV ----
    f32x4 oacc[4] = {};
    float S2l = 0.f;
    const float qlf = (float)(i0 + ql);

    auto subkt = [&](int kt, bool dg, u32& wA, u32& wB) {
      const int krow = kt * 16 + ql;
      const int ksw  = (krow & 7) << 4;
      bf16x8 ka0 = *(const bf16x8*)(kSb + ((krow * 128      + g * 16) ^ ksw));
      bf16x8 ka1 = *(const bf16x8*)(kSb + ((krow * 128 + 64 + g * 16) ^ ksw));
      f32x4 dv = {};
      dv = __builtin_amdgcn_mfma_f32_16x16x32_bf16(ka0, qf0, dv, 0, 0, 0);
      dv = __builtin_amdgcn_mfma_f32_16x16x32_bf16(ka1, qf1, dv, 0, 0, 0);
      const bool v0 = !dg || vm[0], v1 = !dg || vm[1];
      const bool v2 = !dg || vm[2], v3 = !dg || vm[3];
      float e0 = v0 ? expc(dv[0]) : 0.f;
      float e1 = v1 ? expc(dv[1]) : 0.f;
      float e2 = v2 ? expc(dv[2]) : 0.f;
      float e3 = v3 ? expc(dv[3]) : 0.f;
      float p0 = e0, p1 = p0 + e1, p2 = p1 + e2, p3 = p2 + e3;
      float bq = __shfl_xor(p3, 16, 64);
      float s1p = p3 + bq;
      float cq = __shfl_xor(s1p, 32, 64);
      float gp = ((g & 1) ? bq : 0.f) + ((g & 2) ? cq : 0.f);
      const float pbase = cbA[kt] + gp;
      const float pf = qlf - (float)(kt * 16 + 4 * g);
      float ipr[4] = {p0, p1, p2, p3};
      bool  vv[4]  = {v0, v1, v2, v3};
      float sv[4]  = {dv[0], dv[1], dv[2], dv[3]};
      float q2[4];
      #pragma unroll
      for (int rg = 0; rg < 4; ++rg) {
        float rem  = fmaxf((S1 - (pbase + ipr[rg])) * inv1, 0.f);
        float pos  = pf - (float)rg;
        float dist = sqrtf(fmaxf(rem * pos, 0.f));
        float eff  = fmaxf(__expf(gamma * dist), 1e-5f);
        float ee   = vv[rg] ? expc(sv[rg] * eff) : 0.f;
        q2[rg] = ee;
        S2l += ee;
      }
      wA = packbf2(q2[0], q2[1]);
      wB = packbf2(q2[2], q2[3]);
    };

    #pragma unroll
    for (int c = 0; c < 16; ++c) {
      if (2 * c <= rs) {
        u32 w0 = 0, w1 = 0, w2 = 0, w3 = 0;
        subkt(2 * c, (2 * c == rs), w0, w1);
        if (2 * c + 1 <= rs) subkt(2 * c + 1, (2 * c + 1 == rs), w2, w3);
        *(u32*)(pB + ((ql * 64 +      8 * g    ) ^ swp)) = w0;
        *(u32*)(pB + ((ql * 64 +      8 * g + 4) ^ swp)) = w1;
        *(u32*)(pB + ((ql * 64 + 32 + 8 * g    ) ^ swp)) = w2;
        *(u32*)(pB + ((ql * 64 + 32 + 8 * g + 4) ^ swp)) = w3;
        bf16x8 pa = *(const bf16x8*)(pB + ((ql * 64 + 16 * g) ^ swp));
        #pragma unroll
        for (int n = 0; n < 4; ++n) {
          bf16x8 vb = *(const bf16x8*)(vTb + vbase[n] + ((64 * c + 16 * g) ^ vsw[n]));
          oacc[n] = __builtin_amdgcn_mfma_f32_16x16x32_bf16(pa, vb, oacc[n], 0, 0, 0);
        }
      }
    }

    const float S2   = redsum2(S2l);
    const float inv2 = 1.f / fmaxf(S2, 1e-30f);
    float i2[4];
    #pragma unroll
    for (int rg = 0; rg < 4; ++rg) i2[rg] = __shfl(inv2, 4 * g + rg, 64);

    #pragma unroll
    for (int n = 0; n < 4; ++n) {
      #pragma unroll
      for (int rg = 0; rg < 4; ++rg) {
        const int qo = i0 + 4 * g + rg;
        float val = oacc[n][rg] * i2[rg];
        if (zero_pad && qo == 0) val = 0.f;
        out[base + (size_t)qo * DDIM + n * 16 + ql] = pack1bf(val);
      }
    }
  }
}

// ---------- fused residual + LayerNorm: out = LN(a_bf16 + b [+ c]) ----------
__global__ __launch_bounds__(256) void ln_kernel(
    const u16* __restrict__ a, const float* __restrict__ bsrc,
    const float* __restrict__ csrc,
    const float* __restrict__ g, const float* __restrict__ be,
    float* __restrict__ outF, u16* __restrict__ outB)
{
  const int lane = threadIdx.x & 63, w = threadIdx.x >> 6;
  const size_t row = (size_t)blockIdx.x * 4 + w;
  const size_t off8 = row * DDIM + lane * 8;

  uint4 ab = *(const uint4*)(a + off8);
  const u16* ap = (const u16*)&ab;
  float v[8];
  #pragma unroll
  for (int k = 0; k < 8; ++k) v[k] = __uint_as_float(((u32)ap[k]) << 16);

  float4 b0 = *(const float4*)(bsrc + off8);
  float4 b1 = *(const float4*)(bsrc + off8 + 4);
  v[0] += b0.x; v[1] += b0.y; v[2] += b0.z; v[3] += b0.w;
  v[4] += b1.x; v[5] += b1.y; v[6] += b1.z; v[7] += b1.w;
  if (csrc) {
    float4 c0 = *(const float4*)(csrc + off8);
    float4 c1 = *(const float4*)(csrc + off8 + 4);
    v[0] += c0.x; v[1] += c0.y; v[2] += c0.z; v[3] += c0.w;
    v[4] += c1.x; v[5] += c1.y; v[6] += c1.z; v[7] += c1.w;
  }

  float sum = 0.f;
  #pragma unroll
  for (int k = 0; k < 8; ++k) sum += v[k];
  #pragma unroll
  for (int off = 32; off > 0; off >>= 1) sum += __shfl_xor(sum, off, 64);
  const float mean = sum * (1.f / 512.f);
  float var = 0.f;
  #pragma unroll
  for (int k = 0; k < 8; ++k) { float dd = v[k] - mean; var = fmaf(dd, dd, var); }
  #pragma unroll
  for (int off = 32; off > 0; off >>= 1) var += __shfl_xor(var, off, 64);
  var *= (1.f / 512.f);
  const float inv = rsqrtf(var + 1e-5f);

  float4 g0 = *(const float4*)(g + lane * 8);
  float4 g1 = *(const float4*)(g + lane * 8 + 4);
  float4 e0 = *(const float4*)(be + lane * 8);
  float4 e1 = *(const float4*)(be + lane * 8 + 4);
  float gv[8] = {g0.x, g0.y, g0.z, g0.w, g1.x, g1.y, g1.z, g1.w};
  float ev[8] = {e0.x, e0.y, e0.z, e0.w, e1.x, e1.y, e1.z, e1.w};
  float o[8];
  #pragma unroll
  for (int k = 0; k < 8; ++k) o[k] = (v[k] - mean) * inv * gv[k] + ev[k];

  if (outF) {
    float4 f0 = {o[0], o[1], o[2], o[3]};
    float4 f1 = {o[4], o[5], o[6], o[7]};
    *(float4*)(outF + off8)     = f0;
    *(float4*)(outF + off8 + 4) = f1;
  }
  if (outB) {
    uint4 p;
    p.x = packbf2(o[0], o[1]); p.y = packbf2(o[2], o[3]);
    p.z = packbf2(o[4], o[5]); p.w = packbf2(o[6], o[7]);
    *(uint4*)(outB + off8) = p;
  }
}

// ---------- orchestration ----------
extern "C" void kernel_launch(void* const* d_in, const int* in_sizes, int n_in,
                              void* d_out, int out_size, void* d_ws, size_t ws_size,
                              hipStream_t stream) {
  const float* qe  = (const float*)d_in[0];
  const float* qa  = (const float*)d_in[1];
  const float* Wk  = (const float*)d_in[2];
  const float* bk  = (const float*)d_in[3];
  const float* Wv  = (const float*)d_in[4];
  const float* bv  = (const float*)d_in[5];
  const float* Wo  = (const float*)d_in[6];
  const float* bo  = (const float*)d_in[7];
  const float* gm  = (const float*)d_in[8];
  const float* l1g = (const float*)d_in[9];
  const float* l1b = (const float*)d_in[10];
  const float* W1  = (const float*)d_in[11];
  const float* b1  = (const float*)d_in[12];
  const float* W2  = (const float*)d_in[13];
  const float* b2  = (const float*)d_in[14];
  const float* l2g = (const float*)d_in[15];
  const float* l2b = (const float*)d_in[16];

  char* ws = (char*)d_ws;
  u16* WT = (u16*)ws;                              // 17.3 MB packed weights
  u16* A0 = (u16*)(ws + ((size_t)18  << 20));      // 16 MiB bf16 act slots
  u16* A1 = (u16*)(ws + ((size_t)34  << 20));
  u16* A2 = (u16*)(ws + ((size_t)50  << 20));
  u16* A3 = (u16*)(ws + ((size_t)66  << 20));
  float* F0 = (float*)(ws + ((size_t)82  << 20));  // 32 MiB f32 GEMM-out slot
  float* PW2 = (float*)(ws + ((size_t)114 << 20)); // 32 MiB W2 split-K partial
  u16* Amid = (u16*)(ws + ((size_t)146 << 20));    // 64 MiB FFN mid
  float* PWo = (float*)Amid;                        // Wo split-K partial (disjoint lifetime)

  u16* WkT = WT;                    // [L][512][512]
  u16* WvT = WT + (size_t)3 * 262144;
  u16* WoT = WT + (size_t)6 * 262144;
  u16* W1T = WT + (size_t)9 * 262144;              // [L][2048][512]
  u16* W2T = W1T + (size_t)3 * 1048576;            // [L][512][2048]

  pack_w_t<<<dim3(8, 8, 3),  256, 0, stream>>>(Wk, WkT, 512, 512);
  pack_w_t<<<dim3(8, 8, 3),  256, 0, stream>>>(Wv, WvT, 512, 512);
  pack_w_t<<<dim3(8, 8, 3),  256, 0, stream>>>(Wo, WoT, 512, 512);
  pack_w_t<<<dim3(32, 8, 3), 256, 0, stream>>>(W1, W1T, 512, 2048);
  pack_w_t<<<dim3(8, 32, 3), 256, 0, stream>>>(W2, W2T, 2048, 512);
  pack_flat<<<4096, 256, 0, stream>>>(qa, A0);
  pack_flat<<<4096, 256, 0, stream>>>(qe, A1);

  const float SQ = 0.35355339059327373f;  // sqrt(1/8): folds attn scale into QK proj

  auto g8 = [&](const u16* Aa, const u16* Ab, int lda,
                const u16* Ba, const u16* Bb, int ldb,
                const float* ba, const float* bb,
                float* oFa, float* oFb, u16* oBa, u16* oBb,
                int ldc, int M, int N, int Kz, int relu, int nz,
                float sca, float scb) {
    gemm8<<<dim3(N / 256, M / 256, nz), 512, 0, stream>>>(
        Aa, Ab, lda, Ba, Bb, ldb, ba, bb, oFa, oFb, oBa, oBb, ldc, Kz, relu,
        sca, scb);
  };

  auto layer = [&](int li, const u16* qbf, const u16* vbf,
                   int excl, int zp, int pos,
                   u16* x1B, u16* y2B, float* y2F) {
    const float* bk_l = bk + (size_t)li * DDIM;
    const float* bv_l = bv + (size_t)li * DDIM;
    const float* bo_l = bo + (size_t)li * DDIM;
    const float* gm_l = gm + (size_t)li * HH;
    const float* g1   = l1g + (size_t)li * DDIM;
    const float* be1  = l1b + (size_t)li * DDIM;
    const float* g2   = l2g + (size_t)li * DDIM;
    const float* be2  = l2b + (size_t)li * DDIM;
    const float* b1_l = b1 + (size_t)li * DFFN;
    const float* b2_l = b2 + (size_t)li * DDIM;
    const u16* WkT_l = WkT + (size_t)li * 262144;
    const u16* WvT_l = WvT + (size_t)li * 262144;
    const u16* WoT_l = WoT + (size_t)li * 262144;
    const u16* W1T_l = W1T + (size_t)li * 1048576;
    const u16* W2T_l = W2T + (size_t)li * 1048576;

    // fused qk + v projections (z-batched); QK pre-scaled by sqrt(1/8)
    g8(qbf, vbf, 512, WkT_l, WvT_l, 512, bk_l, bv_l,
       nullptr, nullptr, A2, A3, 512, MR, 512, 512, 0, 2, SQ, 1.f);
    attn_mfma<<<BB * HH, 512, 0, stream>>>(A2, A3, gm_l, A3, excl, zp);
    // Wo: split-K (z0: k<256 +bias -> F0; z1: k>=256 -> PWo)
    g8(A3, A3 + 256, 512, WoT_l, WoT_l + 256, 512, bo_l, nullptr,
       F0, PWo, nullptr, nullptr, 512, MR, 512, 256, 0, 2, 1.f, 1.f);
    ln_kernel<<<MR / 4, 256, 0, stream>>>(qbf, F0, PWo, g1, be1, nullptr, x1B);
    if (pos) {
      g8(x1B, nullptr, 512, W1T_l, nullptr, 512, b1_l, nullptr,
         nullptr, nullptr, Amid, nullptr, 2048, MR, 2048, 512, 1, 1, 1.f, 1.f);
      g8(Amid, Amid + 1024, 2048, W2T_l, W2T_l + 1024, 2048, b2_l, nullptr,
         F0, PW2, nullptr, nullptr, 512, MR, 512, 1024, 0, 2, 1.f, 1.f);
      ln_kernel<<<MR / 4, 256, 0, stream>>>(x1B, F0, PW2, g2, be2, y2F, y2B);
    }
  };

  // layer 0: self-attn on qa, incl mask, FFN -> y1 bf16 in A0
  layer(0, A0, A0, 0, 0, 1, A2, A0, nullptr);
  // layer 1: self-attn on qe, incl mask, no FFN -> x1 bf16 in A1 (in-place LN)
  layer(1, A1, A1, 0, 0, 0, A1, nullptr, nullptr);
  // layer 2: cross-attn (q = x1, values = y1), strict mask, zero_pad, FFN -> d_out f32
  layer(2, A1, A0, 1, 1, 1, A1, nullptr, (float*)d_out);
}

// Round 12
// 656.519 us; speedup vs baseline: 1.0972x; 1.0972x over previous
//
#include <hip/hip_runtime.h>

#define BB   32
#define SS   512
#define DDIM 512
#define HH   8
#define DFFN 2048
#define MR   (BB*SS)   // 16384 rows

typedef unsigned int   u32;
typedef unsigned short u16;
typedef unsigned char  u8;
typedef __attribute__((ext_vector_type(8))) short bf16x8;
typedef __attribute__((ext_vector_type(4))) float f32x4;

// ---------- bf16 helpers ----------
__device__ __forceinline__ u32 packbf2(float x, float y) {
  u32 ux = __float_as_uint(x), uy = __float_as_uint(y);
  u32 hx = (ux + 0x7FFFu + ((ux >> 16) & 1u)) >> 16;
  u32 hy = (uy + 0x7FFFu + ((uy >> 16) & 1u)) >> 16;
  return hx | (hy << 16);
}
__device__ __forceinline__ u16 pack1bf(float x) {
  u32 u = __float_as_uint(x);
  return (u16)((u + 0x7FFFu + ((u >> 16) & 1u)) >> 16);
}

__device__ __forceinline__ float redsum2(float v) {
  v += __shfl_xor(v, 16, 64);
  v += __shfl_xor(v, 32, 64);
  return v;
}

// exp2-domain softmax (scores prescaled by log2e via the GEMM epilogue):
// clamped exp2 (2^110 * 512 < f32 max) and raw exp2 (arg <= 0 paths).
#if __has_builtin(__builtin_amdgcn_exp2f)
__device__ __forceinline__ float ex2c(float x) { return __builtin_amdgcn_exp2f(fminf(x, 110.f)); }
__device__ __forceinline__ float ex2r(float x) { return __builtin_amdgcn_exp2f(x); }
#else
__device__ __forceinline__ float ex2c(float x) {
  float r = fminf(x, 110.f);
  asm("v_exp_f32 %0, %1" : "=v"(r) : "v"(r));
  return r;
}
__device__ __forceinline__ float ex2r(float x) {
  float r;
  asm("v_exp_f32 %0, %1" : "=v"(r) : "v"(x));
  return r;
}
#endif

// ---------- flat f32 -> bf16 pack (dual input via blockIdx.y) ----------
__global__ __launch_bounds__(256) void pack_flat2(
    const float* __restrict__ in0, const float* __restrict__ in1,
    u16* __restrict__ out0, u16* __restrict__ out1) {
  const float* in = blockIdx.y ? in1 : in0;
  u16* out = blockIdx.y ? out1 : out0;
  size_t i = ((size_t)blockIdx.x * 256 + threadIdx.x) * 8;
  float4 a = *(const float4*)(in + i);
  float4 b = *(const float4*)(in + i + 4);
  uint4 o;
  o.x = packbf2(a.x, a.y); o.y = packbf2(a.z, a.w);
  o.z = packbf2(b.x, b.y); o.w = packbf2(b.z, b.w);
  *(uint4*)(out + i) = o;
}

// ---------- weight transpose-pack: f32 [K,N] -> bf16 [N,K] ----------
__device__ __forceinline__ void wtp_body(const float* __restrict__ in,
                                         u16* __restrict__ out, int K, int N,
                                         int bx, int by) {
  __shared__ float tile[64][65];
  const int t  = threadIdx.x;
  const int n0 = bx * 64, k0 = by * 64;
  #pragma unroll
  for (int it = 0; it < 4; ++it) {
    int idx = it * 256 + t;
    int kk = idx >> 4, n4 = idx & 15;
    float4 v = *(const float4*)(in + (size_t)(k0 + kk) * N + n0 + n4 * 4);
    tile[kk][n4*4+0] = v.x; tile[kk][n4*4+1] = v.y;
    tile[kk][n4*4+2] = v.z; tile[kk][n4*4+3] = v.w;
  }
  __syncthreads();
  #pragma unroll
  for (int it = 0; it < 4; ++it) {
    int idx = it * 256 + t;
    int nn = idx >> 4, g = idx & 15;
    uint2 o;
    o.x = packbf2(tile[g*4+0][nn], tile[g*4+1][nn]);
    o.y = packbf2(tile[g*4+2][nn], tile[g*4+3][nn]);
    *(uint2*)(out + (size_t)(n0 + nn) * K + k0 + g * 4) = o;
  }
}
__global__ __launch_bounds__(256) void pack_w_t(const float* __restrict__ in,
                                                u16* __restrict__ out, int K, int N) {
  wtp_body(in + (size_t)blockIdx.z * K * N, out + (size_t)blockIdx.z * N * K,
           K, N, blockIdx.x, blockIdx.y);
}
// all nine 512x512 weights in one dispatch: z = which*3 + layer
__global__ __launch_bounds__(256) void pack_w_sq(
    const float* __restrict__ Wk, const float* __restrict__ Wv,
    const float* __restrict__ Wo,
    u16* __restrict__ WkT, u16* __restrict__ WvT, u16* __restrict__ WoT) {
  const int z = blockIdx.z, which = z / 3, li = z % 3;
  const float* in = (which == 0 ? Wk : which == 1 ? Wv : Wo) + (size_t)li * 262144;
  u16* out = (which == 0 ? WkT : which == 1 ? WvT : WoT) + (size_t)li * 262144;
  wtp_body(in, out, 512, 512, blockIdx.x, blockIdx.y);
}

// ---------- 256x256 8-phase bf16 MFMA GEMM (job-array, proper tail) ----------
struct GJob { const u16* A; const u16* Bt; const float* bias;
              float* outF; u16* outB; float sc; };
struct GJobs { GJob j[4]; };

__global__ __launch_bounds__(512, 2) void gemm8(
    GJobs jobs, int lda, int ldb, int ldc, int Kz, int relu)
{
  __shared__ __align__(16) u8 lds[131072];

  const GJob J = jobs.j[blockIdx.z];
  const u16* A    = J.A;
  const u16* Bt   = J.Bt;
  const float* bias = J.bias;
  float* outF = J.outF;
  u16*   outB = J.outB;
  const float sc = J.sc;

  const int nwg  = gridDim.x * gridDim.y;
  const int orig = blockIdx.y * gridDim.x + blockIdx.x;
  const int q8   = nwg >> 3, r8 = nwg & 7;
  const int xcd  = orig & 7, idx8 = orig >> 3;
  const int wg   = (xcd < r8 ? xcd * (q8 + 1) : r8 * (q8 + 1) + (xcd - r8) * q8) + idx8;
  const int bx   = wg % gridDim.x, by = wg / gridDim.x;
  const int row0 = by * 256, col0 = bx * 256;

  const int t    = threadIdx.x;
  const int lane = t & 63, wid = t >> 6;
  const int wm   = wid >> 2, wn = wid & 3;
  const int rl   = lane & 15, kg = lane >> 4;

  const int NT = Kz >> 6;   // >= 4, even

  f32x4 acc[8][4] = {};

  auto stageA = [&](int buf, int h, int kt) {
    #pragma unroll
    for (int l = 0; l < 2; ++l) {
      int s  = (l * 512 + t) >> 3;
      int kb = ((lane & 7) * 16) ^ ((s & 7) << 4);
      int row = row0 + ((s >> 6) * 128) + h * 64 + (s & 63);
      const u8* src = (const u8*)A + (size_t)row * lda * 2 + (size_t)kt * 128 + kb;
      u8* dst = lds + buf * 65536 + h * 16384 + (l * 512 + wid * 64) * 16;
      __builtin_amdgcn_global_load_lds(
          (const __attribute__((address_space(1))) u32*)src,
          (__attribute__((address_space(3))) u32*)dst, 16, 0, 0);
    }
  };
  auto stageB = [&](int buf, int h, int kt) {
    #pragma unroll
    for (int l = 0; l < 2; ++l) {
      int s  = (l * 512 + t) >> 3;
      int kb = ((lane & 7) * 16) ^ ((s & 7) << 4);
      int col = col0 + ((s >> 5) * 64) + h * 32 + (s & 31);
      const u8* src = (const u8*)Bt + (size_t)col * ldb * 2 + (size_t)kt * 128 + kb;
      u8* dst = lds + buf * 65536 + 32768 + h * 16384 + (l * 512 + wid * 64) * 16;
      __builtin_amdgcn_global_load_lds(
          (const __attribute__((address_space(1))) u32*)src,
          (__attribute__((address_space(3))) u32*)dst, 16, 0, 0);
    }
  };

  auto rdA = [&](int buf, int mh, int m, int ks) -> bf16x8 {
    int s = wm * 64 + m * 16 + rl;
    int off = buf * 65536 + mh * 16384 + s * 128 + (((ks * 32 + kg * 8) * 2) ^ ((s & 7) << 4));
    return *(const bf16x8*)(lds + off);
  };
  auto rdB = [&](int buf, int nh, int n, int ks) -> bf16x8 {
    int s = wn * 32 + n * 16 + rl;
    int off = buf * 65536 + 32768 + nh * 16384 + s * 128 + (((ks * 32 + kg * 8) * 2) ^ ((s & 7) << 4));
    return *(const bf16x8*)(lds + off);
  };

#define GBAR asm volatile("s_barrier" ::: "memory")
#define VMW4 asm volatile("s_waitcnt vmcnt(4)" ::: "memory")
#define VMW0 asm volatile("s_waitcnt vmcnt(0)" ::: "memory")

#define PHASE(BUF, MH, NH, STAGECODE, DOVM) do {                               \
    bf16x8 af_[4][2], bf_[2][2];                                               \
    _Pragma("unroll") for (int m_ = 0; m_ < 4; ++m_)                           \
      _Pragma("unroll") for (int k_ = 0; k_ < 2; ++k_)                         \
        af_[m_][k_] = rdA(BUF, MH, m_, k_);                                    \
    _Pragma("unroll") for (int n_ = 0; n_ < 2; ++n_)                           \
      _Pragma("unroll") for (int k_ = 0; k_ < 2; ++k_)                         \
        bf_[n_][k_] = rdB(BUF, NH, n_, k_);                                    \
    STAGECODE;                                                                 \
    if (DOVM == 1) VMW4;                                                       \
    if (DOVM == 2) VMW0;                                                       \
    GBAR;                                                                      \
    __builtin_amdgcn_s_setprio(1);                                             \
    _Pragma("unroll") for (int m_ = 0; m_ < 4; ++m_)                           \
      _Pragma("unroll") for (int n_ = 0; n_ < 2; ++n_) {                       \
        acc[(MH)*4+m_][(NH)*2+n_] = __builtin_amdgcn_mfma_f32_16x16x32_bf16(   \
            af_[m_][0], bf_[n_][0], acc[(MH)*4+m_][(NH)*2+n_], 0, 0, 0);       \
        acc[(MH)*4+m_][(NH)*2+n_] = __builtin_amdgcn_mfma_f32_16x16x32_bf16(   \
            af_[m_][1], bf_[n_][1], acc[(MH)*4+m_][(NH)*2+n_], 0, 0, 0);       \
      }                                                                        \
    __builtin_amdgcn_s_setprio(0);                                             \
    GBAR;                                                                      \
  } while (0)

  // prologue: tile0 fully + tile1's A0,B0
  stageA(0, 0, 0); stageB(0, 0, 0); stageA(0, 1, 0); stageB(0, 1, 0);
  stageA(1, 0, 1); stageB(1, 0, 1);
  VMW4; GBAR;

  // full iterations (no wraps): i <= NT/2-2 keeps T3 = 2i+3 <= NT-1
  for (int i = 0; i < (NT >> 1) - 1; ++i) {
    const int T1 = 2 * i + 1, T2 = 2 * i + 2, T3 = 2 * i + 3;
    PHASE(0, 0, 0, stageA(1, 1, T1), 0);
    PHASE(0, 0, 1, stageB(1, 1, T1), 0);
    PHASE(0, 1, 0, stageA(0, 0, T2), 0);
    PHASE(0, 1, 1, stageB(0, 0, T2), 1);
    PHASE(1, 0, 0, stageA(0, 1, T2), 0);
    PHASE(1, 0, 1, stageB(0, 1, T2), 0);
    PHASE(1, 1, 0, stageA(1, 0, T3), 0);
    PHASE(1, 1, 1, stageB(1, 0, T3), 1);
  }
  // tail: only tile NT-1's A1,B1 remain to stage; drain at phase 4
  PHASE(0, 0, 0, stageA(1, 1, NT - 1), 0);
  PHASE(0, 0, 1, stageB(1, 1, NT - 1), 0);
  PHASE(0, 1, 0, ;, 0);
  PHASE(0, 1, 1, ;, 2);
  PHASE(1, 0, 0, ;, 0);
  PHASE(1, 0, 1, ;, 0);
  PHASE(1, 1, 0, ;, 0);
  PHASE(1, 1, 1, ;, 0);
#undef PHASE
#undef GBAR
#undef VMW4
#undef VMW0

  #pragma unroll
  for (int M = 0; M < 8; ++M) {
    #pragma unroll
    for (int N2 = 0; N2 < 4; ++N2) {
      const int col = col0 + wn * 64 + N2 * 16 + rl;
      const float bs = bias ? bias[col] : 0.f;
      #pragma unroll
      for (int q = 0; q < 4; ++q) {
        const int row = row0 + wm * 128 + M * 16 + kg * 4 + q;
        float v = (acc[M][N2][q] + bs) * sc;
        if (relu) v = fmaxf(v, 0.f);
        if (outF) outF[(size_t)row * ldc + col] = v;
        if (outB) outB[(size_t)row * ldc + col] = pack1bf(v);
      }
    }
  }
}

// ---------- MFMA attention, 2-pass streamed, exp2-domain, dual-layer batched ----------
// Scores arrive pre-scaled by log2e/8 (via SQ2 on BOTH q and k in the proj
// epilogue), so every exp is a single v_exp_f32 (exp2). gamma pre-multiplied
// by log2e. r10 carried-cumsum core (no cbA spill).
__global__ __attribute__((amdgpu_flat_work_group_size(512, 512)))
           __attribute__((amdgpu_waves_per_eu(1, 2)))
void attn_mfma(
    const u16* __restrict__ qkA, const u16* __restrict__ vbA,
    const float* __restrict__ gmA, u16* __restrict__ outAp,
    const u16* __restrict__ qkB, const u16* __restrict__ vbB,
    const float* __restrict__ gmB, u16* __restrict__ outBp,
    int nA, int mask_excl, int zero_pad)
{
  __shared__ __align__(16) u8 kSb[65536];  // K/Q rows [512][64] bf16, byte ^= (row&7)<<4
  __shared__ __align__(16) u8 vTb[65536];  // V^T [64 d][512 k] bf16, u32 ^= ((d&7)^(d>>3))<<4
  __shared__ __align__(16) u8 pChb[8192];  // per-wave 1KB P chunk buffers

  const int t    = threadIdx.x;
  const int lane = t & 63, wid = t >> 6;
  const int ql   = lane & 15, g = lane >> 4;
  const int bid  = blockIdx.x;
  const int sel  = bid >= nA;
  const u16* qk    = sel ? qkB : qkA;
  const u16* vbuf  = sel ? vbB : vbA;
  const float* gam = sel ? gmB : gmA;
  u16* out         = sel ? outBp : outAp;
  const int bh = sel ? bid - nA : bid;
  const int b = bh >> 3, h = bh & 7;
  const size_t base = (size_t)b * SS * DDIM + (size_t)h * 64;

  float gv = gam[h];
  float sp = (gv > 0.f) ? (gv + log1pf(__expf(-gv))) : log1pf(__expf(gv));
  const float gamma2 = -sp * 1.442695041f;   // exp2-domain gamma

  // ---- stage K/Q (pre-scaled) ----
  for (int it = 0; it < 8; ++it) {
    int idx = it * 512 + t;
    int j = idx >> 3, u = idx & 7;
    uint4 w = *(const uint4*)(qk + base + (size_t)j * DDIM + u * 8);
    *(uint4*)(kSb + ((j * 128 + u * 16) ^ ((j & 7) << 4))) = w;
  }
  // ---- stage V^T: row-pair loads, packed u32 writes ----
  for (int it = 0; it < 4; ++it) {
    int idx = it * 512 + t;
    int jp = idx >> 3, u = idx & 7;
    const u16* src = vbuf + base + (size_t)(2 * jp) * DDIM + u * 8;
    uint4 r0 = *(const uint4*)src;
    uint4 r1 = *(const uint4*)(src + DDIM);
    const u16* a0 = (const u16*)&r0;
    const u16* a1 = (const u16*)&r1;
    #pragma unroll
    for (int dd = 0; dd < 8; ++dd) {
      int d = u * 8 + dd;
      u32 w = (u32)a0[dd] | ((u32)a1[dd] << 16);
      *(u32*)(vTb + d * 1024 + ((4 * jp) ^ ((dd ^ u) << 4))) = w;
    }
  }
  __syncthreads();

  bool vm[4];
  #pragma unroll
  for (int rg = 0; rg < 4; ++rg) {
    int kl = 4 * g + rg;
    vm[rg] = mask_excl ? (kl < ql) : (kl <= ql);
  }

  u8* pB = pChb + wid * 1024;
  const int swp = (ql & 7) << 4;

  int vbase[4], vsw[4];
  #pragma unroll
  for (int n = 0; n < 4; ++n) {
    int d = n * 16 + ql;
    vbase[n] = d * 1024;
    vsw[n]   = ((d & 7) ^ ((d >> 3) & 7)) << 4;
  }

  #pragma unroll
  for (int ri = 0; ri < 4; ++ri) {
    int r0_ = (ri == 0) ? wid : (ri == 1) ? (15 - wid) : (ri == 2) ? (16 + wid) : (31 - wid);
    const int rs = __builtin_amdgcn_readfirstlane(r0_);
    const int i0 = rs * 16;

    const int qrow = i0 + ql;
    const int qsw  = (qrow & 7) << 4;
    bf16x8 qf0 = *(const bf16x8*)(kSb + ((qrow * 128      + g * 16) ^ qsw));
    bf16x8 qf1 = *(const bf16x8*)(kSb + ((qrow * 128 + 64 + g * 16) ^ qsw));

    // ---- pass 1: S1 only ----
    float S1l = 0.f;
    #pragma unroll
    for (int kt = 0; kt < 32; ++kt) {
      if (kt <= rs) {
        const bool dg = (kt == rs);
        const int krow = kt * 16 + ql;
        const int ksw  = (krow & 7) << 4;
        bf16x8 ka0 = *(const bf16x8*)(kSb + ((krow * 128      + g * 16) ^ ksw));
        bf16x8 ka1 = *(const bf16x8*)(kSb + ((krow * 128 + 64 + g * 16) ^ ksw));
        f32x4 dv = {};
        dv = __builtin_amdgcn_mfma_f32_16x16x32_bf16(ka0, qf0, dv, 0, 0, 0);
        dv = __builtin_amdgcn_mfma_f32_16x16x32_bf16(ka1, qf1, dv, 0, 0, 0);
        float e0 = (!dg || vm[0]) ? ex2c(dv[0]) : 0.f;
        float e1 = (!dg || vm[1]) ? ex2c(dv[1]) : 0.f;
        float e2 = (!dg || vm[2]) ? ex2c(dv[2]) : 0.f;
        float e3 = (!dg || vm[3]) ? ex2c(dv[3]) : 0.f;
        S1l += (e0 + e1) + (e2 + e3);
      }
    }
    const float S1   = redsum2(S1l);
    const float inv1 = (S1 > 0.f) ? (1.f / S1) : 0.f;

    // ---- pass 2: streamed recompute -> cumsum -> rescore -> PV ----
    f32x4 oacc[4] = {};
    float cbase = 0.f, S2l = 0.f;
    const float qlf = (float)(i0 + ql);

    auto subkt = [&](int kt, bool dg, u32& wA, u32& wB) {
      const int krow = kt * 16 + ql;
      const int ksw  = (krow & 7) << 4;
      bf16x8 ka0 = *(const bf16x8*)(kSb + ((krow * 128      + g * 16) ^ ksw));
      bf16x8 ka1 = *(const bf16x8*)(kSb + ((krow * 128 + 64 + g * 16) ^ ksw));
      f32x4 dv = {};
      dv = __builtin_amdgcn_mfma_f32_16x16x32_bf16(ka0, qf0, dv, 0, 0, 0);
      dv = __builtin_amdgcn_mfma_f32_16x16x32_bf16(ka1, qf1, dv, 0, 0, 0);
      const bool v0 = !dg || vm[0], v1 = !dg || vm[1];
      const bool v2 = !dg || vm[2], v3 = !dg || vm[3];
      float e0 = v0 ? ex2c(dv[0]) : 0.f;
      float e1 = v1 ? ex2c(dv[1]) : 0.f;
      float e2 = v2 ? ex2c(dv[2]) : 0.f;
      float e3 = v3 ? ex2c(dv[3]) : 0.f;
      float p0 = e0, p1 = p0 + e1, p2 = p1 + e2, p3 = p2 + e3;
      float a16 = __shfl_up(p3, 16, 64);
      float a32 = __shfl_up(p3, 32, 64);
      float a48 = __shfl_up(p3, 48, 64);
      float gp = (g >= 1 ? a16 : 0.f) + (g >= 2 ? a32 : 0.f) + (g >= 3 ? a48 : 0.f);
      float tt = __shfl(gp + p3, ql + 48, 64);
      const float pbase = cbase + gp;
      const float pf = qlf - (float)(kt * 16 + 4 * g);
      float ipr[4] = {p0, p1, p2, p3};
      bool  vv[4]  = {v0, v1, v2, v3};
      float sv[4]  = {dv[0], dv[1], dv[2], dv[3]};
      float q2[4];
      #pragma unroll
      for (int rg = 0; rg < 4; ++rg) {
        float rem  = fmaxf((S1 - (pbase + ipr[rg])) * inv1, 0.f);
        float pos  = pf - (float)rg;
        float dist = sqrtf(fmaxf(rem * pos, 0.f));
        float eff  = fmaxf(ex2r(gamma2 * dist), 1e-5f);
        float ee   = vv[rg] ? ex2c(sv[rg] * eff) : 0.f;
        q2[rg] = ee;
        S2l += ee;
      }
      wA = packbf2(q2[0], q2[1]);
      wB = packbf2(q2[2], q2[3]);
      cbase += tt;
    };

    #pragma unroll
    for (int c = 0; c < 16; ++c) {
      if (2 * c <= rs) {
        u32 w0 = 0, w1 = 0, w2 = 0, w3 = 0;
        subkt(2 * c, (2 * c == rs), w0, w1);
        if (2 * c + 1 <= rs) subkt(2 * c + 1, (2 * c + 1 == rs), w2, w3);
        *(u32*)(pB + ((ql * 64 +      8 * g    ) ^ swp)) = w0;
        *(u32*)(pB + ((ql * 64 +      8 * g + 4) ^ swp)) = w1;
        *(u32*)(pB + ((ql * 64 + 32 + 8 * g    ) ^ swp)) = w2;
        *(u32*)(pB + ((ql * 64 + 32 + 8 * g + 4) ^ swp)) = w3;
        bf16x8 pa = *(const bf16x8*)(pB + ((ql * 64 + 16 * g) ^ swp));
        #pragma unroll
        for (int n = 0; n < 4; ++n) {
          bf16x8 vb = *(const bf16x8*)(vTb + vbase[n] + ((64 * c + 16 * g) ^ vsw[n]));
          oacc[n] = __builtin_amdgcn_mfma_f32_16x16x32_bf16(pa, vb, oacc[n], 0, 0, 0);
        }
      }
    }

    const float S2   = redsum2(S2l);
    const float inv2 = 1.f / fmaxf(S2, 1e-30f);
    float i2[4];
    #pragma unroll
    for (int rg = 0; rg < 4; ++rg) i2[rg] = __shfl(inv2, 4 * g + rg, 64);

    #pragma unroll
    for (int n = 0; n < 4; ++n) {
      #pragma unroll
      for (int rg = 0; rg < 4; ++rg) {
        const int qo = i0 + 4 * g + rg;
        float val = oacc[n][rg] * i2[rg];
        if (zero_pad && qo == 0) val = 0.f;
        out[base + (size_t)qo * DDIM + n * 16 + ql] = pack1bf(val);
      }
    }
  }
}

// ---------- fused residual + LayerNorm (job-array): out = LN(a_bf16 + b [+ c]) ----------
struct LNJob { const u16* a; const float* b; const float* c;
               const float* g; const float* be; float* outF; u16* outB; };
struct LNJobs { LNJob j[2]; };

__global__ __launch_bounds__(256) void ln_kernel(LNJobs jobs)
{
  const LNJob J = jobs.j[blockIdx.y];
  const int lane = threadIdx.x & 63, w = threadIdx.x >> 6;
  const size_t row = (size_t)blockIdx.x * 4 + w;
  const size_t off8 = row * DDIM + lane * 8;

  uint4 ab = *(const uint4*)(J.a + off8);
  const u16* ap = (const u16*)&ab;
  float v[8];
  #pragma unroll
  for (int k = 0; k < 8; ++k) v[k] = __uint_as_float(((u32)ap[k]) << 16);

  float4 b0 = *(const float4*)(J.b + off8);
  float4 b1 = *(const float4*)(J.b + off8 + 4);
  v[0] += b0.x; v[1] += b0.y; v[2] += b0.z; v[3] += b0.w;
  v[4] += b1.x; v[5] += b1.y; v[6] += b1.z; v[7] += b1.w;
  if (J.c) {
    float4 c0 = *(const float4*)(J.c + off8);
    float4 c1 = *(const float4*)(J.c + off8 + 4);
    v[0] += c0.x; v[1] += c0.y; v[2] += c0.z; v[3] += c0.w;
    v[4] += c1.x; v[5] += c1.y; v[6] += c1.z; v[7] += c1.w;
  }

  float sum = 0.f;
  #pragma unroll
  for (int k = 0; k < 8; ++k) sum += v[k];
  #pragma unroll
  for (int off = 32; off > 0; off >>= 1) sum += __shfl_xor(sum, off, 64);
  const float mean = sum * (1.f / 512.f);
  float var = 0.f;
  #pragma unroll
  for (int k = 0; k < 8; ++k) { float dd = v[k] - mean; var = fmaf(dd, dd, var); }
  #pragma unroll
  for (int off = 32; off > 0; off >>= 1) var += __shfl_xor(var, off, 64);
  var *= (1.f / 512.f);
  const float inv = rsqrtf(var + 1e-5f);

  float4 g0 = *(const float4*)(J.g + lane * 8);
  float4 g1 = *(const float4*)(J.g + lane * 8 + 4);
  float4 e0 = *(const float4*)(J.be + lane * 8);
  float4 e1 = *(const float4*)(J.be + lane * 8 + 4);
  float gv[8] = {g0.x, g0.y, g0.z, g0.w, g1.x, g1.y, g1.z, g1.w};
  float ev[8] = {e0.x, e0.y, e0.z, e0.w, e1.x, e1.y, e1.z, e1.w};
  float o[8];
  #pragma unroll
  for (int k = 0; k < 8; ++k) o[k] = (v[k] - mean) * inv * gv[k] + ev[k];

  if (J.outF) {
    float4 f0 = {o[0], o[1], o[2], o[3]};
    float4 f1 = {o[4], o[5], o[6], o[7]};
    *(float4*)(J.outF + off8)     = f0;
    *(float4*)(J.outF + off8 + 4) = f1;
  }
  if (J.outB) {
    uint4 p;
    p.x = packbf2(o[0], o[1]); p.y = packbf2(o[2], o[3]);
    p.z = packbf2(o[4], o[5]); p.w = packbf2(o[6], o[7]);
    *(uint4*)(J.outB + off8) = p;
  }
}

// ---------- orchestration ----------
extern "C" void kernel_launch(void* const* d_in, const int* in_sizes, int n_in,
                              void* d_out, int out_size, void* d_ws, size_t ws_size,
                              hipStream_t stream) {
  const float* qe  = (const float*)d_in[0];
  const float* qa  = (const float*)d_in[1];
  const float* Wk  = (const float*)d_in[2];
  const float* bk  = (const float*)d_in[3];
  const float* Wv  = (const float*)d_in[4];
  const float* bv  = (const float*)d_in[5];
  const float* Wo  = (const float*)d_in[6];
  const float* bo  = (const float*)d_in[7];
  const float* gm  = (const float*)d_in[8];
  const float* l1g = (const float*)d_in[9];
  const float* l1b = (const float*)d_in[10];
  const float* W1  = (const float*)d_in[11];
  const float* b1  = (const float*)d_in[12];
  const float* W2  = (const float*)d_in[13];
  const float* b2  = (const float*)d_in[14];
  const float* l2g = (const float*)d_in[15];
  const float* l2b = (const float*)d_in[16];

  char* ws = (char*)d_ws;
  // layout (MiB): WT[0,18) A0[18,34) A1[34,50) A2[50,66) A3[66,82) A4[82,98)
  //               A5[98,114) F0a[114,146) X0[146,162) G1[162,194)
  //               Amid aliases [50,114) (A2..A5 dead during FFN)
  u16* WT  = (u16*)ws;
  u16* A0  = (u16*)(ws + ((size_t)18  << 20));
  u16* A1  = (u16*)(ws + ((size_t)34  << 20));
  u16* A2  = (u16*)(ws + ((size_t)50  << 20));
  u16* A3  = (u16*)(ws + ((size_t)66  << 20));
  u16* A4  = (u16*)(ws + ((size_t)82  << 20));
  u16* A5  = (u16*)(ws + ((size_t)98  << 20));
  float* F0a = (float*)(ws + ((size_t)114 << 20));
  u16* X0  = (u16*)(ws + ((size_t)146 << 20));
  float* G1  = (float*)(ws + ((size_t)162 << 20));
  u16* Amid = A2;   // [50,114)

  u16* WkT = WT;                        // [L][512][512]
  u16* WvT = WT + (size_t)3 * 262144;
  u16* WoT = WT + (size_t)6 * 262144;
  u16* W1T = WT + (size_t)9 * 262144;   // [L][2048][512]
  u16* W2T = W1T + (size_t)3 * 1048576; // [L][512][2048]

  pack_w_sq<<<dim3(8, 8, 9),  256, 0, stream>>>(Wk, Wv, Wo, WkT, WvT, WoT);
  pack_w_t<<<dim3(32, 8, 3), 256, 0, stream>>>(W1, W1T, 512, 2048);
  pack_w_t<<<dim3(8, 32, 3), 256, 0, stream>>>(W2, W2T, 2048, 512);
  pack_flat2<<<dim3(4096, 2), 256, 0, stream>>>(qa, qe, A0, A1);

  // exp2-domain QK prescale: sqrt(log2e/8) on both q and k
  const float SQ2 = 0.4246609001f;

  auto g8 = [&](GJobs jobs, int lda, int ldb, int ldc,
                int M, int N, int Kz, int relu, int nz) {
    gemm8<<<dim3(N / 256, M / 256, nz), 512, 0, stream>>>(
        jobs, lda, ldb, ldc, Kz, relu);
  };
  auto ln2x = [&](LNJobs jobs, int nz) {
    ln_kernel<<<dim3(MR / 4, nz), 256, 0, stream>>>(jobs);
  };

  // per-layer param shortcuts
  auto WkT_l = [&](int l){ return WkT + (size_t)l * 262144; };
  auto WvT_l = [&](int l){ return WvT + (size_t)l * 262144; };
  auto WoT_l = [&](int l){ return WoT + (size_t)l * 262144; };
  auto W1T_l = [&](int l){ return W1T + (size_t)l * 1048576; };
  auto W2T_l = [&](int l){ return W2T + (size_t)l * 1048576; };

  // ===== layers 0 & 1 batched (independent pipelines) =====
  {
    GJobs pj = {{ {A0, WkT_l(0), bk,       nullptr, A2, SQ2},
                  {A0, WvT_l(0), bv,       nullptr, A3, 1.f},
                  {A1, WkT_l(1), bk + 512, nullptr, A4, SQ2},
                  {A1, WvT_l(1), bv + 512, nullptr, A5, 1.f} }};
    g8(pj, 512, 512, 512, MR, 512, 512, 0, 4);

    attn_mfma<<<BB * HH * 2, 512, 0, stream>>>(
        A2, A3, gm, A3, A4, A5, gm + HH, A5, BB * HH, 0, 0);

    GJobs wj = {{ {A3, WoT_l(0), bo,       F0a, nullptr, 1.f},
                  {A5, WoT_l(1), bo + 512, G1,  nullptr, 1.f},
                  {}, {} }};
    g8(wj, 512, 512, 512, MR, 512, 512, 0, 2);

    LNJobs lj = {{ {A0, F0a, nullptr, l1g,       l1b,       nullptr, X0},
                   {A1, G1,  nullptr, l1g + 512, l1b + 512, nullptr, A1} }};
    ln2x(lj, 2);
  }
  // ===== layer 0 FFN =====
  {
    GJobs w1j = {{ {X0, W1T_l(0), b1, nullptr, Amid, 1.f}, {}, {}, {} }};
    g8(w1j, 512, 512, 2048, MR, 2048, 512, 1, 1);
    GJobs w2j = {{ {Amid,        W2T_l(0),        b2,      F0a, nullptr, 1.f},
                   {Amid + 1024, W2T_l(0) + 1024, nullptr, G1,  nullptr, 1.f},
                   {}, {} }};
    g8(w2j, 2048, 2048, 512, MR, 512, 1024, 0, 2);
    LNJobs lj = {{ {X0, F0a, G1, l2g, l2b, nullptr, A0}, {} }};   // y1 -> A0
    ln2x(lj, 1);
  }
  // ===== layer 2 (cross-attn: q = x1 in A1, values = y1 in A0) =====
  {
    GJobs pj = {{ {A1, WkT_l(2), bk + 1024, nullptr, A2, SQ2},
                  {A0, WvT_l(2), bv + 1024, nullptr, A3, 1.f},
                  {}, {} }};
    g8(pj, 512, 512, 512, MR, 512, 512, 0, 2);

    attn_mfma<<<BB * HH, 512, 0, stream>>>(
        A2, A3, gm + 2 * HH, A3, A2, A3, gm + 2 * HH, A3, BB * HH, 1, 1);

    GJobs wj = {{ {A3,       WoT_l(2),       bo + 1024, F0a, nullptr, 1.f},
                  {A3 + 256, WoT_l(2) + 256, nullptr,   G1,  nullptr, 1.f},
                  {}, {} }};
    g8(wj, 512, 512, 512, MR, 512, 256, 0, 2);

    LNJobs l1j = {{ {A1, F0a, G1, l1g + 1024, l1b + 1024, nullptr, A1}, {} }};
    ln2x(l1j, 1);

    GJobs w1j = {{ {A1, W1T_l(2), b1 + 2 * DFFN, nullptr, Amid, 1.f}, {}, {}, {} }};
    g8(w1j, 512, 512, 2048, MR, 2048, 512, 1, 1);
    GJobs w2j = {{ {Amid,        W2T_l(2),        b2 + 1024, F0a, nullptr, 1.f},
                   {Amid + 1024, W2T_l(2) + 1024, nullptr,   G1,  nullptr, 1.f},
                   {}, {} }};
    g8(w2j, 2048, 2048, 512, MR, 512, 1024, 0, 2);

    LNJobs l2j = {{ {A1, F0a, G1, l2g + 1024, l2b + 1024, (float*)d_out, nullptr}, {} }};
    ln2x(l2j, 1);
  }
}

// Round 13
// 653.073 us; speedup vs baseline: 1.1030x; 1.0053x over previous
//
#include <hip/hip_runtime.h>

#define BB   32
#define SS   512
#define DDIM 512
#define HH   8
#define DFFN 2048
#define MR   (BB*SS)   // 16384 rows

typedef unsigned int   u32;
typedef unsigned short u16;
typedef unsigned char  u8;
typedef __attribute__((ext_vector_type(8))) short bf16x8;
typedef __attribute__((ext_vector_type(4))) float f32x4;

// ---------- bf16 helpers ----------
__device__ __forceinline__ u32 packbf2(float x, float y) {
  u32 ux = __float_as_uint(x), uy = __float_as_uint(y);
  u32 hx = (ux + 0x7FFFu + ((ux >> 16) & 1u)) >> 16;
  u32 hy = (uy + 0x7FFFu + ((uy >> 16) & 1u)) >> 16;
  return hx | (hy << 16);
}
__device__ __forceinline__ u16 pack1bf(float x) {
  u32 u = __float_as_uint(x);
  return (u16)((u + 0x7FFFu + ((u >> 16) & 1u)) >> 16);
}

__device__ __forceinline__ float redsum2(float v) {
  v += __shfl_xor(v, 16, 64);
  v += __shfl_xor(v, 32, 64);
  return v;
}

// exp2-domain softmax (scores prescaled by log2e via the GEMM epilogue):
// clamped exp2 (2^110 * 512 < f32 max) and raw exp2 (arg <= 0 paths).
#if __has_builtin(__builtin_amdgcn_exp2f)
__device__ __forceinline__ float ex2c(float x) { return __builtin_amdgcn_exp2f(fminf(x, 110.f)); }
__device__ __forceinline__ float ex2r(float x) { return __builtin_amdgcn_exp2f(x); }
#else
__device__ __forceinline__ float ex2c(float x) {
  float r = fminf(x, 110.f);
  asm("v_exp_f32 %0, %1" : "=v"(r) : "v"(r));
  return r;
}
__device__ __forceinline__ float ex2r(float x) {
  float r;
  asm("v_exp_f32 %0, %1" : "=v"(r) : "v"(x));
  return r;
}
#endif

// ---------- flat f32 -> bf16 pack (dual input via blockIdx.y) ----------
__global__ __launch_bounds__(256) void pack_flat2(
    const float* __restrict__ in0, const float* __restrict__ in1,
    u16* __restrict__ out0, u16* __restrict__ out1) {
  const float* in = blockIdx.y ? in1 : in0;
  u16* out = blockIdx.y ? out1 : out0;
  size_t i = ((size_t)blockIdx.x * 256 + threadIdx.x) * 8;
  float4 a = *(const float4*)(in + i);
  float4 b = *(const float4*)(in + i + 4);
  uint4 o;
  o.x = packbf2(a.x, a.y); o.y = packbf2(a.z, a.w);
  o.z = packbf2(b.x, b.y); o.w = packbf2(b.z, b.w);
  *(uint4*)(out + i) = o;
}

// ---------- weight transpose-pack: f32 [K,N] -> bf16 [N,K] ----------
__device__ __forceinline__ void wtp_body(const float* __restrict__ in,
                                         u16* __restrict__ out, int K, int N,
                                         int bx, int by) {
  __shared__ float tile[64][65];
  const int t  = threadIdx.x;
  const int n0 = bx * 64, k0 = by * 64;
  #pragma unroll
  for (int it = 0; it < 4; ++it) {
    int idx = it * 256 + t;
    int kk = idx >> 4, n4 = idx & 15;
    float4 v = *(const float4*)(in + (size_t)(k0 + kk) * N + n0 + n4 * 4);
    tile[kk][n4*4+0] = v.x; tile[kk][n4*4+1] = v.y;
    tile[kk][n4*4+2] = v.z; tile[kk][n4*4+3] = v.w;
  }
  __syncthreads();
  #pragma unroll
  for (int it = 0; it < 4; ++it) {
    int idx = it * 256 + t;
    int nn = idx >> 4, g = idx & 15;
    uint2 o;
    o.x = packbf2(tile[g*4+0][nn], tile[g*4+1][nn]);
    o.y = packbf2(tile[g*4+2][nn], tile[g*4+3][nn]);
    *(uint2*)(out + (size_t)(n0 + nn) * K + k0 + g * 4) = o;
  }
}
__global__ __launch_bounds__(256) void pack_w_t(const float* __restrict__ in,
                                                u16* __restrict__ out, int K, int N) {
  wtp_body(in + (size_t)blockIdx.z * K * N, out + (size_t)blockIdx.z * N * K,
           K, N, blockIdx.x, blockIdx.y);
}
// all nine 512x512 weights in one dispatch: z = which*3 + layer
__global__ __launch_bounds__(256) void pack_w_sq(
    const float* __restrict__ Wk, const float* __restrict__ Wv,
    const float* __restrict__ Wo,
    u16* __restrict__ WkT, u16* __restrict__ WvT, u16* __restrict__ WoT) {
  const int z = blockIdx.z, which = z / 3, li = z % 3;
  const float* in = (which == 0 ? Wk : which == 1 ? Wv : Wo) + (size_t)li * 262144;
  u16* out = (which == 0 ? WkT : which == 1 ? WvT : WoT) + (size_t)li * 262144;
  wtp_body(in, out, 512, 512, blockIdx.x, blockIdx.y);
}

// ---------- 256x256 8-phase bf16 MFMA GEMM (job-array, proper tail) ----------
struct GJob { const u16* A; const u16* Bt; const float* bias;
              float* outF; u16* outB; float sc; };
struct GJobs { GJob j[4]; };

__global__ __launch_bounds__(512, 2) void gemm8(
    GJobs jobs, int lda, int ldb, int ldc, int Kz, int relu)
{
  __shared__ __align__(16) u8 lds[131072];

  const GJob J = jobs.j[blockIdx.z];
  const u16* A    = J.A;
  const u16* Bt   = J.Bt;
  const float* bias = J.bias;
  float* outF = J.outF;
  u16*   outB = J.outB;
  const float sc = J.sc;

  const int nwg  = gridDim.x * gridDim.y;
  const int orig = blockIdx.y * gridDim.x + blockIdx.x;
  const int q8   = nwg >> 3, r8 = nwg & 7;
  const int xcd  = orig & 7, idx8 = orig >> 3;
  const int wg   = (xcd < r8 ? xcd * (q8 + 1) : r8 * (q8 + 1) + (xcd - r8) * q8) + idx8;
  const int bx   = wg % gridDim.x, by = wg / gridDim.x;
  const int row0 = by * 256, col0 = bx * 256;

  const int t    = threadIdx.x;
  const int lane = t & 63, wid = t >> 6;
  const int wm   = wid >> 2, wn = wid & 3;
  const int rl   = lane & 15, kg = lane >> 4;

  const int NT = Kz >> 6;   // >= 4, even

  f32x4 acc[8][4] = {};

  auto stageA = [&](int buf, int h, int kt) {
    #pragma unroll
    for (int l = 0; l < 2; ++l) {
      int s  = (l * 512 + t) >> 3;
      int kb = ((lane & 7) * 16) ^ ((s & 7) << 4);
      int row = row0 + ((s >> 6) * 128) + h * 64 + (s & 63);
      const u8* src = (const u8*)A + (size_t)row * lda * 2 + (size_t)kt * 128 + kb;
      u8* dst = lds + buf * 65536 + h * 16384 + (l * 512 + wid * 64) * 16;
      __builtin_amdgcn_global_load_lds(
          (const __attribute__((address_space(1))) u32*)src,
          (__attribute__((address_space(3))) u32*)dst, 16, 0, 0);
    }
  };
  auto stageB = [&](int buf, int h, int kt) {
    #pragma unroll
    for (int l = 0; l < 2; ++l) {
      int s  = (l * 512 + t) >> 3;
      int kb = ((lane & 7) * 16) ^ ((s & 7) << 4);
      int col = col0 + ((s >> 5) * 64) + h * 32 + (s & 31);
      const u8* src = (const u8*)Bt + (size_t)col * ldb * 2 + (size_t)kt * 128 + kb;
      u8* dst = lds + buf * 65536 + 32768 + h * 16384 + (l * 512 + wid * 64) * 16;
      __builtin_amdgcn_global_load_lds(
          (const __attribute__((address_space(1))) u32*)src,
          (__attribute__((address_space(3))) u32*)dst, 16, 0, 0);
    }
  };

  auto rdA = [&](int buf, int mh, int m, int ks) -> bf16x8 {
    int s = wm * 64 + m * 16 + rl;
    int off = buf * 65536 + mh * 16384 + s * 128 + (((ks * 32 + kg * 8) * 2) ^ ((s & 7) << 4));
    return *(const bf16x8*)(lds + off);
  };
  auto rdB = [&](int buf, int nh, int n, int ks) -> bf16x8 {
    int s = wn * 32 + n * 16 + rl;
    int off = buf * 65536 + 32768 + nh * 16384 + s * 128 + (((ks * 32 + kg * 8) * 2) ^ ((s & 7) << 4));
    return *(const bf16x8*)(lds + off);
  };

#define GBAR asm volatile("s_barrier" ::: "memory")
#define VMW4 asm volatile("s_waitcnt vmcnt(4)" ::: "memory")
#define VMW0 asm volatile("s_waitcnt vmcnt(0)" ::: "memory")

#define PHASE(BUF, MH, NH, STAGECODE, DOVM) do {                               \
    bf16x8 af_[4][2], bf_[2][2];                                               \
    _Pragma("unroll") for (int m_ = 0; m_ < 4; ++m_)                           \
      _Pragma("unroll") for (int k_ = 0; k_ < 2; ++k_)                         \
        af_[m_][k_] = rdA(BUF, MH, m_, k_);                                    \
    _Pragma("unroll") for (int n_ = 0; n_ < 2; ++n_)                           \
      _Pragma("unroll") for (int k_ = 0; k_ < 2; ++k_)                         \
        bf_[n_][k_] = rdB(BUF, NH, n_, k_);                                    \
    STAGECODE;                                                                 \
    if (DOVM == 1) VMW4;                                                       \
    if (DOVM == 2) VMW0;                                                       \
    GBAR;                                                                      \
    __builtin_amdgcn_s_setprio(1);                                             \
    _Pragma("unroll") for (int m_ = 0; m_ < 4; ++m_)                           \
      _Pragma("unroll") for (int n_ = 0; n_ < 2; ++n_) {                       \
        acc[(MH)*4+m_][(NH)*2+n_] = __builtin_amdgcn_mfma_f32_16x16x32_bf16(   \
            af_[m_][0], bf_[n_][0], acc[(MH)*4+m_][(NH)*2+n_], 0, 0, 0);       \
        acc[(MH)*4+m_][(NH)*2+n_] = __builtin_amdgcn_mfma_f32_16x16x32_bf16(   \
            af_[m_][1], bf_[n_][1], acc[(MH)*4+m_][(NH)*2+n_], 0, 0, 0);       \
      }                                                                        \
    __builtin_amdgcn_s_setprio(0);                                             \
    GBAR;                                                                      \
  } while (0)

  // prologue: tile0 fully + tile1's A0,B0
  stageA(0, 0, 0); stageB(0, 0, 0); stageA(0, 1, 0); stageB(0, 1, 0);
  stageA(1, 0, 1); stageB(1, 0, 1);
  VMW4; GBAR;

  // full iterations (no wraps)
  for (int i = 0; i < (NT >> 1) - 1; ++i) {
    const int T1 = 2 * i + 1, T2 = 2 * i + 2, T3 = 2 * i + 3;
    PHASE(0, 0, 0, stageA(1, 1, T1), 0);
    PHASE(0, 0, 1, stageB(1, 1, T1), 0);
    PHASE(0, 1, 0, stageA(0, 0, T2), 0);
    PHASE(0, 1, 1, stageB(0, 0, T2), 1);
    PHASE(1, 0, 0, stageA(0, 1, T2), 0);
    PHASE(1, 0, 1, stageB(0, 1, T2), 0);
    PHASE(1, 1, 0, stageA(1, 0, T3), 0);
    PHASE(1, 1, 1, stageB(1, 0, T3), 1);
  }
  // tail: only tile NT-1's A1,B1 remain to stage; drain at phase 4
  PHASE(0, 0, 0, stageA(1, 1, NT - 1), 0);
  PHASE(0, 0, 1, stageB(1, 1, NT - 1), 0);
  PHASE(0, 1, 0, ;, 0);
  PHASE(0, 1, 1, ;, 2);
  PHASE(1, 0, 0, ;, 0);
  PHASE(1, 0, 1, ;, 0);
  PHASE(1, 1, 0, ;, 0);
  PHASE(1, 1, 1, ;, 0);
#undef PHASE
#undef GBAR
#undef VMW4
#undef VMW0

  #pragma unroll
  for (int M = 0; M < 8; ++M) {
    #pragma unroll
    for (int N2 = 0; N2 < 4; ++N2) {
      const int col = col0 + wn * 64 + N2 * 16 + rl;
      const float bs = bias ? bias[col] : 0.f;
      #pragma unroll
      for (int q = 0; q < 4; ++q) {
        const int row = row0 + wm * 128 + M * 16 + kg * 4 + q;
        float v = (acc[M][N2][q] + bs) * sc;
        if (relu) v = fmaxf(v, 0.f);
        if (outF) outF[(size_t)row * ldc + col] = v;
        if (outB) outB[(size_t)row * ldc + col] = pack1bf(v);
      }
    }
  }
}

// ---------- MFMA attention, 2-pass streamed, exp2-domain, dual-layer batched ----------
__global__ __attribute__((amdgpu_flat_work_group_size(512, 512)))
           __attribute__((amdgpu_waves_per_eu(1, 2)))
void attn_mfma(
    const u16* __restrict__ qkA, const u16* __restrict__ vbA,
    const float* __restrict__ gmA, u16* __restrict__ outAp,
    const u16* __restrict__ qkB, const u16* __restrict__ vbB,
    const float* __restrict__ gmB, u16* __restrict__ outBp,
    int nA, int mask_excl, int zero_pad)
{
  __shared__ __align__(16) u8 kSb[65536];  // K/Q rows [512][64] bf16, byte ^= (row&7)<<4
  __shared__ __align__(16) u8 vTb[65536];  // V^T [64 d][512 k] bf16, u32 ^= ((d&7)^(d>>3))<<4
  __shared__ __align__(16) u8 pChb[8192];  // per-wave 1KB P chunk buffers

  const int t    = threadIdx.x;
  const int lane = t & 63, wid = t >> 6;
  const int ql   = lane & 15, g = lane >> 4;
  const int bid  = blockIdx.x;
  const int sel  = bid >= nA;
  const u16* qk    = sel ? qkB : qkA;
  const u16* vbuf  = sel ? vbB : vbA;
  const float* gam = sel ? gmB : gmA;
  u16* out         = sel ? outBp : outAp;
  const int bh = sel ? bid - nA : bid;
  const int b = bh >> 3, h = bh & 7;
  const size_t base = (size_t)b * SS * DDIM + (size_t)h * 64;

  float gv = gam[h];
  float sp = (gv > 0.f) ? (gv + log1pf(__expf(-gv))) : log1pf(__expf(gv));
  const float gamma2 = -sp * 1.442695041f;   // exp2-domain gamma

  // ---- stage K/Q (pre-scaled) ----
  for (int it = 0; it < 8; ++it) {
    int idx = it * 512 + t;
    int j = idx >> 3, u = idx & 7;
    uint4 w = *(const uint4*)(qk + base + (size_t)j * DDIM + u * 8);
    *(uint4*)(kSb + ((j * 128 + u * 16) ^ ((j & 7) << 4))) = w;
  }
  // ---- stage V^T: row-pair loads, packed u32 writes ----
  for (int it = 0; it < 4; ++it) {
    int idx = it * 512 + t;
    int jp = idx >> 3, u = idx & 7;
    const u16* src = vbuf + base + (size_t)(2 * jp) * DDIM + u * 8;
    uint4 r0 = *(const uint4*)src;
    uint4 r1 = *(const uint4*)(src + DDIM);
    const u16* a0 = (const u16*)&r0;
    const u16* a1 = (const u16*)&r1;
    #pragma unroll
    for (int dd = 0; dd < 8; ++dd) {
      int d = u * 8 + dd;
      u32 w = (u32)a0[dd] | ((u32)a1[dd] << 16);
      *(u32*)(vTb + d * 1024 + ((4 * jp) ^ ((dd ^ u) << 4))) = w;
    }
  }
  __syncthreads();

  bool vm[4];
  #pragma unroll
  for (int rg = 0; rg < 4; ++rg) {
    int kl = 4 * g + rg;
    vm[rg] = mask_excl ? (kl < ql) : (kl <= ql);
  }

  u8* pB = pChb + wid * 1024;
  const int swp = (ql & 7) << 4;

  int vbase[4], vsw[4];
  #pragma unroll
  for (int n = 0; n < 4; ++n) {
    int d = n * 16 + ql;
    vbase[n] = d * 1024;
    vsw[n]   = ((d & 7) ^ ((d >> 3) & 7)) << 4;
  }

  #pragma unroll
  for (int ri = 0; ri < 4; ++ri) {
    int r0_ = (ri == 0) ? wid : (ri == 1) ? (15 - wid) : (ri == 2) ? (16 + wid) : (31 - wid);
    const int rs = __builtin_amdgcn_readfirstlane(r0_);
    const int i0 = rs * 16;

    const int qrow = i0 + ql;
    const int qsw  = (qrow & 7) << 4;
    bf16x8 qf0 = *(const bf16x8*)(kSb + ((qrow * 128      + g * 16) ^ qsw));
    bf16x8 qf1 = *(const bf16x8*)(kSb + ((qrow * 128 + 64 + g * 16) ^ qsw));

    // ---- pass 1: S1 only ----
    float S1l = 0.f;
    #pragma unroll
    for (int kt = 0; kt < 32; ++kt) {
      if (kt <= rs) {
        const bool dg = (kt == rs);
        const int krow = kt * 16 + ql;
        const int ksw  = (krow & 7) << 4;
        bf16x8 ka0 = *(const bf16x8*)(kSb + ((krow * 128      + g * 16) ^ ksw));
        bf16x8 ka1 = *(const bf16x8*)(kSb + ((krow * 128 + 64 + g * 16) ^ ksw));
        f32x4 dv = {};
        dv = __builtin_amdgcn_mfma_f32_16x16x32_bf16(ka0, qf0, dv, 0, 0, 0);
        dv = __builtin_amdgcn_mfma_f32_16x16x32_bf16(ka1, qf1, dv, 0, 0, 0);
        float e0 = (!dg || vm[0]) ? ex2c(dv[0]) : 0.f;
        float e1 = (!dg || vm[1]) ? ex2c(dv[1]) : 0.f;
        float e2 = (!dg || vm[2]) ? ex2c(dv[2]) : 0.f;
        float e3 = (!dg || vm[3]) ? ex2c(dv[3]) : 0.f;
        S1l += (e0 + e1) + (e2 + e3);
      }
    }
    const float S1   = redsum2(S1l);
    const float inv1 = (S1 > 0.f) ? (1.f / S1) : 0.f;

    // ---- pass 2: streamed recompute -> butterfly cumsum -> rescore -> PV ----
    f32x4 oacc[4] = {};
    float cbase = 0.f, S2l = 0.f;
    const float qlf = (float)(i0 + ql);

    auto subkt = [&](int kt, bool dg, u32& wA, u32& wB) {
      const int krow = kt * 16 + ql;
      const int ksw  = (krow & 7) << 4;
      bf16x8 ka0 = *(const bf16x8*)(kSb + ((krow * 128      + g * 16) ^ ksw));
      bf16x8 ka1 = *(const bf16x8*)(kSb + ((krow * 128 + 64 + g * 16) ^ ksw));
      f32x4 dv = {};
      dv = __builtin_amdgcn_mfma_f32_16x16x32_bf16(ka0, qf0, dv, 0, 0, 0);
      dv = __builtin_amdgcn_mfma_f32_16x16x32_bf16(ka1, qf1, dv, 0, 0, 0);
      const bool v0 = !dg || vm[0], v1 = !dg || vm[1];
      const bool v2 = !dg || vm[2], v3 = !dg || vm[3];
      float e0 = v0 ? ex2c(dv[0]) : 0.f;
      float e1 = v1 ? ex2c(dv[1]) : 0.f;
      float e2 = v2 ? ex2c(dv[2]) : 0.f;
      float e3 = v3 ? ex2c(dv[3]) : 0.f;
      float p0 = e0, p1 = p0 + e1, p2 = p1 + e2, p3 = p2 + e3;
      // butterfly group-scan over g (2 shfl_xor; tt uniform, no broadcast)
      float bq  = __shfl_xor(p3, 16, 64);       // partner pair value
      float s1p = p3 + bq;                      // pair sum
      float cq  = __shfl_xor(s1p, 32, 64);      // other pair's sum
      float gp  = ((g & 1) ? bq : 0.f) + ((g & 2) ? cq : 0.f);
      float tt  = s1p + cq;                     // chunk total (uniform over g)
      const float pbase = cbase + gp;
      const float pf = qlf - (float)(kt * 16 + 4 * g);
      float ipr[4] = {p0, p1, p2, p3};
      bool  vv[4]  = {v0, v1, v2, v3};
      float sv[4]  = {dv[0], dv[1], dv[2], dv[3]};
      float q2[4];
      #pragma unroll
      for (int rg = 0; rg < 4; ++rg) {
        float rem  = fmaxf((S1 - (pbase + ipr[rg])) * inv1, 0.f);
        float pos  = pf - (float)rg;            // >= 0 for all unmasked elems
        float dist = sqrtf(rem * pos);          // masked lanes: NaN -> gated to 0
        float eff  = fmaxf(ex2r(gamma2 * dist), 1e-5f);
        float ee   = vv[rg] ? ex2c(sv[rg] * eff) : 0.f;
        q2[rg] = ee;
        S2l += ee;
      }
      wA = packbf2(q2[0], q2[1]);
      wB = packbf2(q2[2], q2[3]);
      cbase += tt;
    };

    #pragma unroll
    for (int c = 0; c < 16; ++c) {
      if (2 * c <= rs) {
        u32 w0 = 0, w1 = 0, w2 = 0, w3 = 0;
        subkt(2 * c, (2 * c == rs), w0, w1);
        if (2 * c + 1 <= rs) subkt(2 * c + 1, (2 * c + 1 == rs), w2, w3);
        *(u32*)(pB + ((ql * 64 +      8 * g    ) ^ swp)) = w0;
        *(u32*)(pB + ((ql * 64 +      8 * g + 4) ^ swp)) = w1;
        *(u32*)(pB + ((ql * 64 + 32 + 8 * g    ) ^ swp)) = w2;
        *(u32*)(pB + ((ql * 64 + 32 + 8 * g + 4) ^ swp)) = w3;
        bf16x8 pa = *(const bf16x8*)(pB + ((ql * 64 + 16 * g) ^ swp));
        #pragma unroll
        for (int n = 0; n < 4; ++n) {
          bf16x8 vb = *(const bf16x8*)(vTb + vbase[n] + ((64 * c + 16 * g) ^ vsw[n]));
          oacc[n] = __builtin_amdgcn_mfma_f32_16x16x32_bf16(pa, vb, oacc[n], 0, 0, 0);
        }
      }
    }

    const float S2   = redsum2(S2l);
    const float inv2 = 1.f / fmaxf(S2, 1e-30f);
    float i2[4];
    #pragma unroll
    for (int rg = 0; rg < 4; ++rg) i2[rg] = __shfl(inv2, 4 * g + rg, 64);

    #pragma unroll
    for (int n = 0; n < 4; ++n) {
      #pragma unroll
      for (int rg = 0; rg < 4; ++rg) {
        const int qo = i0 + 4 * g + rg;
        float val = oacc[n][rg] * i2[rg];
        if (zero_pad && qo == 0) val = 0.f;
        out[base + (size_t)qo * DDIM + n * 16 + ql] = pack1bf(val);
      }
    }
  }
}

// ---------- fused residual + LayerNorm (job-array): out = LN(a + b [+ c]), all bf16 in ----------
struct LNJob { const u16* a; const u16* b; const u16* c;
               const float* g; const float* be; float* outF; u16* outB; };
struct LNJobs { LNJob j[2]; };

__global__ __launch_bounds__(256) void ln_kernel(LNJobs jobs)
{
  const LNJob J = jobs.j[blockIdx.y];
  const int lane = threadIdx.x & 63, w = threadIdx.x >> 6;
  const size_t row = (size_t)blockIdx.x * 4 + w;
  const size_t off8 = row * DDIM + lane * 8;

  uint4 ab = *(const uint4*)(J.a + off8);
  uint4 bb = *(const uint4*)(J.b + off8);
  const u16* ap = (const u16*)&ab;
  const u16* bp = (const u16*)&bb;
  float v[8];
  #pragma unroll
  for (int k = 0; k < 8; ++k)
    v[k] = __uint_as_float(((u32)ap[k]) << 16) + __uint_as_float(((u32)bp[k]) << 16);
  if (J.c) {
    uint4 cb = *(const uint4*)(J.c + off8);
    const u16* cp = (const u16*)&cb;
    #pragma unroll
    for (int k = 0; k < 8; ++k) v[k] += __uint_as_float(((u32)cp[k]) << 16);
  }

  float sum = 0.f;
  #pragma unroll
  for (int k = 0; k < 8; ++k) sum += v[k];
  #pragma unroll
  for (int off = 32; off > 0; off >>= 1) sum += __shfl_xor(sum, off, 64);
  const float mean = sum * (1.f / 512.f);
  float var = 0.f;
  #pragma unroll
  for (int k = 0; k < 8; ++k) { float dd = v[k] - mean; var = fmaf(dd, dd, var); }
  #pragma unroll
  for (int off = 32; off > 0; off >>= 1) var += __shfl_xor(var, off, 64);
  var *= (1.f / 512.f);
  const float inv = rsqrtf(var + 1e-5f);

  float4 g0 = *(const float4*)(J.g + lane * 8);
  float4 g1 = *(const float4*)(J.g + lane * 8 + 4);
  float4 e0 = *(const float4*)(J.be + lane * 8);
  float4 e1 = *(const float4*)(J.be + lane * 8 + 4);
  float gv[8] = {g0.x, g0.y, g0.z, g0.w, g1.x, g1.y, g1.z, g1.w};
  float ev[8] = {e0.x, e0.y, e0.z, e0.w, e1.x, e1.y, e1.z, e1.w};
  float o[8];
  #pragma unroll
  for (int k = 0; k < 8; ++k) o[k] = (v[k] - mean) * inv * gv[k] + ev[k];

  if (J.outF) {
    float4 f0 = {o[0], o[1], o[2], o[3]};
    float4 f1 = {o[4], o[5], o[6], o[7]};
    *(float4*)(J.outF + off8)     = f0;
    *(float4*)(J.outF + off8 + 4) = f1;
  }
  if (J.outB) {
    uint4 p;
    p.x = packbf2(o[0], o[1]); p.y = packbf2(o[2], o[3]);
    p.z = packbf2(o[4], o[5]); p.w = packbf2(o[6], o[7]);
    *(uint4*)(J.outB + off8) = p;
  }
}

// ---------- orchestration ----------
extern "C" void kernel_launch(void* const* d_in, const int* in_sizes, int n_in,
                              void* d_out, int out_size, void* d_ws, size_t ws_size,
                              hipStream_t stream) {
  const float* qe  = (const float*)d_in[0];
  const float* qa  = (const float*)d_in[1];
  const float* Wk  = (const float*)d_in[2];
  const float* bk  = (const float*)d_in[3];
  const float* Wv  = (const float*)d_in[4];
  const float* bv  = (const float*)d_in[5];
  const float* Wo  = (const float*)d_in[6];
  const float* bo  = (const float*)d_in[7];
  const float* gm  = (const float*)d_in[8];
  const float* l1g = (const float*)d_in[9];
  const float* l1b = (const float*)d_in[10];
  const float* W1  = (const float*)d_in[11];
  const float* b1  = (const float*)d_in[12];
  const float* W2  = (const float*)d_in[13];
  const float* b2  = (const float*)d_in[14];
  const float* l2g = (const float*)d_in[15];
  const float* l2b = (const float*)d_in[16];

  char* ws = (char*)d_ws;
  // layout (MiB): WT[0,18) A0[18,34) A1[34,50) A2[50,66) A3[66,82) A4[82,98)
  //               A5[98,114) B0[114,130) B1[130,146) X0[146,162)
  //               Amid aliases [50,114) (A2..A5 dead during FFN)
  u16* WT  = (u16*)ws;
  u16* A0  = (u16*)(ws + ((size_t)18  << 20));
  u16* A1  = (u16*)(ws + ((size_t)34  << 20));
  u16* A2  = (u16*)(ws + ((size_t)50  << 20));
  u16* A3  = (u16*)(ws + ((size_t)66  << 20));
  u16* A4  = (u16*)(ws + ((size_t)82  << 20));
  u16* A5  = (u16*)(ws + ((size_t)98  << 20));
  u16* B0  = (u16*)(ws + ((size_t)114 << 20));   // bf16 GEMM-out slot
  u16* B1  = (u16*)(ws + ((size_t)130 << 20));   // bf16 partial slot
  u16* X0  = (u16*)(ws + ((size_t)146 << 20));
  u16* Amid = A2;   // [50,114)

  u16* WkT = WT;                        // [L][512][512]
  u16* WvT = WT + (size_t)3 * 262144;
  u16* WoT = WT + (size_t)6 * 262144;
  u16* W1T = WT + (size_t)9 * 262144;   // [L][2048][512]
  u16* W2T = W1T + (size_t)3 * 1048576; // [L][512][2048]

  pack_w_sq<<<dim3(8, 8, 9),  256, 0, stream>>>(Wk, Wv, Wo, WkT, WvT, WoT);
  pack_w_t<<<dim3(32, 8, 3), 256, 0, stream>>>(W1, W1T, 512, 2048);
  pack_w_t<<<dim3(8, 32, 3), 256, 0, stream>>>(W2, W2T, 2048, 512);
  pack_flat2<<<dim3(4096, 2), 256, 0, stream>>>(qa, qe, A0, A1);

  // exp2-domain QK prescale: sqrt(log2e/8) on both q and k
  const float SQ2 = 0.4246609001f;

  auto g8 = [&](GJobs jobs, int lda, int ldb, int ldc,
                int M, int N, int Kz, int relu, int nz) {
    gemm8<<<dim3(N / 256, M / 256, nz), 512, 0, stream>>>(
        jobs, lda, ldb, ldc, Kz, relu);
  };
  auto ln2x = [&](LNJobs jobs, int nz) {
    ln_kernel<<<dim3(MR / 4, nz), 256, 0, stream>>>(jobs);
  };

  auto WkT_l = [&](int l){ return WkT + (size_t)l * 262144; };
  auto WvT_l = [&](int l){ return WvT + (size_t)l * 262144; };
  auto WoT_l = [&](int l){ return WoT + (size_t)l * 262144; };
  auto W1T_l = [&](int l){ return W1T + (size_t)l * 1048576; };
  auto W2T_l = [&](int l){ return W2T + (size_t)l * 1048576; };

  // ===== layers 0 & 1 batched (independent pipelines) =====
  {
    GJobs pj = {{ {A0, WkT_l(0), bk,       nullptr, A2, SQ2},
                  {A0, WvT_l(0), bv,       nullptr, A3, 1.f},
                  {A1, WkT_l(1), bk + 512, nullptr, A4, SQ2},
                  {A1, WvT_l(1), bv + 512, nullptr, A5, 1.f} }};
    g8(pj, 512, 512, 512, MR, 512, 512, 0, 4);

    attn_mfma<<<BB * HH * 2, 512, 0, stream>>>(
        A2, A3, gm, A3, A4, A5, gm + HH, A5, BB * HH, 0, 0);

    GJobs wj = {{ {A3, WoT_l(0), bo,       nullptr, B0, 1.f},
                  {A5, WoT_l(1), bo + 512, nullptr, B1, 1.f},
                  {}, {} }};
    g8(wj, 512, 512, 512, MR, 512, 512, 0, 2);

    LNJobs lj = {{ {A0, B0, nullptr, l1g,       l1b,       nullptr, X0},
                   {A1, B1, nullptr, l1g + 512, l1b + 512, nullptr, A1} }};
    ln2x(lj, 2);
  }
  // ===== layer 0 FFN =====
  {
    GJobs w1j = {{ {X0, W1T_l(0), b1, nullptr, Amid, 1.f}, {}, {}, {} }};
    g8(w1j, 512, 512, 2048, MR, 2048, 512, 1, 1);
    GJobs w2j = {{ {Amid,        W2T_l(0),        b2,      nullptr, B0, 1.f},
                   {Amid + 1024, W2T_l(0) + 1024, nullptr, nullptr, B1, 1.f},
                   {}, {} }};
    g8(w2j, 2048, 2048, 512, MR, 512, 1024, 0, 2);
    LNJobs lj = {{ {X0, B0, B1, l2g, l2b, nullptr, A0}, {} }};   // y1 -> A0
    ln2x(lj, 1);
  }
  // ===== layer 2 (cross-attn: q = x1 in A1, values = y1 in A0) =====
  {
    GJobs pj = {{ {A1, WkT_l(2), bk + 1024, nullptr, A2, SQ2},
                  {A0, WvT_l(2), bv + 1024, nullptr, A3, 1.f},
                  {}, {} }};
    g8(pj, 512, 512, 512, MR, 512, 512, 0, 2);

    attn_mfma<<<BB * HH, 512, 0, stream>>>(
        A2, A3, gm + 2 * HH, A3, A2, A3, gm + 2 * HH, A3, BB * HH, 1, 1);

    GJobs wj = {{ {A3,       WoT_l(2),       bo + 1024, nullptr, B0, 1.f},
                  {A3 + 256, WoT_l(2) + 256, nullptr,   nullptr, B1, 1.f},
                  {}, {} }};
    g8(wj, 512, 512, 512, MR, 512, 256, 0, 2);

    LNJobs l1j = {{ {A1, B0, B1, l1g + 1024, l1b + 1024, nullptr, A1}, {} }};
    ln2x(l1j, 1);

    GJobs w1j = {{ {A1, W1T_l(2), b1 + 2 * DFFN, nullptr, Amid, 1.f}, {}, {}, {} }};
    g8(w1j, 512, 512, 2048, MR, 2048, 512, 1, 1);
    GJobs w2j = {{ {Amid,        W2T_l(2),        b2 + 1024, nullptr, B0, 1.f},
                   {Amid + 1024, W2T_l(2) + 1024, nullptr,   nullptr, B1, 1.f},
                   {}, {} }};
    g8(w2j, 2048, 2048, 512, MR, 512, 1024, 0, 2);

    LNJobs l2j = {{ {A1, B0, B1, l2g + 1024, l2b + 1024, (float*)d_out, nullptr}, {} }};
    ln2x(l2j, 1);
  }
}

// Round 14
// 603.720 us; speedup vs baseline: 1.1932x; 1.0817x over previous
//
#include <hip/hip_runtime.h>

#define BB   32
#define SS   512
#define DDIM 512
#define HH   8
#define DFFN 2048
#define MR   (BB*SS)   // 16384 rows

typedef unsigned int   u32;
typedef unsigned short u16;
typedef unsigned char  u8;
typedef __attribute__((ext_vector_type(8))) short bf16x8;
typedef __attribute__((ext_vector_type(4))) float f32x4;

// ---------- bf16 helpers ----------
__device__ __forceinline__ u32 packbf2(float x, float y) {
  u32 ux = __float_as_uint(x), uy = __float_as_uint(y);
  u32 hx = (ux + 0x7FFFu + ((ux >> 16) & 1u)) >> 16;
  u32 hy = (uy + 0x7FFFu + ((uy >> 16) & 1u)) >> 16;
  return hx | (hy << 16);
}
__device__ __forceinline__ u16 pack1bf(float x) {
  u32 u = __float_as_uint(x);
  return (u16)((u + 0x7FFFu + ((u >> 16) & 1u)) >> 16);
}

__device__ __forceinline__ float redsum2(float v) {
  v += __shfl_xor(v, 16, 64);
  v += __shfl_xor(v, 32, 64);
  return v;
}

// exp2-domain softmax (scores prescaled by log2e via the GEMM epilogue):
#if __has_builtin(__builtin_amdgcn_exp2f)
__device__ __forceinline__ float ex2c(float x) { return __builtin_amdgcn_exp2f(fminf(x, 110.f)); }
__device__ __forceinline__ float ex2r(float x) { return __builtin_amdgcn_exp2f(x); }
#else
__device__ __forceinline__ float ex2c(float x) {
  float r = fminf(x, 110.f);
  asm("v_exp_f32 %0, %1" : "=v"(r) : "v"(r));
  return r;
}
__device__ __forceinline__ float ex2r(float x) {
  float r;
  asm("v_exp_f32 %0, %1" : "=v"(r) : "v"(x));
  return r;
}
#endif

// ---------- flat f32 -> bf16 pack (dual input via blockIdx.y) ----------
__global__ __launch_bounds__(256) void pack_flat2(
    const float* __restrict__ in0, const float* __restrict__ in1,
    u16* __restrict__ out0, u16* __restrict__ out1) {
  const float* in = blockIdx.y ? in1 : in0;
  u16* out = blockIdx.y ? out1 : out0;
  size_t i = ((size_t)blockIdx.x * 256 + threadIdx.x) * 8;
  float4 a = *(const float4*)(in + i);
  float4 b = *(const float4*)(in + i + 4);
  uint4 o;
  o.x = packbf2(a.x, a.y); o.y = packbf2(a.z, a.w);
  o.z = packbf2(b.x, b.y); o.w = packbf2(b.z, b.w);
  *(uint4*)(out + i) = o;
}

// ---------- weight transpose-pack: f32 [K,N] -> bf16 [N,K] ----------
__device__ __forceinline__ void wtp_body(const float* __restrict__ in,
                                         u16* __restrict__ out, int K, int N,
                                         int bx, int by) {
  __shared__ float tile[64][65];
  const int t  = threadIdx.x;
  const int n0 = bx * 64, k0 = by * 64;
  #pragma unroll
  for (int it = 0; it < 4; ++it) {
    int idx = it * 256 + t;
    int kk = idx >> 4, n4 = idx & 15;
    float4 v = *(const float4*)(in + (size_t)(k0 + kk) * N + n0 + n4 * 4);
    tile[kk][n4*4+0] = v.x; tile[kk][n4*4+1] = v.y;
    tile[kk][n4*4+2] = v.z; tile[kk][n4*4+3] = v.w;
  }
  __syncthreads();
  #pragma unroll
  for (int it = 0; it < 4; ++it) {
    int idx = it * 256 + t;
    int nn = idx >> 4, g = idx & 15;
    uint2 o;
    o.x = packbf2(tile[g*4+0][nn], tile[g*4+1][nn]);
    o.y = packbf2(tile[g*4+2][nn], tile[g*4+3][nn]);
    *(uint2*)(out + (size_t)(n0 + nn) * K + k0 + g * 4) = o;
  }
}
__global__ __launch_bounds__(256) void pack_w_t(const float* __restrict__ in,
                                                u16* __restrict__ out, int K, int N) {
  wtp_body(in + (size_t)blockIdx.z * K * N, out + (size_t)blockIdx.z * N * K,
           K, N, blockIdx.x, blockIdx.y);
}
__global__ __launch_bounds__(256) void pack_w_sq(
    const float* __restrict__ Wk, const float* __restrict__ Wv,
    const float* __restrict__ Wo,
    u16* __restrict__ WkT, u16* __restrict__ WvT, u16* __restrict__ WoT) {
  const int z = blockIdx.z, which = z / 3, li = z % 3;
  const float* in = (which == 0 ? Wk : which == 1 ? Wv : Wo) + (size_t)li * 262144;
  u16* out = (which == 0 ? WkT : which == 1 ? WvT : WoT) + (size_t)li * 262144;
  wtp_body(in, out, 512, 512, blockIdx.x, blockIdx.y);
}

// ---------- 256x256 8-phase bf16 MFMA GEMM (job-array, proper tail) ----------
struct GJob { const u16* A; const u16* Bt; const float* bias;
              float* outF; u16* outB; float sc; };
struct GJobs { GJob j[4]; };

__global__ __launch_bounds__(512, 2) void gemm8(
    GJobs jobs, int lda, int ldb, int ldc, int Kz, int relu)
{
  __shared__ __align__(16) u8 lds[131072];

  const GJob J = jobs.j[blockIdx.z];
  const u16* A    = J.A;
  const u16* Bt   = J.Bt;
  const float* bias = J.bias;
  float* outF = J.outF;
  u16*   outB = J.outB;
  const float sc = J.sc;

  const int nwg  = gridDim.x * gridDim.y;
  const int orig = blockIdx.y * gridDim.x + blockIdx.x;
  const int q8   = nwg >> 3, r8 = nwg & 7;
  const int xcd  = orig & 7, idx8 = orig >> 3;
  const int wg   = (xcd < r8 ? xcd * (q8 + 1) : r8 * (q8 + 1) + (xcd - r8) * q8) + idx8;
  const int bx   = wg % gridDim.x, by = wg / gridDim.x;
  const int row0 = by * 256, col0 = bx * 256;

  const int t    = threadIdx.x;
  const int lane = t & 63, wid = t >> 6;
  const int wm   = wid >> 2, wn = wid & 3;
  const int rl   = lane & 15, kg = lane >> 4;

  const int NT = Kz >> 6;   // >= 4, even

  f32x4 acc[8][4] = {};

  auto stageA = [&](int buf, int h, int kt) {
    #pragma unroll
    for (int l = 0; l < 2; ++l) {
      int s  = (l * 512 + t) >> 3;
      int kb = ((lane & 7) * 16) ^ ((s & 7) << 4);
      int row = row0 + ((s >> 6) * 128) + h * 64 + (s & 63);
      const u8* src = (const u8*)A + (size_t)row * lda * 2 + (size_t)kt * 128 + kb;
      u8* dst = lds + buf * 65536 + h * 16384 + (l * 512 + wid * 64) * 16;
      __builtin_amdgcn_global_load_lds(
          (const __attribute__((address_space(1))) u32*)src,
          (__attribute__((address_space(3))) u32*)dst, 16, 0, 0);
    }
  };
  auto stageB = [&](int buf, int h, int kt) {
    #pragma unroll
    for (int l = 0; l < 2; ++l) {
      int s  = (l * 512 + t) >> 3;
      int kb = ((lane & 7) * 16) ^ ((s & 7) << 4);
      int col = col0 + ((s >> 5) * 64) + h * 32 + (s & 31);
      const u8* src = (const u8*)Bt + (size_t)col * ldb * 2 + (size_t)kt * 128 + kb;
      u8* dst = lds + buf * 65536 + 32768 + h * 16384 + (l * 512 + wid * 64) * 16;
      __builtin_amdgcn_global_load_lds(
          (const __attribute__((address_space(1))) u32*)src,
          (__attribute__((address_space(3))) u32*)dst, 16, 0, 0);
    }
  };

  auto rdA = [&](int buf, int mh, int m, int ks) -> bf16x8 {
    int s = wm * 64 + m * 16 + rl;
    int off = buf * 65536 + mh * 16384 + s * 128 + (((ks * 32 + kg * 8) * 2) ^ ((s & 7) << 4));
    return *(const bf16x8*)(lds + off);
  };
  auto rdB = [&](int buf, int nh, int n, int ks) -> bf16x8 {
    int s = wn * 32 + n * 16 + rl;
    int off = buf * 65536 + 32768 + nh * 16384 + s * 128 + (((ks * 32 + kg * 8) * 2) ^ ((s & 7) << 4));
    return *(const bf16x8*)(lds + off);
  };

#define GBAR asm volatile("s_barrier" ::: "memory")
#define VMW4 asm volatile("s_waitcnt vmcnt(4)" ::: "memory")
#define VMW0 asm volatile("s_waitcnt vmcnt(0)" ::: "memory")

#define PHASE(BUF, MH, NH, STAGECODE, DOVM) do {                               \
    bf16x8 af_[4][2], bf_[2][2];                                               \
    _Pragma("unroll") for (int m_ = 0; m_ < 4; ++m_)                           \
      _Pragma("unroll") for (int k_ = 0; k_ < 2; ++k_)                         \
        af_[m_][k_] = rdA(BUF, MH, m_, k_);                                    \
    _Pragma("unroll") for (int n_ = 0; n_ < 2; ++n_)                           \
      _Pragma("unroll") for (int k_ = 0; k_ < 2; ++k_)                         \
        bf_[n_][k_] = rdB(BUF, NH, n_, k_);                                    \
    STAGECODE;                                                                 \
    if (DOVM == 1) VMW4;                                                       \
    if (DOVM == 2) VMW0;                                                       \
    GBAR;                                                                      \
    __builtin_amdgcn_s_setprio(1);                                             \
    _Pragma("unroll") for (int m_ = 0; m_ < 4; ++m_)                           \
      _Pragma("unroll") for (int n_ = 0; n_ < 2; ++n_) {                       \
        acc[(MH)*4+m_][(NH)*2+n_] = __builtin_amdgcn_mfma_f32_16x16x32_bf16(   \
            af_[m_][0], bf_[n_][0], acc[(MH)*4+m_][(NH)*2+n_], 0, 0, 0);       \
        acc[(MH)*4+m_][(NH)*2+n_] = __builtin_amdgcn_mfma_f32_16x16x32_bf16(   \
            af_[m_][1], bf_[n_][1], acc[(MH)*4+m_][(NH)*2+n_], 0, 0, 0);       \
      }                                                                        \
    __builtin_amdgcn_s_setprio(0);                                             \
    GBAR;                                                                      \
  } while (0)

  // prologue: tile0 fully + tile1's A0,B0
  stageA(0, 0, 0); stageB(0, 0, 0); stageA(0, 1, 0); stageB(0, 1, 0);
  stageA(1, 0, 1); stageB(1, 0, 1);
  VMW4; GBAR;

  for (int i = 0; i < (NT >> 1) - 1; ++i) {
    const int T1 = 2 * i + 1, T2 = 2 * i + 2, T3 = 2 * i + 3;
    PHASE(0, 0, 0, stageA(1, 1, T1), 0);
    PHASE(0, 0, 1, stageB(1, 1, T1), 0);
    PHASE(0, 1, 0, stageA(0, 0, T2), 0);
    PHASE(0, 1, 1, stageB(0, 0, T2), 1);
    PHASE(1, 0, 0, stageA(0, 1, T2), 0);
    PHASE(1, 0, 1, stageB(0, 1, T2), 0);
    PHASE(1, 1, 0, stageA(1, 0, T3), 0);
    PHASE(1, 1, 1, stageB(1, 0, T3), 1);
  }
  // tail
  PHASE(0, 0, 0, stageA(1, 1, NT - 1), 0);
  PHASE(0, 0, 1, stageB(1, 1, NT - 1), 0);
  PHASE(0, 1, 0, ;, 0);
  PHASE(0, 1, 1, ;, 2);
  PHASE(1, 0, 0, ;, 0);
  PHASE(1, 0, 1, ;, 0);
  PHASE(1, 1, 0, ;, 0);
  PHASE(1, 1, 1, ;, 0);
#undef PHASE
#undef GBAR
#undef VMW4
#undef VMW0

  #pragma unroll
  for (int M = 0; M < 8; ++M) {
    #pragma unroll
    for (int N2 = 0; N2 < 4; ++N2) {
      const int col = col0 + wn * 64 + N2 * 16 + rl;
      const float bs = bias ? bias[col] : 0.f;
      #pragma unroll
      for (int q = 0; q < 4; ++q) {
        const int row = row0 + wm * 128 + M * 16 + kg * 4 + q;
        float v = (acc[M][N2][q] + bs) * sc;
        if (relu) v = fmaxf(v, 0.f);
        if (outF) outF[(size_t)row * ldc + col] = v;
        if (outB) outB[(size_t)row * ldc + col] = pack1bf(v);
      }
    }
  }
}

// ---------- MFMA attention: 1024 threads (16 waves) per (b,h) block ----------
// r13 was stuck at 2 waves/SIMD (136KB LDS, 8 waves, 1 block/CU). Keep the
// LDS-resident K/V design but double TLP: 16 waves/block (144KB LDS incl.
// 16KB pChb, still 1 block/CU) -> 4 waves/SIMD. Wave w owns row-tiles
// {w, 31-w}: cost (w+1)+(32-w)=33 uniform. VGPR 120 fits the 128 budget.
__global__ __attribute__((amdgpu_flat_work_group_size(1024, 1024)))
void attn_mfma(
    const u16* __restrict__ qkA, const u16* __restrict__ vbA,
    const float* __restrict__ gmA, u16* __restrict__ outAp,
    const u16* __restrict__ qkB, const u16* __restrict__ vbB,
    const float* __restrict__ gmB, u16* __restrict__ outBp,
    int nA, int mask_excl, int zero_pad)
{
  __shared__ __align__(16) u8 kSb[65536];   // K/Q rows [512][64] bf16, byte ^= (row&7)<<4
  __shared__ __align__(16) u8 vTb[65536];   // V^T [64 d][512 k] bf16, u32 ^= ((d&7)^(d>>3))<<4
  __shared__ __align__(16) u8 pChb[16384];  // per-wave 1KB P chunk buffers (16 waves)

  const int t    = threadIdx.x;
  const int lane = t & 63, wid = t >> 6;    // wid in 0..15
  const int ql   = lane & 15, g = lane >> 4;
  const int bid  = blockIdx.x;
  const int sel  = bid >= nA;
  const u16* qk    = sel ? qkB : qkA;
  const u16* vbuf  = sel ? vbB : vbA;
  const float* gam = sel ? gmB : gmA;
  u16* out         = sel ? outBp : outAp;
  const int bh = sel ? bid - nA : bid;
  const int b = bh >> 3, h = bh & 7;
  const size_t base = (size_t)b * SS * DDIM + (size_t)h * 64;

  float gv = gam[h];
  float sp = (gv > 0.f) ? (gv + log1pf(__expf(-gv))) : log1pf(__expf(gv));
  const float gamma2 = -sp * 1.442695041f;   // exp2-domain gamma

  // ---- stage K/Q (pre-scaled): 4096 uint4 stores = 4 iters x 1024 thr ----
  for (int it = 0; it < 4; ++it) {
    int idx = it * 1024 + t;
    int j = idx >> 3, u = idx & 7;
    uint4 w = *(const uint4*)(qk + base + (size_t)j * DDIM + u * 8);
    *(uint4*)(kSb + ((j * 128 + u * 16) ^ ((j & 7) << 4))) = w;
  }
  // ---- stage V^T: 2048 row-pair jobs = 2 iters x 1024 thr ----
  for (int it = 0; it < 2; ++it) {
    int idx = it * 1024 + t;
    int jp = idx >> 3, u = idx & 7;
    const u16* src = vbuf + base + (size_t)(2 * jp) * DDIM + u * 8;
    uint4 r0 = *(const uint4*)src;
    uint4 r1 = *(const uint4*)(src + DDIM);
    const u16* a0 = (const u16*)&r0;
    const u16* a1 = (const u16*)&r1;
    #pragma unroll
    for (int dd = 0; dd < 8; ++dd) {
      int d = u * 8 + dd;
      u32 w = (u32)a0[dd] | ((u32)a1[dd] << 16);
      *(u32*)(vTb + d * 1024 + ((4 * jp) ^ ((dd ^ u) << 4))) = w;
    }
  }
  __syncthreads();

  bool vm[4];
  #pragma unroll
  for (int rg = 0; rg < 4; ++rg) {
    int kl = 4 * g + rg;
    vm[rg] = mask_excl ? (kl < ql) : (kl <= ql);
  }

  u8* pB = pChb + wid * 1024;
  const int swp = (ql & 7) << 4;

  int vbase[4], vsw[4];
  #pragma unroll
  for (int n = 0; n < 4; ++n) {
    int d = n * 16 + ql;
    vbase[n] = d * 1024;
    vsw[n]   = ((d & 7) ^ ((d >> 3) & 7)) << 4;
  }

  #pragma unroll
  for (int ri = 0; ri < 2; ++ri) {
    const int rs = __builtin_amdgcn_readfirstlane(ri ? (31 - wid) : wid);
    const int i0 = rs * 16;

    const int qrow = i0 + ql;
    const int qsw  = (qrow & 7) << 4;
    bf16x8 qf0 = *(const bf16x8*)(kSb + ((qrow * 128      + g * 16) ^ qsw));
    bf16x8 qf1 = *(const bf16x8*)(kSb + ((qrow * 128 + 64 + g * 16) ^ qsw));

    // ---- pass 1: S1 only ----
    float S1l = 0.f;
    #pragma unroll
    for (int kt = 0; kt < 32; ++kt) {
      if (kt <= rs) {
        const bool dg = (kt == rs);
        const int krow = kt * 16 + ql;
        const int ksw  = (krow & 7) << 4;
        bf16x8 ka0 = *(const bf16x8*)(kSb + ((krow * 128      + g * 16) ^ ksw));
        bf16x8 ka1 = *(const bf16x8*)(kSb + ((krow * 128 + 64 + g * 16) ^ ksw));
        f32x4 dv = {};
        dv = __builtin_amdgcn_mfma_f32_16x16x32_bf16(ka0, qf0, dv, 0, 0, 0);
        dv = __builtin_amdgcn_mfma_f32_16x16x32_bf16(ka1, qf1, dv, 0, 0, 0);
        float e0 = (!dg || vm[0]) ? ex2c(dv[0]) : 0.f;
        float e1 = (!dg || vm[1]) ? ex2c(dv[1]) : 0.f;
        float e2 = (!dg || vm[2]) ? ex2c(dv[2]) : 0.f;
        float e3 = (!dg || vm[3]) ? ex2c(dv[3]) : 0.f;
        S1l += (e0 + e1) + (e2 + e3);
      }
    }
    const float S1   = redsum2(S1l);
    const float inv1 = (S1 > 0.f) ? (1.f / S1) : 0.f;

    // ---- pass 2: streamed recompute -> butterfly cumsum -> rescore -> PV ----
    f32x4 oacc[4] = {};
    float cbase = 0.f, S2l = 0.f;
    const float qlf = (float)(i0 + ql);

    auto subkt = [&](int kt, bool dg, u32& wA, u32& wB) {
      const int krow = kt * 16 + ql;
      const int ksw  = (krow & 7) << 4;
      bf16x8 ka0 = *(const bf16x8*)(kSb + ((krow * 128      + g * 16) ^ ksw));
      bf16x8 ka1 = *(const bf16x8*)(kSb + ((krow * 128 + 64 + g * 16) ^ ksw));
      f32x4 dv = {};
      dv = __builtin_amdgcn_mfma_f32_16x16x32_bf16(ka0, qf0, dv, 0, 0, 0);
      dv = __builtin_amdgcn_mfma_f32_16x16x32_bf16(ka1, qf1, dv, 0, 0, 0);
      const bool v0 = !dg || vm[0], v1 = !dg || vm[1];
      const bool v2 = !dg || vm[2], v3 = !dg || vm[3];
      float e0 = v0 ? ex2c(dv[0]) : 0.f;
      float e1 = v1 ? ex2c(dv[1]) : 0.f;
      float e2 = v2 ? ex2c(dv[2]) : 0.f;
      float e3 = v3 ? ex2c(dv[3]) : 0.f;
      float p0 = e0, p1 = p0 + e1, p2 = p1 + e2, p3 = p2 + e3;
      float bq  = __shfl_xor(p3, 16, 64);
      float s1p = p3 + bq;
      float cq  = __shfl_xor(s1p, 32, 64);
      float gp  = ((g & 1) ? bq : 0.f) + ((g & 2) ? cq : 0.f);
      float tt  = s1p + cq;
      const float pbase = cbase + gp;
      const float pf = qlf - (float)(kt * 16 + 4 * g);
      float ipr[4] = {p0, p1, p2, p3};
      bool  vv[4]  = {v0, v1, v2, v3};
      float sv[4]  = {dv[0], dv[1], dv[2], dv[3]};
      float q2[4];
      #pragma unroll
      for (int rg = 0; rg < 4; ++rg) {
        float rem  = fmaxf((S1 - (pbase + ipr[rg])) * inv1, 0.f);
        float pos  = pf - (float)rg;
        float dist = sqrtf(rem * pos);
        float eff  = fmaxf(ex2r(gamma2 * dist), 1e-5f);
        float ee   = vv[rg] ? ex2c(sv[rg] * eff) : 0.f;
        q2[rg] = ee;
        S2l += ee;
      }
      wA = packbf2(q2[0], q2[1]);
      wB = packbf2(q2[2], q2[3]);
      cbase += tt;
    };

    #pragma unroll
    for (int c = 0; c < 16; ++c) {
      if (2 * c <= rs) {
        u32 w0 = 0, w1 = 0, w2 = 0, w3 = 0;
        subkt(2 * c, (2 * c == rs), w0, w1);
        if (2 * c + 1 <= rs) subkt(2 * c + 1, (2 * c + 1 == rs), w2, w3);
        *(u32*)(pB + ((ql * 64 +      8 * g    ) ^ swp)) = w0;
        *(u32*)(pB + ((ql * 64 +      8 * g + 4) ^ swp)) = w1;
        *(u32*)(pB + ((ql * 64 + 32 + 8 * g    ) ^ swp)) = w2;
        *(u32*)(pB + ((ql * 64 + 32 + 8 * g + 4) ^ swp)) = w3;
        bf16x8 pa = *(const bf16x8*)(pB + ((ql * 64 + 16 * g) ^ swp));
        #pragma unroll
        for (int n = 0; n < 4; ++n) {
          bf16x8 vb = *(const bf16x8*)(vTb + vbase[n] + ((64 * c + 16 * g) ^ vsw[n]));
          oacc[n] = __builtin_amdgcn_mfma_f32_16x16x32_bf16(pa, vb, oacc[n], 0, 0, 0);
        }
      }
    }

    const float S2   = redsum2(S2l);
    const float inv2 = 1.f / fmaxf(S2, 1e-30f);
    float i2[4];
    #pragma unroll
    for (int rg = 0; rg < 4; ++rg) i2[rg] = __shfl(inv2, 4 * g + rg, 64);

    #pragma unroll
    for (int n = 0; n < 4; ++n) {
      #pragma unroll
      for (int rg = 0; rg < 4; ++rg) {
        const int qo = i0 + 4 * g + rg;
        float val = oacc[n][rg] * i2[rg];
        if (zero_pad && qo == 0) val = 0.f;
        out[base + (size_t)qo * DDIM + n * 16 + ql] = pack1bf(val);
      }
    }
  }
}

// ---------- fused residual + LayerNorm (job-array): out = LN(a + b [+ c]), all bf16 in ----------
struct LNJob { const u16* a; const u16* b; const u16* c;
               const float* g; const float* be; float* outF; u16* outB; };
struct LNJobs { LNJob j[2]; };

__global__ __launch_bounds__(256) void ln_kernel(LNJobs jobs)
{
  const LNJob J = jobs.j[blockIdx.y];
  const int lane = threadIdx.x & 63, w = threadIdx.x >> 6;
  const size_t row = (size_t)blockIdx.x * 4 + w;
  const size_t off8 = row * DDIM + lane * 8;

  uint4 ab = *(const uint4*)(J.a + off8);
  uint4 bb = *(const uint4*)(J.b + off8);
  const u16* ap = (const u16*)&ab;
  const u16* bp = (const u16*)&bb;
  float v[8];
  #pragma unroll
  for (int k = 0; k < 8; ++k)
    v[k] = __uint_as_float(((u32)ap[k]) << 16) + __uint_as_float(((u32)bp[k]) << 16);
  if (J.c) {
    uint4 cb = *(const uint4*)(J.c + off8);
    const u16* cp = (const u16*)&cb;
    #pragma unroll
    for (int k = 0; k < 8; ++k) v[k] += __uint_as_float(((u32)cp[k]) << 16);
  }

  float sum = 0.f;
  #pragma unroll
  for (int k = 0; k < 8; ++k) sum += v[k];
  #pragma unroll
  for (int off = 32; off > 0; off >>= 1) sum += __shfl_xor(sum, off, 64);
  const float mean = sum * (1.f / 512.f);
  float var = 0.f;
  #pragma unroll
  for (int k = 0; k < 8; ++k) { float dd = v[k] - mean; var = fmaf(dd, dd, var); }
  #pragma unroll
  for (int off = 32; off > 0; off >>= 1) var += __shfl_xor(var, off, 64);
  var *= (1.f / 512.f);
  const float inv = rsqrtf(var + 1e-5f);

  float4 g0 = *(const float4*)(J.g + lane * 8);
  float4 g1 = *(const float4*)(J.g + lane * 8 + 4);
  float4 e0 = *(const float4*)(J.be + lane * 8);
  float4 e1 = *(const float4*)(J.be + lane * 8 + 4);
  float gv[8] = {g0.x, g0.y, g0.z, g0.w, g1.x, g1.y, g1.z, g1.w};
  float ev[8] = {e0.x, e0.y, e0.z, e0.w, e1.x, e1.y, e1.z, e1.w};
  float o[8];
  #pragma unroll
  for (int k = 0; k < 8; ++k) o[k] = (v[k] - mean) * inv * gv[k] + ev[k];

  if (J.outF) {
    float4 f0 = {o[0], o[1], o[2], o[3]};
    float4 f1 = {o[4], o[5], o[6], o[7]};
    *(float4*)(J.outF + off8)     = f0;
    *(float4*)(J.outF + off8 + 4) = f1;
  }
  if (J.outB) {
    uint4 p;
    p.x = packbf2(o[0], o[1]); p.y = packbf2(o[2], o[3]);
    p.z = packbf2(o[4], o[5]); p.w = packbf2(o[6], o[7]);
    *(uint4*)(J.outB + off8) = p;
  }
}

// ---------- orchestration ----------
extern "C" void kernel_launch(void* const* d_in, const int* in_sizes, int n_in,
                              void* d_out, int out_size, void* d_ws, size_t ws_size,
                              hipStream_t stream) {
  const float* qe  = (const float*)d_in[0];
  const float* qa  = (const float*)d_in[1];
  const float* Wk  = (const float*)d_in[2];
  const float* bk  = (const float*)d_in[3];
  const float* Wv  = (const float*)d_in[4];
  const float* bv  = (const float*)d_in[5];
  const float* Wo  = (const float*)d_in[6];
  const float* bo  = (const float*)d_in[7];
  const float* gm  = (const float*)d_in[8];
  const float* l1g = (const float*)d_in[9];
  const float* l1b = (const float*)d_in[10];
  const float* W1  = (const float*)d_in[11];
  const float* b1  = (const float*)d_in[12];
  const float* W2  = (const float*)d_in[13];
  const float* b2  = (const float*)d_in[14];
  const float* l2g = (const float*)d_in[15];
  const float* l2b = (const float*)d_in[16];

  char* ws = (char*)d_ws;
  u16* WT  = (u16*)ws;
  u16* A0  = (u16*)(ws + ((size_t)18  << 20));
  u16* A1  = (u16*)(ws + ((size_t)34  << 20));
  u16* A2  = (u16*)(ws + ((size_t)50  << 20));
  u16* A3  = (u16*)(ws + ((size_t)66  << 20));
  u16* A4  = (u16*)(ws + ((size_t)82  << 20));
  u16* A5  = (u16*)(ws + ((size_t)98  << 20));
  u16* B0  = (u16*)(ws + ((size_t)114 << 20));
  u16* B1  = (u16*)(ws + ((size_t)130 << 20));
  u16* X0  = (u16*)(ws + ((size_t)146 << 20));
  u16* Amid = A2;   // [50,114)

  u16* WkT = WT;
  u16* WvT = WT + (size_t)3 * 262144;
  u16* WoT = WT + (size_t)6 * 262144;
  u16* W1T = WT + (size_t)9 * 262144;
  u16* W2T = W1T + (size_t)3 * 1048576;

  pack_w_sq<<<dim3(8, 8, 9),  256, 0, stream>>>(Wk, Wv, Wo, WkT, WvT, WoT);
  pack_w_t<<<dim3(32, 8, 3), 256, 0, stream>>>(W1, W1T, 512, 2048);
  pack_w_t<<<dim3(8, 32, 3), 256, 0, stream>>>(W2, W2T, 2048, 512);
  pack_flat2<<<dim3(4096, 2), 256, 0, stream>>>(qa, qe, A0, A1);

  const float SQ2 = 0.4246609001f;   // sqrt(log2e/8)

  auto g8 = [&](GJobs jobs, int lda, int ldb, int ldc,
                int M, int N, int Kz, int relu, int nz) {
    gemm8<<<dim3(N / 256, M / 256, nz), 512, 0, stream>>>(
        jobs, lda, ldb, ldc, Kz, relu);
  };
  auto ln2x = [&](LNJobs jobs, int nz) {
    ln_kernel<<<dim3(MR / 4, nz), 256, 0, stream>>>(jobs);
  };

  auto WkT_l = [&](int l){ return WkT + (size_t)l * 262144; };
  auto WvT_l = [&](int l){ return WvT + (size_t)l * 262144; };
  auto WoT_l = [&](int l){ return WoT + (size_t)l * 262144; };
  auto W1T_l = [&](int l){ return W1T + (size_t)l * 1048576; };
  auto W2T_l = [&](int l){ return W2T + (size_t)l * 1048576; };

  // ===== layers 0 & 1 batched =====
  {
    GJobs pj = {{ {A0, WkT_l(0), bk,       nullptr, A2, SQ2},
                  {A0, WvT_l(0), bv,       nullptr, A3, 1.f},
                  {A1, WkT_l(1), bk + 512, nullptr, A4, SQ2},
                  {A1, WvT_l(1), bv + 512, nullptr, A5, 1.f} }};
    g8(pj, 512, 512, 512, MR, 512, 512, 0, 4);

    attn_mfma<<<BB * HH * 2, 1024, 0, stream>>>(
        A2, A3, gm, A3, A4, A5, gm + HH, A5, BB * HH, 0, 0);

    GJobs wj = {{ {A3, WoT_l(0), bo,       nullptr, B0, 1.f},
                  {A5, WoT_l(1), bo + 512, nullptr, B1, 1.f},
                  {}, {} }};
    g8(wj, 512, 512, 512, MR, 512, 512, 0, 2);

    LNJobs lj = {{ {A0, B0, nullptr, l1g,       l1b,       nullptr, X0},
                   {A1, B1, nullptr, l1g + 512, l1b + 512, nullptr, A1} }};
    ln2x(lj, 2);
  }
  // ===== layer 0 FFN =====
  {
    GJobs w1j = {{ {X0, W1T_l(0), b1, nullptr, Amid, 1.f}, {}, {}, {} }};
    g8(w1j, 512, 512, 2048, MR, 2048, 512, 1, 1);
    GJobs w2j = {{ {Amid,        W2T_l(0),        b2,      nullptr, B0, 1.f},
                   {Amid + 1024, W2T_l(0) + 1024, nullptr, nullptr, B1, 1.f},
                   {}, {} }};
    g8(w2j, 2048, 2048, 512, MR, 512, 1024, 0, 2);
    LNJobs lj = {{ {X0, B0, B1, l2g, l2b, nullptr, A0}, {} }};   // y1 -> A0
    ln2x(lj, 1);
  }
  // ===== layer 2 =====
  {
    GJobs pj = {{ {A1, WkT_l(2), bk + 1024, nullptr, A2, SQ2},
                  {A0, WvT_l(2), bv + 1024, nullptr, A3, 1.f},
                  {}, {} }};
    g8(pj, 512, 512, 512, MR, 512, 512, 0, 2);

    attn_mfma<<<BB * HH, 1024, 0, stream>>>(
        A2, A3, gm + 2 * HH, A3, A2, A3, gm + 2 * HH, A3, BB * HH, 1, 1);

    GJobs wj = {{ {A3,       WoT_l(2),       bo + 1024, nullptr, B0, 1.f},
                  {A3 + 256, WoT_l(2) + 256, nullptr,   nullptr, B1, 1.f},
                  {}, {} }};
    g8(wj, 512, 512, 512, MR, 512, 256, 0, 2);

    LNJobs l1j = {{ {A1, B0, B1, l1g + 1024, l1b + 1024, nullptr, A1}, {} }};
    ln2x(l1j, 1);

    GJobs w1j = {{ {A1, W1T_l(2), b1 + 2 * DFFN, nullptr, Amid, 1.f}, {}, {}, {} }};
    g8(w1j, 512, 512, 2048, MR, 2048, 512, 1, 1);
    GJobs w2j = {{ {Amid,        W2T_l(2),        b2 + 1024, nullptr, B0, 1.f},
                   {Amid + 1024, W2T_l(2) + 1024, nullptr,   nullptr, B1, 1.f},
                   {}, {} }};
    g8(w2j, 2048, 2048, 512, MR, 512, 1024, 0, 2);

    LNJobs l2j = {{ {A1, B0, B1, l2g + 1024, l2b + 1024, (float*)d_out, nullptr}, {} }};
    ln2x(l2j, 1);
  }
}

// Round 15
// 601.227 us; speedup vs baseline: 1.1981x; 1.0041x over previous
//
#include <hip/hip_runtime.h>

#define BB   32
#define SS   512
#define DDIM 512
#define HH   8
#define DFFN 2048
#define MR   (BB*SS)   // 16384 rows

typedef unsigned int   u32;
typedef unsigned short u16;
typedef unsigned char  u8;
typedef __attribute__((ext_vector_type(8)))  short bf16x8;
typedef __attribute__((ext_vector_type(4)))  float f32x4;
typedef __attribute__((ext_vector_type(16))) float f32x16;

// ---------- bf16 helpers ----------
__device__ __forceinline__ u32 packbf2(float x, float y) {
  u32 ux = __float_as_uint(x), uy = __float_as_uint(y);
  u32 hx = (ux + 0x7FFFu + ((ux >> 16) & 1u)) >> 16;
  u32 hy = (uy + 0x7FFFu + ((uy >> 16) & 1u)) >> 16;
  return hx | (hy << 16);
}
__device__ __forceinline__ u16 pack1bf(float x) {
  u32 u = __float_as_uint(x);
  return (u16)((u + 0x7FFFu + ((u >> 16) & 1u)) >> 16);
}

__device__ __forceinline__ float redsum2(float v) {
  v += __shfl_xor(v, 16, 64);
  v += __shfl_xor(v, 32, 64);
  return v;
}

// exp2-domain softmax (scores prescaled by log2e via the GEMM epilogue):
#if __has_builtin(__builtin_amdgcn_exp2f)
__device__ __forceinline__ float ex2c(float x) { return __builtin_amdgcn_exp2f(fminf(x, 110.f)); }
__device__ __forceinline__ float ex2r(float x) { return __builtin_amdgcn_exp2f(x); }
#else
__device__ __forceinline__ float ex2c(float x) {
  float r = fminf(x, 110.f);
  asm("v_exp_f32 %0, %1" : "=v"(r) : "v"(r));
  return r;
}
__device__ __forceinline__ float ex2r(float x) {
  float r;
  asm("v_exp_f32 %0, %1" : "=v"(r) : "v"(x));
  return r;
}
#endif

// ---------- flat f32 -> bf16 pack (dual input via blockIdx.y) ----------
__global__ __launch_bounds__(256) void pack_flat2(
    const float* __restrict__ in0, const float* __restrict__ in1,
    u16* __restrict__ out0, u16* __restrict__ out1) {
  const float* in = blockIdx.y ? in1 : in0;
  u16* out = blockIdx.y ? out1 : out0;
  size_t i = ((size_t)blockIdx.x * 256 + threadIdx.x) * 8;
  float4 a = *(const float4*)(in + i);
  float4 b = *(const float4*)(in + i + 4);
  uint4 o;
  o.x = packbf2(a.x, a.y); o.y = packbf2(a.z, a.w);
  o.z = packbf2(b.x, b.y); o.w = packbf2(b.z, b.w);
  *(uint4*)(out + i) = o;
}

// ---------- weight transpose-pack: f32 [K,N] -> bf16 [N,K] ----------
__device__ __forceinline__ void wtp_body(const float* __restrict__ in,
                                         u16* __restrict__ out, int K, int N,
                                         int bx, int by) {
  __shared__ float tile[64][65];
  const int t  = threadIdx.x;
  const int n0 = bx * 64, k0 = by * 64;
  #pragma unroll
  for (int it = 0; it < 4; ++it) {
    int idx = it * 256 + t;
    int kk = idx >> 4, n4 = idx & 15;
    float4 v = *(const float4*)(in + (size_t)(k0 + kk) * N + n0 + n4 * 4);
    tile[kk][n4*4+0] = v.x; tile[kk][n4*4+1] = v.y;
    tile[kk][n4*4+2] = v.z; tile[kk][n4*4+3] = v.w;
  }
  __syncthreads();
  #pragma unroll
  for (int it = 0; it < 4; ++it) {
    int idx = it * 256 + t;
    int nn = idx >> 4, g = idx & 15;
    uint2 o;
    o.x = packbf2(tile[g*4+0][nn], tile[g*4+1][nn]);
    o.y = packbf2(tile[g*4+2][nn], tile[g*4+3][nn]);
    *(uint2*)(out + (size_t)(n0 + nn) * K + k0 + g * 4) = o;
  }
}
__global__ __launch_bounds__(256) void pack_w_t(const float* __restrict__ in,
                                                u16* __restrict__ out, int K, int N) {
  wtp_body(in + (size_t)blockIdx.z * K * N, out + (size_t)blockIdx.z * N * K,
           K, N, blockIdx.x, blockIdx.y);
}
__global__ __launch_bounds__(256) void pack_w_sq(
    const float* __restrict__ Wk, const float* __restrict__ Wv,
    const float* __restrict__ Wo,
    u16* __restrict__ WkT, u16* __restrict__ WvT, u16* __restrict__ WoT) {
  const int z = blockIdx.z, which = z / 3, li = z % 3;
  const float* in = (which == 0 ? Wk : which == 1 ? Wv : Wo) + (size_t)li * 262144;
  u16* out = (which == 0 ? WkT : which == 1 ? WvT : WoT) + (size_t)li * 262144;
  wtp_body(in, out, 512, 512, blockIdx.x, blockIdx.y);
}

// ---------- 256x256 8-phase GEMM with 32x32x16 MFMA (r15) ----------
// r14 post-mortem: phases were LDS-BW-bound (96KB/block-phase for 16 16x16
// MFMA/wave). 32x32x16 doubles reuse per LDS byte. Phase = (A-row-half mh,
// B-k-half kh): per wave 8 b128 reads + 8 MFMA (64KB/block-phase, -33%).
// B stored as k-halves: [kh][col][32k], 64B col-rows, slot^=(col&3) swizzle
// (bank-optimal: 8 groups x 4 banks, 8 accesses each). A layout unchanged.
// Stagger safety re-verified: every stage slot writes a (buf,half) whose last
// reader finished a barrier earlier in the 8-phase schedule.
struct GJob { const u16* A; const u16* Bt; const float* bias;
              float* outF; u16* outB; float sc; };
struct GJobs { GJob j[4]; };

__global__ __launch_bounds__(512, 2) void gemm8(
    GJobs jobs, int lda, int ldb, int ldc, int Kz, int relu)
{
  __shared__ __align__(16) u8 lds[131072];

  const GJob J = jobs.j[blockIdx.z];
  const u16* A    = J.A;
  const u16* Bt   = J.Bt;
  const float* bias = J.bias;
  float* outF = J.outF;
  u16*   outB = J.outB;
  const float sc = J.sc;

  const int nwg  = gridDim.x * gridDim.y;
  const int orig = blockIdx.y * gridDim.x + blockIdx.x;
  const int q8   = nwg >> 3, r8 = nwg & 7;
  const int xcd  = orig & 7, idx8 = orig >> 3;
  const int wg   = (xcd < r8 ? xcd * (q8 + 1) : r8 * (q8 + 1) + (xcd - r8) * q8) + idx8;
  const int bx   = wg % gridDim.x, by = wg / gridDim.x;
  const int row0 = by * 256, col0 = bx * 256;

  const int t    = threadIdx.x;
  const int lane = t & 63, wid = t >> 6;
  const int wm   = wid >> 2, wn = wid & 3;
  const int rl   = lane & 31, lhi = lane >> 5;

  const int NT = Kz >> 6;   // >= 4, even

  f32x16 acc[4][2] = {};

  // A-half h: rows {128r + 64h + 0..63}, full K=64, 16KB. (unchanged)
  auto stageA = [&](int buf, int h, int kt) {
    #pragma unroll
    for (int l = 0; l < 2; ++l) {
      int s  = (l * 512 + t) >> 3;
      int kb = ((lane & 7) * 16) ^ ((s & 7) << 4);
      int row = row0 + ((s >> 6) * 128) + h * 64 + (s & 63);
      const u8* src = (const u8*)A + (size_t)row * lda * 2 + (size_t)kt * 128 + kb;
      u8* dst = lds + buf * 65536 + h * 16384 + (l * 512 + wid * 64) * 16;
      __builtin_amdgcn_global_load_lds(
          (const __attribute__((address_space(1))) u32*)src,
          (__attribute__((address_space(3))) u32*)dst, 16, 0, 0);
    }
  };
  // B k-half h: all 256 cols, k in [kt*64+32h, +32). LDS: col*64B + slot*16,
  // slot = j ^ (col&3), j = k_local/8. Linear dest, pre-swizzled source.
  auto stageB = [&](int buf, int h, int kt) {
    #pragma unroll
    for (int l = 0; l < 2; ++l) {
      int idx = l * 512 + t;           // 0..1023 = 16B chunks
      int c  = idx >> 2, jj = idx & 3;
      int j  = jj ^ (c & 3);
      const u16* src = Bt + (size_t)(col0 + c) * ldb + kt * 64 + h * 32 + j * 8;
      u8* dst = lds + buf * 65536 + 32768 + h * 16384 + (l * 512 + wid * 64) * 16;
      __builtin_amdgcn_global_load_lds(
          (const __attribute__((address_space(1))) u32*)src,
          (__attribute__((address_space(3))) u32*)dst, 16, 0, 0);
    }
  };

  // A frag (32x32x16): rows wm*128+mh*64+mt*32+rl, k = kh*32+q*16+lhi*8
  auto rdA = [&](int buf, int mh, int mt, int kh, int q) -> bf16x8 {
    int s = wm * 64 + mt * 32 + rl;
    int off = buf * 65536 + mh * 16384 + s * 128 +
              (((kh * 64 + q * 32 + lhi * 16)) ^ ((s & 7) << 4));
    return *(const bf16x8*)(lds + off);
  };
  // B frag: cols wn*64+nt*32+rl, k_local = q*16+lhi*8 -> j = q*2+lhi
  auto rdB = [&](int buf, int kh, int nt, int q) -> bf16x8 {
    int c = wn * 64 + nt * 32 + rl;
    int off = buf * 65536 + 32768 + kh * 16384 + c * 64 +
              (((q * 2 + lhi) ^ (c & 3)) * 16);
    return *(const bf16x8*)(lds + off);
  };

#define GBAR asm volatile("s_barrier" ::: "memory")
#define VMW4 asm volatile("s_waitcnt vmcnt(4)" ::: "memory")
#define VMW0 asm volatile("s_waitcnt vmcnt(0)" ::: "memory")

#define PHASE(BUF, MH, KH, STAGECODE, DOVM) do {                               \
    bf16x8 af_[2][2], bf_[2][2];                                               \
    _Pragma("unroll") for (int mt_ = 0; mt_ < 2; ++mt_)                        \
      _Pragma("unroll") for (int q_ = 0; q_ < 2; ++q_)                         \
        af_[mt_][q_] = rdA(BUF, MH, mt_, KH, q_);                              \
    _Pragma("unroll") for (int nt_ = 0; nt_ < 2; ++nt_)                        \
      _Pragma("unroll") for (int q_ = 0; q_ < 2; ++q_)                         \
        bf_[nt_][q_] = rdB(BUF, KH, nt_, q_);                                  \
    STAGECODE;                                                                 \
    if (DOVM == 1) VMW4;                                                       \
    if (DOVM == 2) VMW0;                                                       \
    GBAR;                                                                      \
    __builtin_amdgcn_s_setprio(1);                                             \
    _Pragma("unroll") for (int mt_ = 0; mt_ < 2; ++mt_)                        \
      _Pragma("unroll") for (int nt_ = 0; nt_ < 2; ++nt_) {                    \
        acc[(MH)*2+mt_][nt_] = __builtin_amdgcn_mfma_f32_32x32x16_bf16(        \
            af_[mt_][0], bf_[nt_][0], acc[(MH)*2+mt_][nt_], 0, 0, 0);          \
        acc[(MH)*2+mt_][nt_] = __builtin_amdgcn_mfma_f32_32x32x16_bf16(        \
            af_[mt_][1], bf_[nt_][1], acc[(MH)*2+mt_][nt_], 0, 0, 0);          \
      }                                                                        \
    __builtin_amdgcn_s_setprio(0);                                             \
    GBAR;                                                                      \
  } while (0)

  // prologue: tile0 fully + tile1's A-h0, B-kh0
  stageA(0, 0, 0); stageB(0, 0, 0); stageA(0, 1, 0); stageB(0, 1, 0);
  stageA(1, 0, 1); stageB(1, 0, 1);
  VMW4; GBAR;

  for (int i = 0; i < (NT >> 1) - 1; ++i) {
    const int T1 = 2 * i + 1, T2 = 2 * i + 2, T3 = 2 * i + 3;
    PHASE(0, 0, 0, stageA(1, 1, T1), 0);
    PHASE(0, 0, 1, stageB(1, 1, T1), 0);
    PHASE(0, 1, 0, stageA(0, 0, T2), 0);
    PHASE(0, 1, 1, stageB(0, 0, T2), 1);
    PHASE(1, 0, 0, stageA(0, 1, T2), 0);
    PHASE(1, 0, 1, stageB(0, 1, T2), 0);
    PHASE(1, 1, 0, stageA(1, 0, T3), 0);
    PHASE(1, 1, 1, stageB(1, 0, T3), 1);
  }
  // tail
  PHASE(0, 0, 0, stageA(1, 1, NT - 1), 0);
  PHASE(0, 0, 1, stageB(1, 1, NT - 1), 0);
  PHASE(0, 1, 0, ;, 0);
  PHASE(0, 1, 1, ;, 2);
  PHASE(1, 0, 0, ;, 0);
  PHASE(1, 0, 1, ;, 0);
  PHASE(1, 1, 0, ;, 0);
  PHASE(1, 1, 1, ;, 0);
#undef PHASE
#undef GBAR
#undef VMW4
#undef VMW0

  // epilogue: 32x32 C/D map: col = lane&31, row = (reg&3)+8*(reg>>2)+4*lhi
  #pragma unroll
  for (int mi = 0; mi < 4; ++mi) {
    #pragma unroll
    for (int nt = 0; nt < 2; ++nt) {
      const int col = col0 + wn * 64 + nt * 32 + rl;
      const float bs = bias ? bias[col] : 0.f;
      #pragma unroll
      for (int reg = 0; reg < 16; ++reg) {
        const int row = row0 + wm * 128 + mi * 32 + (reg & 3) + 8 * (reg >> 2) + 4 * lhi;
        float v = (acc[mi][nt][reg] + bs) * sc;
        if (relu) v = fmaxf(v, 0.f);
        if (outF) outF[(size_t)row * ldc + col] = v;
        if (outB) outB[(size_t)row * ldc + col] = pack1bf(v);
      }
    }
  }
}

// ---------- MFMA attention: 1024 threads (16 waves) per (b,h) block ----------
__global__ __attribute__((amdgpu_flat_work_group_size(1024, 1024)))
void attn_mfma(
    const u16* __restrict__ qkA, const u16* __restrict__ vbA,
    const float* __restrict__ gmA, u16* __restrict__ outAp,
    const u16* __restrict__ qkB, const u16* __restrict__ vbB,
    const float* __restrict__ gmB, u16* __restrict__ outBp,
    int nA, int mask_excl, int zero_pad)
{
  __shared__ __align__(16) u8 kSb[65536];   // K/Q rows [512][64] bf16, byte ^= (row&7)<<4
  __shared__ __align__(16) u8 vTb[65536];   // V^T [64 d][512 k] bf16, u32 ^= ((d&7)^(d>>3))<<4
  __shared__ __align__(16) u8 pChb[16384];  // per-wave 1KB P chunk buffers (16 waves)

  const int t    = threadIdx.x;
  const int lane = t & 63, wid = t >> 6;    // wid in 0..15
  const int ql   = lane & 15, g = lane >> 4;
  const int bid  = blockIdx.x;
  const int sel  = bid >= nA;
  const u16* qk    = sel ? qkB : qkA;
  const u16* vbuf  = sel ? vbB : vbA;
  const float* gam = sel ? gmB : gmA;
  u16* out         = sel ? outBp : outAp;
  const int bh = sel ? bid - nA : bid;
  const int b = bh >> 3, h = bh & 7;
  const size_t base = (size_t)b * SS * DDIM + (size_t)h * 64;

  float gv = gam[h];
  float sp = (gv > 0.f) ? (gv + log1pf(__expf(-gv))) : log1pf(__expf(gv));
  const float gamma2 = -sp * 1.442695041f;   // exp2-domain gamma

  for (int it = 0; it < 4; ++it) {
    int idx = it * 1024 + t;
    int j = idx >> 3, u = idx & 7;
    uint4 w = *(const uint4*)(qk + base + (size_t)j * DDIM + u * 8);
    *(uint4*)(kSb + ((j * 128 + u * 16) ^ ((j & 7) << 4))) = w;
  }
  for (int it = 0; it < 2; ++it) {
    int idx = it * 1024 + t;
    int jp = idx >> 3, u = idx & 7;
    const u16* src = vbuf + base + (size_t)(2 * jp) * DDIM + u * 8;
    uint4 r0 = *(const uint4*)src;
    uint4 r1 = *(const uint4*)(src + DDIM);
    const u16* a0 = (const u16*)&r0;
    const u16* a1 = (const u16*)&r1;
    #pragma unroll
    for (int dd = 0; dd < 8; ++dd) {
      int d = u * 8 + dd;
      u32 w = (u32)a0[dd] | ((u32)a1[dd] << 16);
      *(u32*)(vTb + d * 1024 + ((4 * jp) ^ ((dd ^ u) << 4))) = w;
    }
  }
  __syncthreads();

  bool vm[4];
  #pragma unroll
  for (int rg = 0; rg < 4; ++rg) {
    int kl = 4 * g + rg;
    vm[rg] = mask_excl ? (kl < ql) : (kl <= ql);
  }

  u8* pB = pChb + wid * 1024;
  const int swp = (ql & 7) << 4;

  int vbase[4], vsw[4];
  #pragma unroll
  for (int n = 0; n < 4; ++n) {
    int d = n * 16 + ql;
    vbase[n] = d * 1024;
    vsw[n]   = ((d & 7) ^ ((d >> 3) & 7)) << 4;
  }

  #pragma unroll
  for (int ri = 0; ri < 2; ++ri) {
    const int rs = __builtin_amdgcn_readfirstlane(ri ? (31 - wid) : wid);
    const int i0 = rs * 16;

    const int qrow = i0 + ql;
    const int qsw  = (qrow & 7) << 4;
    bf16x8 qf0 = *(const bf16x8*)(kSb + ((qrow * 128      + g * 16) ^ qsw));
    bf16x8 qf1 = *(const bf16x8*)(kSb + ((qrow * 128 + 64 + g * 16) ^ qsw));

    // ---- pass 1: S1 only ----
    float S1l = 0.f;
    #pragma unroll
    for (int kt = 0; kt < 32; ++kt) {
      if (kt <= rs) {
        const bool dg = (kt == rs);
        const int krow = kt * 16 + ql;
        const int ksw  = (krow & 7) << 4;
        bf16x8 ka0 = *(const bf16x8*)(kSb + ((krow * 128      + g * 16) ^ ksw));
        bf16x8 ka1 = *(const bf16x8*)(kSb + ((krow * 128 + 64 + g * 16) ^ ksw));
        f32x4 dv = {};
        dv = __builtin_amdgcn_mfma_f32_16x16x32_bf16(ka0, qf0, dv, 0, 0, 0);
        dv = __builtin_amdgcn_mfma_f32_16x16x32_bf16(ka1, qf1, dv, 0, 0, 0);
        float e0 = (!dg || vm[0]) ? ex2c(dv[0]) : 0.f;
        float e1 = (!dg || vm[1]) ? ex2c(dv[1]) : 0.f;
        float e2 = (!dg || vm[2]) ? ex2c(dv[2]) : 0.f;
        float e3 = (!dg || vm[3]) ? ex2c(dv[3]) : 0.f;
        S1l += (e0 + e1) + (e2 + e3);
      }
    }
    const float S1   = redsum2(S1l);
    const float inv1 = (S1 > 0.f) ? (1.f / S1) : 0.f;

    // ---- pass 2: streamed recompute -> butterfly cumsum -> rescore -> PV ----
    f32x4 oacc[4] = {};
    float cbase = 0.f, S2l = 0.f;
    const float qlf = (float)(i0 + ql);

    auto subkt = [&](int kt, bool dg, u32& wA, u32& wB) {
      const int krow = kt * 16 + ql;
      const int ksw  = (krow & 7) << 4;
      bf16x8 ka0 = *(const bf16x8*)(kSb + ((krow * 128      + g * 16) ^ ksw));
      bf16x8 ka1 = *(const bf16x8*)(kSb + ((krow * 128 + 64 + g * 16) ^ ksw));
      f32x4 dv = {};
      dv = __builtin_amdgcn_mfma_f32_16x16x32_bf16(ka0, qf0, dv, 0, 0, 0);
      dv = __builtin_amdgcn_mfma_f32_16x16x32_bf16(ka1, qf1, dv, 0, 0, 0);
      const bool v0 = !dg || vm[0], v1 = !dg || vm[1];
      const bool v2 = !dg || vm[2], v3 = !dg || vm[3];
      float e0 = v0 ? ex2c(dv[0]) : 0.f;
      float e1 = v1 ? ex2c(dv[1]) : 0.f;
      float e2 = v2 ? ex2c(dv[2]) : 0.f;
      float e3 = v3 ? ex2c(dv[3]) : 0.f;
      float p0 = e0, p1 = p0 + e1, p2 = p1 + e2, p3 = p2 + e3;
      float bq  = __shfl_xor(p3, 16, 64);
      float s1p = p3 + bq;
      float cq  = __shfl_xor(s1p, 32, 64);
      float gp  = ((g & 1) ? bq : 0.f) + ((g & 2) ? cq : 0.f);
      float tt  = s1p + cq;
      const float pbase = cbase + gp;
      const float pf = qlf - (float)(kt * 16 + 4 * g);
      float ipr[4] = {p0, p1, p2, p3};
      bool  vv[4]  = {v0, v1, v2, v3};
      float sv[4]  = {dv[0], dv[1], dv[2], dv[3]};
      float q2[4];
      #pragma unroll
      for (int rg = 0; rg < 4; ++rg) {
        float rem  = fmaxf((S1 - (pbase + ipr[rg])) * inv1, 0.f);
        float pos  = pf - (float)rg;
        float dist = sqrtf(rem * pos);
        float eff  = fmaxf(ex2r(gamma2 * dist), 1e-5f);
        float ee   = vv[rg] ? ex2c(sv[rg] * eff) : 0.f;
        q2[rg] = ee;
        S2l += ee;
      }
      wA = packbf2(q2[0], q2[1]);
      wB = packbf2(q2[2], q2[3]);
      cbase += tt;
    };

    #pragma unroll
    for (int c = 0; c < 16; ++c) {
      if (2 * c <= rs) {
        u32 w0 = 0, w1 = 0, w2 = 0, w3 = 0;
        subkt(2 * c, (2 * c == rs), w0, w1);
        if (2 * c + 1 <= rs) subkt(2 * c + 1, (2 * c + 1 == rs), w2, w3);
        *(u32*)(pB + ((ql * 64 +      8 * g    ) ^ swp)) = w0;
        *(u32*)(pB + ((ql * 64 +      8 * g + 4) ^ swp)) = w1;
        *(u32*)(pB + ((ql * 64 + 32 + 8 * g    ) ^ swp)) = w2;
        *(u32*)(pB + ((ql * 64 + 32 + 8 * g + 4) ^ swp)) = w3;
        bf16x8 pa = *(const bf16x8*)(pB + ((ql * 64 + 16 * g) ^ swp));
        #pragma unroll
        for (int n = 0; n < 4; ++n) {
          bf16x8 vb = *(const bf16x8*)(vTb + vbase[n] + ((64 * c + 16 * g) ^ vsw[n]));
          oacc[n] = __builtin_amdgcn_mfma_f32_16x16x32_bf16(pa, vb, oacc[n], 0, 0, 0);
        }
      }
    }

    const float S2   = redsum2(S2l);
    const float inv2 = 1.f / fmaxf(S2, 1e-30f);
    float i2[4];
    #pragma unroll
    for (int rg = 0; rg < 4; ++rg) i2[rg] = __shfl(inv2, 4 * g + rg, 64);

    #pragma unroll
    for (int n = 0; n < 4; ++n) {
      #pragma unroll
      for (int rg = 0; rg < 4; ++rg) {
        const int qo = i0 + 4 * g + rg;
        float val = oacc[n][rg] * i2[rg];
        if (zero_pad && qo == 0) val = 0.f;
        out[base + (size_t)qo * DDIM + n * 16 + ql] = pack1bf(val);
      }
    }
  }
}

// ---------- fused residual + LayerNorm (job-array), all bf16 in ----------
struct LNJob { const u16* a; const u16* b; const u16* c;
               const float* g; const float* be; float* outF; u16* outB; };
struct LNJobs { LNJob j[2]; };

__global__ __launch_bounds__(256) void ln_kernel(LNJobs jobs)
{
  const LNJob J = jobs.j[blockIdx.y];
  const int lane = threadIdx.x & 63, w = threadIdx.x >> 6;
  const size_t row = (size_t)blockIdx.x * 4 + w;
  const size_t off8 = row * DDIM + lane * 8;

  uint4 ab = *(const uint4*)(J.a + off8);
  uint4 bb = *(const uint4*)(J.b + off8);
  const u16* ap = (const u16*)&ab;
  const u16* bp = (const u16*)&bb;
  float v[8];
  #pragma unroll
  for (int k = 0; k < 8; ++k)
    v[k] = __uint_as_float(((u32)ap[k]) << 16) + __uint_as_float(((u32)bp[k]) << 16);
  if (J.c) {
    uint4 cb = *(const uint4*)(J.c + off8);
    const u16* cp = (const u16*)&cb;
    #pragma unroll
    for (int k = 0; k < 8; ++k) v[k] += __uint_as_float(((u32)cp[k]) << 16);
  }

  float sum = 0.f;
  #pragma unroll
  for (int k = 0; k < 8; ++k) sum += v[k];
  #pragma unroll
  for (int off = 32; off > 0; off >>= 1) sum += __shfl_xor(sum, off, 64);
  const float mean = sum * (1.f / 512.f);
  float var = 0.f;
  #pragma unroll
  for (int k = 0; k < 8; ++k) { float dd = v[k] - mean; var = fmaf(dd, dd, var); }
  #pragma unroll
  for (int off = 32; off > 0; off >>= 1) var += __shfl_xor(var, off, 64);
  var *= (1.f / 512.f);
  const float inv = rsqrtf(var + 1e-5f);

  float4 g0 = *(const float4*)(J.g + lane * 8);
  float4 g1 = *(const float4*)(J.g + lane * 8 + 4);
  float4 e0 = *(const float4*)(J.be + lane * 8);
  float4 e1 = *(const float4*)(J.be + lane * 8 + 4);
  float gv[8] = {g0.x, g0.y, g0.z, g0.w, g1.x, g1.y, g1.z, g1.w};
  float ev[8] = {e0.x, e0.y, e0.z, e0.w, e1.x, e1.y, e1.z, e1.w};
  float o[8];
  #pragma unroll
  for (int k = 0; k < 8; ++k) o[k] = (v[k] - mean) * inv * gv[k] + ev[k];

  if (J.outF) {
    float4 f0 = {o[0], o[1], o[2], o[3]};
    float4 f1 = {o[4], o[5], o[6], o[7]};
    *(float4*)(J.outF + off8)     = f0;
    *(float4*)(J.outF + off8 + 4) = f1;
  }
  if (J.outB) {
    uint4 p;
    p.x = packbf2(o[0], o[1]); p.y = packbf2(o[2], o[3]);
    p.z = packbf2(o[4], o[5]); p.w = packbf2(o[6], o[7]);
    *(uint4*)(J.outB + off8) = p;
  }
}

// ---------- orchestration ----------
extern "C" void kernel_launch(void* const* d_in, const int* in_sizes, int n_in,
                              void* d_out, int out_size, void* d_ws, size_t ws_size,
                              hipStream_t stream) {
  const float* qe  = (const float*)d_in[0];
  const float* qa  = (const float*)d_in[1];
  const float* Wk  = (const float*)d_in[2];
  const float* bk  = (const float*)d_in[3];
  const float* Wv  = (const float*)d_in[4];
  const float* bv  = (const float*)d_in[5];
  const float* Wo  = (const float*)d_in[6];
  const float* bo  = (const float*)d_in[7];
  const float* gm  = (const float*)d_in[8];
  const float* l1g = (const float*)d_in[9];
  const float* l1b = (const float*)d_in[10];
  const float* W1  = (const float*)d_in[11];
  const float* b1  = (const float*)d_in[12];
  const float* W2  = (const float*)d_in[13];
  const float* b2  = (const float*)d_in[14];
  const float* l2g = (const float*)d_in[15];
  const float* l2b = (const float*)d_in[16];

  char* ws = (char*)d_ws;
  u16* WT  = (u16*)ws;
  u16* A0  = (u16*)(ws + ((size_t)18  << 20));
  u16* A1  = (u16*)(ws + ((size_t)34  << 20));
  u16* A2  = (u16*)(ws + ((size_t)50  << 20));
  u16* A3  = (u16*)(ws + ((size_t)66  << 20));
  u16* A4  = (u16*)(ws + ((size_t)82  << 20));
  u16* A5  = (u16*)(ws + ((size_t)98  << 20));
  u16* B0  = (u16*)(ws + ((size_t)114 << 20));
  u16* B1  = (u16*)(ws + ((size_t)130 << 20));
  u16* X0  = (u16*)(ws + ((size_t)146 << 20));
  u16* Amid = A2;   // [50,114)

  u16* WkT = WT;
  u16* WvT = WT + (size_t)3 * 262144;
  u16* WoT = WT + (size_t)6 * 262144;
  u16* W1T = WT + (size_t)9 * 262144;
  u16* W2T = W1T + (size_t)3 * 1048576;

  pack_w_sq<<<dim3(8, 8, 9),  256, 0, stream>>>(Wk, Wv, Wo, WkT, WvT, WoT);
  pack_w_t<<<dim3(32, 8, 3), 256, 0, stream>>>(W1, W1T, 512, 2048);
  pack_w_t<<<dim3(8, 32, 3), 256, 0, stream>>>(W2, W2T, 2048, 512);
  pack_flat2<<<dim3(4096, 2), 256, 0, stream>>>(qa, qe, A0, A1);

  const float SQ2 = 0.4246609001f;   // sqrt(log2e/8)

  auto g8 = [&](GJobs jobs, int lda, int ldb, int ldc,
                int M, int N, int Kz, int relu, int nz) {
    gemm8<<<dim3(N / 256, M / 256, nz), 512, 0, stream>>>(
        jobs, lda, ldb, ldc, Kz, relu);
  };
  auto ln2x = [&](LNJobs jobs, int nz) {
    ln_kernel<<<dim3(MR / 4, nz), 256, 0, stream>>>(jobs);
  };

  auto WkT_l = [&](int l){ return WkT + (size_t)l * 262144; };
  auto WvT_l = [&](int l){ return WvT + (size_t)l * 262144; };
  auto WoT_l = [&](int l){ return WoT + (size_t)l * 262144; };
  auto W1T_l = [&](int l){ return W1T + (size_t)l * 1048576; };
  auto W2T_l = [&](int l){ return W2T + (size_t)l * 1048576; };

  // ===== layers 0 & 1 batched =====
  {
    GJobs pj = {{ {A0, WkT_l(0), bk,       nullptr, A2, SQ2},
                  {A0, WvT_l(0), bv,       nullptr, A3, 1.f},
                  {A1, WkT_l(1), bk + 512, nullptr, A4, SQ2},
                  {A1, WvT_l(1), bv + 512, nullptr, A5, 1.f} }};
    g8(pj, 512, 512, 512, MR, 512, 512, 0, 4);

    attn_mfma<<<BB * HH * 2, 1024, 0, stream>>>(
        A2, A3, gm, A3, A4, A5, gm + HH, A5, BB * HH, 0, 0);

    GJobs wj = {{ {A3, WoT_l(0), bo,       nullptr, B0, 1.f},
                  {A5, WoT_l(1), bo + 512, nullptr, B1, 1.f},
                  {}, {} }};
    g8(wj, 512, 512, 512, MR, 512, 512, 0, 2);

    LNJobs lj = {{ {A0, B0, nullptr, l1g,       l1b,       nullptr, X0},
                   {A1, B1, nullptr, l1g + 512, l1b + 512, nullptr, A1} }};
    ln2x(lj, 2);
  }
  // ===== layer 0 FFN =====
  {
    GJobs w1j = {{ {X0, W1T_l(0), b1, nullptr, Amid, 1.f}, {}, {}, {} }};
    g8(w1j, 512, 512, 2048, MR, 2048, 512, 1, 1);
    GJobs w2j = {{ {Amid,        W2T_l(0),        b2,      nullptr, B0, 1.f},
                   {Amid + 1024, W2T_l(0) + 1024, nullptr, nullptr, B1, 1.f},
                   {}, {} }};
    g8(w2j, 2048, 2048, 512, MR, 512, 1024, 0, 2);
    LNJobs lj = {{ {X0, B0, B1, l2g, l2b, nullptr, A0}, {} }};   // y1 -> A0
    ln2x(lj, 1);
  }
  // ===== layer 2 =====
  {
    GJobs pj = {{ {A1, WkT_l(2), bk + 1024, nullptr, A2, SQ2},
                  {A0, WvT_l(2), bv + 1024, nullptr, A3, 1.f},
                  {}, {} }};
    g8(pj, 512, 512, 512, MR, 512, 512, 0, 2);

    attn_mfma<<<BB * HH, 1024, 0, stream>>>(
        A2, A3, gm + 2 * HH, A3, A2, A3, gm + 2 * HH, A3, BB * HH, 1, 1);

    GJobs wj = {{ {A3,       WoT_l(2),       bo + 1024, nullptr, B0, 1.f},
                  {A3 + 256, WoT_l(2) + 256, nullptr,   nullptr, B1, 1.f},
                  {}, {} }};
    g8(wj, 512, 512, 512, MR, 512, 256, 0, 2);

    LNJobs l1j = {{ {A1, B0, B1, l1g + 1024, l1b + 1024, nullptr, A1}, {} }};
    ln2x(l1j, 1);

    GJobs w1j = {{ {A1, W1T_l(2), b1 + 2 * DFFN, nullptr, Amid, 1.f}, {}, {}, {} }};
    g8(w1j, 512, 512, 2048, MR, 2048, 512, 1, 1);
    GJobs w2j = {{ {Amid,        W2T_l(2),        b2 + 1024, nullptr, B0, 1.f},
                   {Amid + 1024, W2T_l(2) + 1024, nullptr,   nullptr, B1, 1.f},
                   {}, {} }};
    g8(w2j, 2048, 2048, 512, MR, 512, 1024, 0, 2);

    LNJobs l2j = {{ {A1, B0, B1, l2g + 1024, l2b + 1024, (float*)d_out, nullptr}, {} }};
    ln2x(l2j, 1);
  }
}

// Round 16
// 597.383 us; speedup vs baseline: 1.2058x; 1.0064x over previous
//
#include <hip/hip_runtime.h>

#define BB   32
#define SS   512
#define DDIM 512
#define HH   8
#define DFFN 2048
#define MR   (BB*SS)   // 16384 rows

typedef unsigned int   u32;
typedef unsigned short u16;
typedef unsigned char  u8;
typedef __attribute__((ext_vector_type(8)))  short bf16x8;
typedef __attribute__((ext_vector_type(4)))  float f32x4;
typedef __attribute__((ext_vector_type(16))) float f32x16;
typedef __attribute__((ext_vector_type(2)))  _Float16 h16x2;

// ---------- bf16 helpers ----------
__device__ __forceinline__ u32 packbf2(float x, float y) {
  u32 ux = __float_as_uint(x), uy = __float_as_uint(y);
  u32 hx = (ux + 0x7FFFu + ((ux >> 16) & 1u)) >> 16;
  u32 hy = (uy + 0x7FFFu + ((uy >> 16) & 1u)) >> 16;
  return hx | (hy << 16);
}
__device__ __forceinline__ u16 pack1bf(float x) {
  u32 u = __float_as_uint(x);
  return (u16)((u + 0x7FFFu + ((u >> 16) & 1u)) >> 16);
}

__device__ __forceinline__ float redsum2(float v) {
  v += __shfl_xor(v, 16, 64);
  v += __shfl_xor(v, 32, 64);
  return v;
}

// exp2-domain softmax (scores prescaled by log2e via the GEMM epilogue):
#if __has_builtin(__builtin_amdgcn_exp2f)
__device__ __forceinline__ float ex2c(float x) { return __builtin_amdgcn_exp2f(fminf(x, 110.f)); }
__device__ __forceinline__ float ex2r(float x) { return __builtin_amdgcn_exp2f(x); }
#else
__device__ __forceinline__ float ex2c(float x) {
  float r = fminf(x, 110.f);
  asm("v_exp_f32 %0, %1" : "=v"(r) : "v"(r));
  return r;
}
__device__ __forceinline__ float ex2r(float x) {
  float r;
  asm("v_exp_f32 %0, %1" : "=v"(r) : "v"(x));
  return r;
}
#endif

// ---------- flat f32 -> bf16 pack (dual input via blockIdx.y) ----------
__global__ __launch_bounds__(256) void pack_flat2(
    const float* __restrict__ in0, const float* __restrict__ in1,
    u16* __restrict__ out0, u16* __restrict__ out1) {
  const float* in = blockIdx.y ? in1 : in0;
  u16* out = blockIdx.y ? out1 : out0;
  size_t i = ((size_t)blockIdx.x * 256 + threadIdx.x) * 8;
  float4 a = *(const float4*)(in + i);
  float4 b = *(const float4*)(in + i + 4);
  uint4 o;
  o.x = packbf2(a.x, a.y); o.y = packbf2(a.z, a.w);
  o.z = packbf2(b.x, b.y); o.w = packbf2(b.z, b.w);
  *(uint4*)(out + i) = o;
}

// ---------- weight transpose-pack: f32 [K,N] -> bf16 [N,K] ----------
__device__ __forceinline__ void wtp_body(const float* __restrict__ in,
                                         u16* __restrict__ out, int K, int N,
                                         int bx, int by) {
  __shared__ float tile[64][65];
  const int t  = threadIdx.x;
  const int n0 = bx * 64, k0 = by * 64;
  #pragma unroll
  for (int it = 0; it < 4; ++it) {
    int idx = it * 256 + t;
    int kk = idx >> 4, n4 = idx & 15;
    float4 v = *(const float4*)(in + (size_t)(k0 + kk) * N + n0 + n4 * 4);
    tile[kk][n4*4+0] = v.x; tile[kk][n4*4+1] = v.y;
    tile[kk][n4*4+2] = v.z; tile[kk][n4*4+3] = v.w;
  }
  __syncthreads();
  #pragma unroll
  for (int it = 0; it < 4; ++it) {
    int idx = it * 256 + t;
    int nn = idx >> 4, g = idx & 15;
    uint2 o;
    o.x = packbf2(tile[g*4+0][nn], tile[g*4+1][nn]);
    o.y = packbf2(tile[g*4+2][nn], tile[g*4+3][nn]);
    *(uint2*)(out + (size_t)(n0 + nn) * K + k0 + g * 4) = o;
  }
}
__global__ __launch_bounds__(256) void pack_w_t(const float* __restrict__ in,
                                                u16* __restrict__ out, int K, int N) {
  wtp_body(in + (size_t)blockIdx.z * K * N, out + (size_t)blockIdx.z * N * K,
           K, N, blockIdx.x, blockIdx.y);
}
__global__ __launch_bounds__(256) void pack_w_sq(
    const float* __restrict__ Wk, const float* __restrict__ Wv,
    const float* __restrict__ Wo,
    u16* __restrict__ WkT, u16* __restrict__ WvT, u16* __restrict__ WoT) {
  const int z = blockIdx.z, which = z / 3, li = z % 3;
  const float* in = (which == 0 ? Wk : which == 1 ? Wv : Wo) + (size_t)li * 262144;
  u16* out = (which == 0 ? WkT : which == 1 ? WvT : WoT) + (size_t)li * 262144;
  wtp_body(in, out, 512, 512, blockIdx.x, blockIdx.y);
}

// ---------- 256x256 8-phase GEMM with 32x32x16 MFMA ----------
struct GJob { const u16* A; const u16* Bt; const float* bias;
              float* outF; u16* outB; float sc; };
struct GJobs { GJob j[4]; };

__global__ __launch_bounds__(512, 2) void gemm8(
    GJobs jobs, int lda, int ldb, int ldc, int Kz, int relu)
{
  __shared__ __align__(16) u8 lds[131072];

  const GJob J = jobs.j[blockIdx.z];
  const u16* A    = J.A;
  const u16* Bt   = J.Bt;
  const float* bias = J.bias;
  float* outF = J.outF;
  u16*   outB = J.outB;
  const float sc = J.sc;

  const int nwg  = gridDim.x * gridDim.y;
  const int orig = blockIdx.y * gridDim.x + blockIdx.x;
  const int q8   = nwg >> 3, r8 = nwg & 7;
  const int xcd  = orig & 7, idx8 = orig >> 3;
  const int wg   = (xcd < r8 ? xcd * (q8 + 1) : r8 * (q8 + 1) + (xcd - r8) * q8) + idx8;
  const int bx   = wg % gridDim.x, by = wg / gridDim.x;
  const int row0 = by * 256, col0 = bx * 256;

  const int t    = threadIdx.x;
  const int lane = t & 63, wid = t >> 6;
  const int wm   = wid >> 2, wn = wid & 3;
  const int rl   = lane & 31, lhi = lane >> 5;

  const int NT = Kz >> 6;   // >= 4, even

  f32x16 acc[4][2] = {};

  auto stageA = [&](int buf, int h, int kt) {
    #pragma unroll
    for (int l = 0; l < 2; ++l) {
      int s  = (l * 512 + t) >> 3;
      int kb = ((lane & 7) * 16) ^ ((s & 7) << 4);
      int row = row0 + ((s >> 6) * 128) + h * 64 + (s & 63);
      const u8* src = (const u8*)A + (size_t)row * lda * 2 + (size_t)kt * 128 + kb;
      u8* dst = lds + buf * 65536 + h * 16384 + (l * 512 + wid * 64) * 16;
      __builtin_amdgcn_global_load_lds(
          (const __attribute__((address_space(1))) u32*)src,
          (__attribute__((address_space(3))) u32*)dst, 16, 0, 0);
    }
  };
  auto stageB = [&](int buf, int h, int kt) {
    #pragma unroll
    for (int l = 0; l < 2; ++l) {
      int idx = l * 512 + t;           // 0..1023 = 16B chunks
      int c  = idx >> 2, jj = idx & 3;
      int j  = jj ^ (c & 3);
      const u16* src = Bt + (size_t)(col0 + c) * ldb + kt * 64 + h * 32 + j * 8;
      u8* dst = lds + buf * 65536 + 32768 + h * 16384 + (l * 512 + wid * 64) * 16;
      __builtin_amdgcn_global_load_lds(
          (const __attribute__((address_space(1))) u32*)src,
          (__attribute__((address_space(3))) u32*)dst, 16, 0, 0);
    }
  };

  auto rdA = [&](int buf, int mh, int mt, int kh, int q) -> bf16x8 {
    int s = wm * 64 + mt * 32 + rl;
    int off = buf * 65536 + mh * 16384 + s * 128 +
              (((kh * 64 + q * 32 + lhi * 16)) ^ ((s & 7) << 4));
    return *(const bf16x8*)(lds + off);
  };
  auto rdB = [&](int buf, int kh, int nt, int q) -> bf16x8 {
    int c = wn * 64 + nt * 32 + rl;
    int off = buf * 65536 + 32768 + kh * 16384 + c * 64 +
              (((q * 2 + lhi) ^ (c & 3)) * 16);
    return *(const bf16x8*)(lds + off);
  };

#define GBAR asm volatile("s_barrier" ::: "memory")
#define VMW4 asm volatile("s_waitcnt vmcnt(4)" ::: "memory")
#define VMW0 asm volatile("s_waitcnt vmcnt(0)" ::: "memory")

#define PHASE(BUF, MH, KH, STAGECODE, DOVM) do {                               \
    bf16x8 af_[2][2], bf_[2][2];                                               \
    _Pragma("unroll") for (int mt_ = 0; mt_ < 2; ++mt_)                        \
      _Pragma("unroll") for (int q_ = 0; q_ < 2; ++q_)                         \
        af_[mt_][q_] = rdA(BUF, MH, mt_, KH, q_);                              \
    _Pragma("unroll") for (int nt_ = 0; nt_ < 2; ++nt_)                        \
      _Pragma("unroll") for (int q_ = 0; q_ < 2; ++q_)                         \
        bf_[nt_][q_] = rdB(BUF, KH, nt_, q_);                                  \
    STAGECODE;                                                                 \
    if (DOVM == 1) VMW4;                                                       \
    if (DOVM == 2) VMW0;                                                       \
    GBAR;                                                                      \
    __builtin_amdgcn_s_setprio(1);                                             \
    _Pragma("unroll") for (int mt_ = 0; mt_ < 2; ++mt_)                        \
      _Pragma("unroll") for (int nt_ = 0; nt_ < 2; ++nt_) {                    \
        acc[(MH)*2+mt_][nt_] = __builtin_amdgcn_mfma_f32_32x32x16_bf16(        \
            af_[mt_][0], bf_[nt_][0], acc[(MH)*2+mt_][nt_], 0, 0, 0);          \
        acc[(MH)*2+mt_][nt_] = __builtin_amdgcn_mfma_f32_32x32x16_bf16(        \
            af_[mt_][1], bf_[nt_][1], acc[(MH)*2+mt_][nt_], 0, 0, 0);          \
      }                                                                        \
    __builtin_amdgcn_s_setprio(0);                                             \
    GBAR;                                                                      \
  } while (0)

  // prologue: tile0 fully + tile1's A-h0, B-kh0
  stageA(0, 0, 0); stageB(0, 0, 0); stageA(0, 1, 0); stageB(0, 1, 0);
  stageA(1, 0, 1); stageB(1, 0, 1);
  VMW4; GBAR;

  for (int i = 0; i < (NT >> 1) - 1; ++i) {
    const int T1 = 2 * i + 1, T2 = 2 * i + 2, T3 = 2 * i + 3;
    PHASE(0, 0, 0, stageA(1, 1, T1), 0);
    PHASE(0, 0, 1, stageB(1, 1, T1), 0);
    PHASE(0, 1, 0, stageA(0, 0, T2), 0);
    PHASE(0, 1, 1, stageB(0, 0, T2), 1);
    PHASE(1, 0, 0, stageA(0, 1, T2), 0);
    PHASE(1, 0, 1, stageB(0, 1, T2), 0);
    PHASE(1, 1, 0, stageA(1, 0, T3), 0);
    PHASE(1, 1, 1, stageB(1, 0, T3), 1);
  }
  // tail
  PHASE(0, 0, 0, stageA(1, 1, NT - 1), 0);
  PHASE(0, 0, 1, stageB(1, 1, NT - 1), 0);
  PHASE(0, 1, 0, ;, 0);
  PHASE(0, 1, 1, ;, 2);
  PHASE(1, 0, 0, ;, 0);
  PHASE(1, 0, 1, ;, 0);
  PHASE(1, 1, 0, ;, 0);
  PHASE(1, 1, 1, ;, 0);
#undef PHASE
#undef GBAR
#undef VMW4
#undef VMW0

  // epilogue: 32x32 C/D map: col = lane&31, row = (reg&3)+8*(reg>>2)+4*lhi
  #pragma unroll
  for (int mi = 0; mi < 4; ++mi) {
    #pragma unroll
    for (int nt = 0; nt < 2; ++nt) {
      const int col = col0 + wn * 64 + nt * 32 + rl;
      const float bs = bias ? bias[col] : 0.f;
      #pragma unroll
      for (int reg = 0; reg < 16; ++reg) {
        const int row = row0 + wm * 128 + mi * 32 + (reg & 3) + 8 * (reg >> 2) + 4 * lhi;
        float v = (acc[mi][nt][reg] + bs) * sc;
        if (relu) v = fmaxf(v, 0.f);
        if (outF) outF[(size_t)row * ldc + col] = v;
        if (outB) outB[(size_t)row * ldc + col] = pack1bf(v);
      }
    }
  }
}

// ---------- MFMA attention: 16 waves/block, scores carried in f16 regs ----------
// r16: pass 1 stores each lane's 4 scores/chunk as packed f16 (64 VGPRs;
// budget 128 at 4 waves/SIMD, base was 52) -> pass 2 skips the entire QK^T
// recompute (2 MFMA + 2 swizzled ds_read_b128 + addressing per chunk).
// f16 rounding on scores: ~5e-4 rel -> <1% on p2, normalized by S2.
__global__ __attribute__((amdgpu_flat_work_group_size(1024, 1024)))
void attn_mfma(
    const u16* __restrict__ qkA, const u16* __restrict__ vbA,
    const float* __restrict__ gmA, u16* __restrict__ outAp,
    const u16* __restrict__ qkB, const u16* __restrict__ vbB,
    const float* __restrict__ gmB, u16* __restrict__ outBp,
    int nA, int mask_excl, int zero_pad)
{
  __shared__ __align__(16) u8 kSb[65536];   // K/Q rows [512][64] bf16, byte ^= (row&7)<<4
  __shared__ __align__(16) u8 vTb[65536];   // V^T [64 d][512 k] bf16, u32 ^= ((d&7)^(d>>3))<<4
  __shared__ __align__(16) u8 pChb[16384];  // per-wave 1KB P chunk buffers (16 waves)

  const int t    = threadIdx.x;
  const int lane = t & 63, wid = t >> 6;    // wid in 0..15
  const int ql   = lane & 15, g = lane >> 4;
  const int bid  = blockIdx.x;
  const int sel  = bid >= nA;
  const u16* qk    = sel ? qkB : qkA;
  const u16* vbuf  = sel ? vbB : vbA;
  const float* gam = sel ? gmB : gmA;
  u16* out         = sel ? outBp : outAp;
  const int bh = sel ? bid - nA : bid;
  const int b = bh >> 3, h = bh & 7;
  const size_t base = (size_t)b * SS * DDIM + (size_t)h * 64;

  float gv = gam[h];
  float sp = (gv > 0.f) ? (gv + log1pf(__expf(-gv))) : log1pf(__expf(gv));
  const float gamma2 = -sp * 1.442695041f;   // exp2-domain gamma

  for (int it = 0; it < 4; ++it) {
    int idx = it * 1024 + t;
    int j = idx >> 3, u = idx & 7;
    uint4 w = *(const uint4*)(qk + base + (size_t)j * DDIM + u * 8);
    *(uint4*)(kSb + ((j * 128 + u * 16) ^ ((j & 7) << 4))) = w;
  }
  for (int it = 0; it < 2; ++it) {
    int idx = it * 1024 + t;
    int jp = idx >> 3, u = idx & 7;
    const u16* src = vbuf + base + (size_t)(2 * jp) * DDIM + u * 8;
    uint4 r0 = *(const uint4*)src;
    uint4 r1 = *(const uint4*)(src + DDIM);
    const u16* a0 = (const u16*)&r0;
    const u16* a1 = (const u16*)&r1;
    #pragma unroll
    for (int dd = 0; dd < 8; ++dd) {
      int d = u * 8 + dd;
      u32 w = (u32)a0[dd] | ((u32)a1[dd] << 16);
      *(u32*)(vTb + d * 1024 + ((4 * jp) ^ ((dd ^ u) << 4))) = w;
    }
  }
  __syncthreads();

  bool vm[4];
  #pragma unroll
  for (int rg = 0; rg < 4; ++rg) {
    int kl = 4 * g + rg;
    vm[rg] = mask_excl ? (kl < ql) : (kl <= ql);
  }

  u8* pB = pChb + wid * 1024;
  const int swp = (ql & 7) << 4;

  int vbase[4], vsw[4];
  #pragma unroll
  for (int n = 0; n < 4; ++n) {
    int d = n * 16 + ql;
    vbase[n] = d * 1024;
    vsw[n]   = ((d & 7) ^ ((d >> 3) & 7)) << 4;
  }

  #pragma unroll
  for (int ri = 0; ri < 2; ++ri) {
    const int rs = __builtin_amdgcn_readfirstlane(ri ? (31 - wid) : wid);
    const int i0 = rs * 16;

    // ---- pass 1: scores -> f16 regs; S1 ----
    h16x2 sv16[32][2];
    float S1l = 0.f;
    {
      const int qrow = i0 + ql;
      const int qsw  = (qrow & 7) << 4;
      bf16x8 qf0 = *(const bf16x8*)(kSb + ((qrow * 128      + g * 16) ^ qsw));
      bf16x8 qf1 = *(const bf16x8*)(kSb + ((qrow * 128 + 64 + g * 16) ^ qsw));
      #pragma unroll
      for (int kt = 0; kt < 32; ++kt) {
        if (kt <= rs) {
          const bool dg = (kt == rs);
          const int krow = kt * 16 + ql;
          const int ksw  = (krow & 7) << 4;
          bf16x8 ka0 = *(const bf16x8*)(kSb + ((krow * 128      + g * 16) ^ ksw));
          bf16x8 ka1 = *(const bf16x8*)(kSb + ((krow * 128 + 64 + g * 16) ^ ksw));
          f32x4 dv = {};
          dv = __builtin_amdgcn_mfma_f32_16x16x32_bf16(ka0, qf0, dv, 0, 0, 0);
          dv = __builtin_amdgcn_mfma_f32_16x16x32_bf16(ka1, qf1, dv, 0, 0, 0);
          sv16[kt][0] = h16x2{(_Float16)dv[0], (_Float16)dv[1]};
          sv16[kt][1] = h16x2{(_Float16)dv[2], (_Float16)dv[3]};
          float e0 = (!dg || vm[0]) ? ex2c(dv[0]) : 0.f;
          float e1 = (!dg || vm[1]) ? ex2c(dv[1]) : 0.f;
          float e2 = (!dg || vm[2]) ? ex2c(dv[2]) : 0.f;
          float e3 = (!dg || vm[3]) ? ex2c(dv[3]) : 0.f;
          S1l += (e0 + e1) + (e2 + e3);
        } else {
          sv16[kt][0] = h16x2{(_Float16)0.f, (_Float16)0.f};
          sv16[kt][1] = h16x2{(_Float16)0.f, (_Float16)0.f};
        }
      }
    }
    const float S1   = redsum2(S1l);
    const float inv1 = (S1 > 0.f) ? (1.f / S1) : 0.f;

    // ---- pass 2: f16 scores -> butterfly cumsum -> rescore -> PV ----
    f32x4 oacc[4] = {};
    float cbase = 0.f, S2l = 0.f;
    const float qlf = (float)(i0 + ql);

    auto subkt = [&](int kt, bool dg, u32& wA, u32& wB) {
      float sv[4];
      sv[0] = (float)sv16[kt][0].x; sv[1] = (float)sv16[kt][0].y;
      sv[2] = (float)sv16[kt][1].x; sv[3] = (float)sv16[kt][1].y;
      const bool v0 = !dg || vm[0], v1 = !dg || vm[1];
      const bool v2 = !dg || vm[2], v3 = !dg || vm[3];
      float e0 = v0 ? ex2c(sv[0]) : 0.f;
      float e1 = v1 ? ex2c(sv[1]) : 0.f;
      float e2 = v2 ? ex2c(sv[2]) : 0.f;
      float e3 = v3 ? ex2c(sv[3]) : 0.f;
      float p0 = e0, p1 = p0 + e1, p2 = p1 + e2, p3 = p2 + e3;
      float bq  = __shfl_xor(p3, 16, 64);
      float s1p = p3 + bq;
      float cq  = __shfl_xor(s1p, 32, 64);
      float gp  = ((g & 1) ? bq : 0.f) + ((g & 2) ? cq : 0.f);
      float tt  = s1p + cq;
      const float pbase = cbase + gp;
      const float pf = qlf - (float)(kt * 16 + 4 * g);
      float ipr[4] = {p0, p1, p2, p3};
      bool  vv[4]  = {v0, v1, v2, v3};
      float q2[4];
      #pragma unroll
      for (int rg = 0; rg < 4; ++rg) {
        float rem  = fmaxf((S1 - (pbase + ipr[rg])) * inv1, 0.f);
        float pos  = pf - (float)rg;
        float dist = sqrtf(rem * pos);
        float eff  = fmaxf(ex2r(gamma2 * dist), 1e-5f);
        float ee   = vv[rg] ? ex2c(sv[rg] * eff) : 0.f;
        q2[rg] = ee;
        S2l += ee;
      }
      wA = packbf2(q2[0], q2[1]);
      wB = packbf2(q2[2], q2[3]);
      cbase += tt;
    };

    #pragma unroll
    for (int c = 0; c < 16; ++c) {
      if (2 * c <= rs) {
        u32 w0 = 0, w1 = 0, w2 = 0, w3 = 0;
        subkt(2 * c, (2 * c == rs), w0, w1);
        if (2 * c + 1 <= rs) subkt(2 * c + 1, (2 * c + 1 == rs), w2, w3);
        *(u32*)(pB + ((ql * 64 +      8 * g    ) ^ swp)) = w0;
        *(u32*)(pB + ((ql * 64 +      8 * g + 4) ^ swp)) = w1;
        *(u32*)(pB + ((ql * 64 + 32 + 8 * g    ) ^ swp)) = w2;
        *(u32*)(pB + ((ql * 64 + 32 + 8 * g + 4) ^ swp)) = w3;
        bf16x8 pa = *(const bf16x8*)(pB + ((ql * 64 + 16 * g) ^ swp));
        #pragma unroll
        for (int n = 0; n < 4; ++n) {
          bf16x8 vb = *(const bf16x8*)(vTb + vbase[n] + ((64 * c + 16 * g) ^ vsw[n]));
          oacc[n] = __builtin_amdgcn_mfma_f32_16x16x32_bf16(pa, vb, oacc[n], 0, 0, 0);
        }
      }
    }

    const float S2   = redsum2(S2l);
    const float inv2 = 1.f / fmaxf(S2, 1e-30f);
    float i2[4];
    #pragma unroll
    for (int rg = 0; rg < 4; ++rg) i2[rg] = __shfl(inv2, 4 * g + rg, 64);

    #pragma unroll
    for (int n = 0; n < 4; ++n) {
      #pragma unroll
      for (int rg = 0; rg < 4; ++rg) {
        const int qo = i0 + 4 * g + rg;
        float val = oacc[n][rg] * i2[rg];
        if (zero_pad && qo == 0) val = 0.f;
        out[base + (size_t)qo * DDIM + n * 16 + ql] = pack1bf(val);
      }
    }
  }
}

// ---------- fused residual + LayerNorm (job-array), all bf16 in ----------
struct LNJob { const u16* a; const u16* b; const u16* c;
               const float* g; const float* be; float* outF; u16* outB; };
struct LNJobs { LNJob j[2]; };

__global__ __launch_bounds__(256) void ln_kernel(LNJobs jobs)
{
  const LNJob J = jobs.j[blockIdx.y];
  const int lane = threadIdx.x & 63, w = threadIdx.x >> 6;
  const size_t row = (size_t)blockIdx.x * 4 + w;
  const size_t off8 = row * DDIM + lane * 8;

  uint4 ab = *(const uint4*)(J.a + off8);
  uint4 bb = *(const uint4*)(J.b + off8);
  const u16* ap = (const u16*)&ab;
  const u16* bp = (const u16*)&bb;
  float v[8];
  #pragma unroll
  for (int k = 0; k < 8; ++k)
    v[k] = __uint_as_float(((u32)ap[k]) << 16) + __uint_as_float(((u32)bp[k]) << 16);
  if (J.c) {
    uint4 cb = *(const uint4*)(J.c + off8);
    const u16* cp = (const u16*)&cb;
    #pragma unroll
    for (int k = 0; k < 8; ++k) v[k] += __uint_as_float(((u32)cp[k]) << 16);
  }

  float sum = 0.f;
  #pragma unroll
  for (int k = 0; k < 8; ++k) sum += v[k];
  #pragma unroll
  for (int off = 32; off > 0; off >>= 1) sum += __shfl_xor(sum, off, 64);
  const float mean = sum * (1.f / 512.f);
  float var = 0.f;
  #pragma unroll
  for (int k = 0; k < 8; ++k) { float dd = v[k] - mean; var = fmaf(dd, dd, var); }
  #pragma unroll
  for (int off = 32; off > 0; off >>= 1) var += __shfl_xor(var, off, 64);
  var *= (1.f / 512.f);
  const float inv = rsqrtf(var + 1e-5f);

  float4 g0 = *(const float4*)(J.g + lane * 8);
  float4 g1 = *(const float4*)(J.g + lane * 8 + 4);
  float4 e0 = *(const float4*)(J.be + lane * 8);
  float4 e1 = *(const float4*)(J.be + lane * 8 + 4);
  float gv[8] = {g0.x, g0.y, g0.z, g0.w, g1.x, g1.y, g1.z, g1.w};
  float ev[8] = {e0.x, e0.y, e0.z, e0.w, e1.x, e1.y, e1.z, e1.w};
  float o[8];
  #pragma unroll
  for (int k = 0; k < 8; ++k) o[k] = (v[k] - mean) * inv * gv[k] + ev[k];

  if (J.outF) {
    float4 f0 = {o[0], o[1], o[2], o[3]};
    float4 f1 = {o[4], o[5], o[6], o[7]};
    *(float4*)(J.outF + off8)     = f0;
    *(float4*)(J.outF + off8 + 4) = f1;
  }
  if (J.outB) {
    uint4 p;
    p.x = packbf2(o[0], o[1]); p.y = packbf2(o[2], o[3]);
    p.z = packbf2(o[4], o[5]); p.w = packbf2(o[6], o[7]);
    *(uint4*)(J.outB + off8) = p;
  }
}

// ---------- orchestration ----------
extern "C" void kernel_launch(void* const* d_in, const int* in_sizes, int n_in,
                              void* d_out, int out_size, void* d_ws, size_t ws_size,
                              hipStream_t stream) {
  const float* qe  = (const float*)d_in[0];
  const float* qa  = (const float*)d_in[1];
  const float* Wk  = (const float*)d_in[2];
  const float* bk  = (const float*)d_in[3];
  const float* Wv  = (const float*)d_in[4];
  const float* bv  = (const float*)d_in[5];
  const float* Wo  = (const float*)d_in[6];
  const float* bo  = (const float*)d_in[7];
  const float* gm  = (const float*)d_in[8];
  const float* l1g = (const float*)d_in[9];
  const float* l1b = (const float*)d_in[10];
  const float* W1  = (const float*)d_in[11];
  const float* b1  = (const float*)d_in[12];
  const float* W2  = (const float*)d_in[13];
  const float* b2  = (const float*)d_in[14];
  const float* l2g = (const float*)d_in[15];
  const float* l2b = (const float*)d_in[16];

  char* ws = (char*)d_ws;
  u16* WT  = (u16*)ws;
  u16* A0  = (u16*)(ws + ((size_t)18  << 20));
  u16* A1  = (u16*)(ws + ((size_t)34  << 20));
  u16* A2  = (u16*)(ws + ((size_t)50  << 20));
  u16* A3  = (u16*)(ws + ((size_t)66  << 20));
  u16* A4  = (u16*)(ws + ((size_t)82  << 20));
  u16* A5  = (u16*)(ws + ((size_t)98  << 20));
  u16* B0  = (u16*)(ws + ((size_t)114 << 20));
  u16* B1  = (u16*)(ws + ((size_t)130 << 20));
  u16* X0  = (u16*)(ws + ((size_t)146 << 20));
  u16* Amid = A2;   // [50,114)

  u16* WkT = WT;
  u16* WvT = WT + (size_t)3 * 262144;
  u16* WoT = WT + (size_t)6 * 262144;
  u16* W1T = WT + (size_t)9 * 262144;
  u16* W2T = W1T + (size_t)3 * 1048576;

  pack_w_sq<<<dim3(8, 8, 9),  256, 0, stream>>>(Wk, Wv, Wo, WkT, WvT, WoT);
  pack_w_t<<<dim3(32, 8, 3), 256, 0, stream>>>(W1, W1T, 512, 2048);
  pack_w_t<<<dim3(8, 32, 3), 256, 0, stream>>>(W2, W2T, 2048, 512);
  pack_flat2<<<dim3(4096, 2), 256, 0, stream>>>(qa, qe, A0, A1);

  const float SQ2 = 0.4246609001f;   // sqrt(log2e/8)

  auto g8 = [&](GJobs jobs, int lda, int ldb, int ldc,
                int M, int N, int Kz, int relu, int nz) {
    gemm8<<<dim3(N / 256, M / 256, nz), 512, 0, stream>>>(
        jobs, lda, ldb, ldc, Kz, relu);
  };
  auto ln2x = [&](LNJobs jobs, int nz) {
    ln_kernel<<<dim3(MR / 4, nz), 256, 0, stream>>>(jobs);
  };

  auto WkT_l = [&](int l){ return WkT + (size_t)l * 262144; };
  auto WvT_l = [&](int l){ return WvT + (size_t)l * 262144; };
  auto WoT_l = [&](int l){ return WoT + (size_t)l * 262144; };
  auto W1T_l = [&](int l){ return W1T + (size_t)l * 1048576; };
  auto W2T_l = [&](int l){ return W2T + (size_t)l * 1048576; };

  // ===== layers 0 & 1 batched =====
  {
    GJobs pj = {{ {A0, WkT_l(0), bk,       nullptr, A2, SQ2},
                  {A0, WvT_l(0), bv,       nullptr, A3, 1.f},
                  {A1, WkT_l(1), bk + 512, nullptr, A4, SQ2},
                  {A1, WvT_l(1), bv + 512, nullptr, A5, 1.f} }};
    g8(pj, 512, 512, 512, MR, 512, 512, 0, 4);

    attn_mfma<<<BB * HH * 2, 1024, 0, stream>>>(
        A2, A3, gm, A3, A4, A5, gm + HH, A5, BB * HH, 0, 0);

    GJobs wj = {{ {A3, WoT_l(0), bo,       nullptr, B0, 1.f},
                  {A5, WoT_l(1), bo + 512, nullptr, B1, 1.f},
                  {}, {} }};
    g8(wj, 512, 512, 512, MR, 512, 512, 0, 2);

    LNJobs lj = {{ {A0, B0, nullptr, l1g,       l1b,       nullptr, X0},
                   {A1, B1, nullptr, l1g + 512, l1b + 512, nullptr, A1} }};
    ln2x(lj, 2);
  }
  // ===== layer 0 FFN =====
  {
    GJobs w1j = {{ {X0, W1T_l(0), b1, nullptr, Amid, 1.f}, {}, {}, {} }};
    g8(w1j, 512, 512, 2048, MR, 2048, 512, 1, 1);
    GJobs w2j = {{ {Amid,        W2T_l(0),        b2,      nullptr, B0, 1.f},
                   {Amid + 1024, W2T_l(0) + 1024, nullptr, nullptr, B1, 1.f},
                   {}, {} }};
    g8(w2j, 2048, 2048, 512, MR, 512, 1024, 0, 2);
    LNJobs lj = {{ {X0, B0, B1, l2g, l2b, nullptr, A0}, {} }};   // y1 -> A0
    ln2x(lj, 1);
  }
  // ===== layer 2 =====
  {
    GJobs pj = {{ {A1, WkT_l(2), bk + 1024, nullptr, A2, SQ2},
                  {A0, WvT_l(2), bv + 1024, nullptr, A3, 1.f},
                  {}, {} }};
    g8(pj, 512, 512, 512, MR, 512, 512, 0, 2);

    attn_mfma<<<BB * HH, 1024, 0, stream>>>(
        A2, A3, gm + 2 * HH, A3, A2, A3, gm + 2 * HH, A3, BB * HH, 1, 1);

    GJobs wj = {{ {A3,       WoT_l(2),       bo + 1024, nullptr, B0, 1.f},
                  {A3 + 256, WoT_l(2) + 256, nullptr,   nullptr, B1, 1.f},
                  {}, {} }};
    g8(wj, 512, 512, 512, MR, 512, 256, 0, 2);

    LNJobs l1j = {{ {A1, B0, B1, l1g + 1024, l1b + 1024, nullptr, A1}, {} }};
    ln2x(l1j, 1);

    GJobs w1j = {{ {A1, W1T_l(2), b1 + 2 * DFFN, nullptr, Amid, 1.f}, {}, {}, {} }};
    g8(w1j, 512, 512, 2048, MR, 2048, 512, 1, 1);
    GJobs w2j = {{ {Amid,        W2T_l(2),        b2 + 1024, nullptr, B0, 1.f},
                   {Amid + 1024, W2T_l(2) + 1024, nullptr,   nullptr, B1, 1.f},
                   {}, {} }};
    g8(w2j, 2048, 2048, 512, MR, 512, 1024, 0, 2);

    LNJobs l2j = {{ {A1, B0, B1, l2g + 1024, l2b + 1024, (float*)d_out, nullptr}, {} }};
    ln2x(l2j, 1);
  }
}